// Round 11
// baseline (880.139 us; speedup 1.0000x reference)
//
#include <hip/hip_runtime.h>
#include <hip/hip_bf16.h>
#include <cstddef>

#define THREADS 256
#define NSLOT 64   // stats replication slots (kills atomic hot-spotting)

typedef unsigned short ushort_t;
typedef unsigned int uint_t;

// ---- bf16 <-> f32 helpers (RNE) ----
__device__ __forceinline__ float b2f(ushort_t u) {
    union { float f; uint_t i; } v; v.i = ((uint_t)u) << 16; return v.f;
}
__device__ __forceinline__ ushort_t f2b(float f) {
    uint_t i = __float_as_uint(f);
    uint_t r = i + 0x7fffu + ((i >> 16) & 1u);
    return (ushort_t)(r >> 16);
}
__device__ __forceinline__ void unpack8(uint4 r, float* v) {
    v[0] = b2f(r.x & 0xffff); v[1] = b2f(r.x >> 16);
    v[2] = b2f(r.y & 0xffff); v[3] = b2f(r.y >> 16);
    v[4] = b2f(r.z & 0xffff); v[5] = b2f(r.z >> 16);
    v[6] = b2f(r.w & 0xffff); v[7] = b2f(r.w >> 16);
}
__device__ __forceinline__ uint4 pack8(const float* v) {
    uint4 r;
    r.x = (uint_t)f2b(v[0]) | ((uint_t)f2b(v[1]) << 16);
    r.y = (uint_t)f2b(v[2]) | ((uint_t)f2b(v[3]) << 16);
    r.z = (uint_t)f2b(v[4]) | ((uint_t)f2b(v[5]) << 16);
    r.w = (uint_t)f2b(v[6]) | ((uint_t)f2b(v[7]) << 16);
    return r;
}

// ---------------- small kernels ----------------

// LDS-staged per-class mean of local_x (nl <= 512)
__global__ __launch_bounds__(256) void local_means_kernel(const float* __restrict__ lx,
                                                          const int* __restrict__ lt,
                                                          float* __restrict__ means, int nl)
{
    __shared__ float slx[512 * 19];
    __shared__ int   slt[512];
    const int tid = threadIdx.x;
    for (int i = tid; i < nl * 19; i += 256) slx[i] = lx[i];
    for (int i = tid; i < nl; i += 256) slt[i] = lt[i];
    __syncthreads();
    if (tid >= 7 * 19) return;
    int c = tid / 19, dd = tid % 19;
    float s = 0.f; int cnt = 0;
    for (int i = 0; i < nl; ++i) {
        if (slt[i] == c) { s += slx[i * 19 + dd]; cnt++; }
    }
    means[tid] = cnt > 0 ? s / (float)cnt : 0.f;
}

__global__ void hist_kernel(const int* __restrict__ dst, int* __restrict__ degi, int E)
{
    int t = blockIdx.x * THREADS + threadIdx.x;
    if (t < E) atomicAdd(&degi[dst[t]], 1);
}

// ---- 3-pass parallel exclusive scan over degi ----

__global__ __launch_bounds__(256) void scan_part1_kernel(const int* __restrict__ degi,
                                                         int* __restrict__ blocksums, int n)
{
    const int tid = threadIdx.x;
    const int idx = blockIdx.x * 1024 + tid * 4;
    int v = 0;
    if (idx + 3 < n) {
        int4 d = *(const int4*)&degi[idx];
        v = d.x + d.y + d.z + d.w;
    } else {
        for (int i = 0; i < 4; ++i) if (idx + i < n) v += degi[idx + i];
    }
    __shared__ int s[256];
    s[tid] = v;
    __syncthreads();
    for (int off = 128; off >= 1; off >>= 1) {
        if (tid < off) s[tid] += s[tid + off];
        __syncthreads();
    }
    if (tid == 0) blocksums[blockIdx.x] = s[0];
}

__global__ __launch_bounds__(256) void scan_part2_kernel(int* __restrict__ blocksums, int nb)
{
    __shared__ int s[256];
    const int tid = threadIdx.x;
    int v = (tid < nb) ? blocksums[tid] : 0;
    s[tid] = v;
    __syncthreads();
    for (int off = 1; off < 256; off <<= 1) {
        int t = (tid >= off) ? s[tid - off] : 0;
        __syncthreads();
        s[tid] += t;
        __syncthreads();
    }
    if (tid < nb) blocksums[tid] = s[tid] - v;  // exclusive
}

// writes rowptr + cursor copy + dinv (fused)
__global__ __launch_bounds__(256) void scan_part3_kernel(const int* __restrict__ degi,
                                                         const int* __restrict__ blocksums,
                                                         int* __restrict__ rowptr,
                                                         int* __restrict__ cursor,
                                                         float* __restrict__ dinv, int n, int E)
{
    const int tid = threadIdx.x;
    const int idx = blockIdx.x * 1024 + tid * 4;
    int d0 = 0, d1 = 0, d2 = 0, d3 = 0;
    if (idx + 3 < n) {
        int4 d = *(const int4*)&degi[idx];
        d0 = d.x; d1 = d.y; d2 = d.z; d3 = d.w;
    } else {
        if (idx     < n) d0 = degi[idx];
        if (idx + 1 < n) d1 = degi[idx + 1];
        if (idx + 2 < n) d2 = degi[idx + 2];
        if (idx + 3 < n) d3 = degi[idx + 3];
    }
    const int v = d0 + d1 + d2 + d3;
    __shared__ int s[256];
    s[tid] = v;
    __syncthreads();
    for (int off = 1; off < 256; off <<= 1) {
        int t = (tid >= off) ? s[tid - off] : 0;
        __syncthreads();
        s[tid] += t;
        __syncthreads();
    }
    int run = blocksums[blockIdx.x] + s[tid] - v;
    if (idx + 3 < n) {
        int4 o;
        o.x = run; run += d0;
        o.y = run; run += d1;
        o.z = run; run += d2;
        o.w = run;
        *(int4*)&rowptr[idx] = o;
        *(int4*)&cursor[idx] = o;
        float4 dv;
        dv.x = rsqrtf((float)d0 + 1.0f);
        dv.y = rsqrtf((float)d1 + 1.0f);
        dv.z = rsqrtf((float)d2 + 1.0f);
        dv.w = rsqrtf((float)d3 + 1.0f);
        *(float4*)&dinv[idx] = dv;
    } else {
        if (idx     < n) { rowptr[idx]     = run; cursor[idx]     = run; dinv[idx]     = rsqrtf((float)d0 + 1.0f); run += d0; }
        if (idx + 1 < n) { rowptr[idx + 1] = run; cursor[idx + 1] = run; dinv[idx + 1] = rsqrtf((float)d1 + 1.0f); run += d1; }
        if (idx + 2 < n) { rowptr[idx + 2] = run; cursor[idx + 2] = run; dinv[idx + 2] = rsqrtf((float)d2 + 1.0f); run += d2; }
        if (idx + 3 < n) { rowptr[idx + 3] = run; cursor[idx + 3] = run; dinv[idx + 3] = rsqrtf((float)d3 + 1.0f); }
    }
    if (blockIdx.x == 0 && tid == 0) rowptr[n] = E;
}

__global__ void fill_kernel(const int* __restrict__ src, const int* __restrict__ dst,
                            int* __restrict__ cursor, int* __restrict__ esrc, int E)
{
    int t = blockIdx.x * THREADS + threadIdx.x;
    if (t >= E) return;
    int s = src[t], d = dst[t];
    int pos = atomicAdd(&cursor[d], 1);
    esrc[pos] = s;
}

__global__ void build_x0_kernel(const float* __restrict__ means,
                                const int* __restrict__ vt,
                                const float* __restrict__ vx,
                                const float* __restrict__ label,
                                float* __restrict__ out, int n)
{
    int tid = blockIdx.x * THREADS + threadIdx.x;
    int node = tid >> 5, c = tid & 31;
    if (node >= n) return;
    float v;
    if (c < 19)      v = means[vt[node] * 19 + c];
    else if (c < 25) v = vx[node * 6 + (c - 19)];
    else             v = label[node * 7 + (c - 25)];
    out[(size_t)node * 32 + c] = v;
}

// ---------------- elementwise GN-affine + ReLU + dinv row-scale (f32 in, bf16 out) ----
template<int D>
__global__ void transform_kernel(const float* __restrict__ x, ushort_t* __restrict__ out,
                                 const float* __restrict__ tr, const float* __restrict__ dinv, int n)
{
    constexpr int Q = D / 8;
    int t = blockIdx.x * THREADS + threadIdx.x;
    int node = t / Q, q = t % Q;
    if (node >= n) return;
    float v[8], o[8];
    *(float4*)&v[0] = *(const float4*)&x[(size_t)node * D + q * 8];
    *(float4*)&v[4] = *(const float4*)&x[(size_t)node * D + q * 8 + 4];
    const float dd = dinv[node];
#pragma unroll
    for (int e = 0; e < 8; ++e) {
        o[e] = fmaxf(fmaf(v[e], tr[q * 8 + e], tr[D + q * 8 + e]), 0.f) * dd;
    }
    *(uint4*)&out[(size_t)node * D + q * 8] = pack8(o);
}

// ---------------- dense layer (f32 in, f32 or bf16 out, fp32 math) ----------------
// Split-J tiling + register double-buffered staging: global loads for k-tile t+1
// issue before the compute of tile t (latency hidden under ~4096 FMA cycles),
// regs are dumped to LDS after the post-compute barrier. No extra LDS used.
template<int DIN, int DOUT, int BN, int JPER, bool RELU, bool BIAS, bool TRANSFORM, bool SCALE, bool OUTBF>
__global__ __launch_bounds__(256) void mlp_kernel(
    const float* __restrict__ in, void* __restrict__ out_v,
    const float* __restrict__ W, const float* __restrict__ bias,
    const float* __restrict__ tr /* a[0:DIN), c[DIN:2*DIN) */,
    const float* __restrict__ rowscale, int n)
{
    constexpr int KT  = 32;
    constexpr int NT  = DIN / KT;       // k-tiles
    constexpr int TJ  = DOUT / JPER;    // threads along j
    constexpr int TN  = 256 / TJ;       // thread groups along nodes
    constexpr int NPT = BN / TN;        // nodes per thread
    constexpr int JQ  = JPER / 4;       // 4-col chunks per thread
    constexpr int CS  = 4 * TJ;         // chunk stride in cols
    constexpr int BNP = BN + 4;
    constexpr int WSTAGE = (KT * DOUT) / 1024;  // float4 per thread for W tile
    constexpr int XSTAGE = (BN * KT) / 1024;    // float4 per thread for x tile

    __shared__ float Wt[KT * DOUT];
    __shared__ float xT[KT][BNP];

    const int tid   = threadIdx.x;
    const int nbase = blockIdx.x * BN;
    const int tj = tid % TJ, tn = tid / TJ;
    const int j0 = tj * 4, n0 = tn * NPT;

    float4 wbuf[WSTAGE];
    float4 xbuf[XSTAGE];

    auto load_tile = [&](int kt) {
#pragma unroll
        for (int s = 0; s < WSTAGE; ++s)
            wbuf[s] = *(const float4*)&W[(size_t)kt * DOUT + (tid + s * 256) * 4];
#pragma unroll
        for (int s = 0; s < XSTAGE; ++s) {
            const int i    = tid + s * 256;
            const int node = i / (KT / 4);
            const int kq   = i % (KT / 4);
            const int g    = nbase + node;
            float4 v = make_float4(0.f, 0.f, 0.f, 0.f);
            if (g < n) {
                v = *(const float4*)&in[(size_t)g * DIN + kt + kq * 4];
                if (TRANSFORM) {
                    const float4 a = *(const float4*)&tr[kt + kq * 4];
                    const float4 c = *(const float4*)&tr[DIN + kt + kq * 4];
                    v.x = fmaxf(fmaf(v.x, a.x, c.x), 0.f);
                    v.y = fmaxf(fmaf(v.y, a.y, c.y), 0.f);
                    v.z = fmaxf(fmaf(v.z, a.z, c.z), 0.f);
                    v.w = fmaxf(fmaf(v.w, a.w, c.w), 0.f);
                }
            }
            xbuf[s] = v;
        }
    };
    auto store_tile = [&]() {
#pragma unroll
        for (int s = 0; s < WSTAGE; ++s)
            *(float4*)&Wt[(tid + s * 256) * 4] = wbuf[s];
#pragma unroll
        for (int s = 0; s < XSTAGE; ++s) {
            const int i    = tid + s * 256;
            const int node = i / (KT / 4);
            const int kq   = i % (KT / 4);
            xT[kq * 4 + 0][node] = xbuf[s].x;
            xT[kq * 4 + 1][node] = xbuf[s].y;
            xT[kq * 4 + 2][node] = xbuf[s].z;
            xT[kq * 4 + 3][node] = xbuf[s].w;
        }
    };

    float acc[NPT][JPER];
#pragma unroll
    for (int p = 0; p < NPT; ++p)
#pragma unroll
        for (int j = 0; j < JPER; ++j) acc[p][j] = 0.f;

    load_tile(0);
    store_tile();

    for (int t = 0; t < NT; ++t) {
        __syncthreads();                        // staged LDS visible
        if (t + 1 < NT) load_tile((t + 1) * KT); // issue next tile's global loads
#pragma unroll 4
        for (int kk = 0; kk < KT; ++kk) {
            float wv[JPER];
#pragma unroll
            for (int q = 0; q < JQ; ++q)
                *(float4*)&wv[q * 4] = *(const float4*)&Wt[kk * DOUT + q * CS + j0];
            float xv[NPT];
#pragma unroll
            for (int q = 0; q < NPT / 4; ++q)
                *(float4*)&xv[q * 4] = *(const float4*)&xT[kk][n0 + q * 4];
#pragma unroll
            for (int p = 0; p < NPT; ++p)
#pragma unroll
                for (int j = 0; j < JPER; ++j)
                    acc[p][j] = fmaf(xv[p], wv[j], acc[p][j]);
        }
        __syncthreads();                        // all LDS reads of tile t done
        if (t + 1 < NT) store_tile();           // dump regs -> LDS
    }

    float bv[JPER];
#pragma unroll
    for (int j = 0; j < JPER; ++j) bv[j] = 0.f;
    if (BIAS) {
#pragma unroll
        for (int q = 0; q < JQ; ++q)
            *(float4*)&bv[q * 4] = *(const float4*)&bias[q * CS + j0];
    }

#pragma unroll
    for (int p = 0; p < NPT; ++p) {
        const int g = nbase + n0 + p;
        if (g >= n) continue;
        float rs = 1.f;
        if (SCALE) rs = rowscale[g];
#pragma unroll
        for (int q = 0; q < JQ; ++q) {
            float o[4];
#pragma unroll
            for (int e = 0; e < 4; ++e) {
                float x = acc[p][q * 4 + e] + bv[q * 4 + e];
                if (RELU) x = fmaxf(x, 0.f);
                if (SCALE) x *= rs;
                o[e] = x;
            }
            if (OUTBF) {
                ushort4 ob;
                ob.x = f2b(o[0]); ob.y = f2b(o[1]); ob.z = f2b(o[2]); ob.w = f2b(o[3]);
                *(ushort4*)&((ushort_t*)out_v)[(size_t)g * DOUT + q * CS + j0] = ob;
            } else {
                *(float4*)&((float*)out_v)[(size_t)g * DOUT + q * CS + j0] =
                    make_float4(o[0], o[1], o[2], o[3]);
            }
        }
    }
}

// ---------------- CSR gather aggregation (post-GEMM), bf16 table -> f32 out ----
template<int D>
__global__ __launch_bounds__(256) void gather_agg_kernel(
    const ushort_t* __restrict__ y, float* __restrict__ out,
    const int* __restrict__ rowptr, const int* __restrict__ esrc,
    const float* __restrict__ dinv,
    const float* __restrict__ bias, float* __restrict__ statsP, int n)
{
    constexpr int JT  = D / 8;       // threads per node
    constexpr int NPB = 256 / JT;    // nodes per block-pass
    const int tid  = threadIdx.x;
    const int jq   = tid % JT;
    const int nsub = tid / JT;
    const int j0   = jq * 8;

    float bv[8];
#pragma unroll
    for (int e = 0; e < 8; ++e) bv[e] = bias[j0 + e];

    float s1[8], s2[8];
#pragma unroll
    for (int e = 0; e < 8; ++e) { s1[e] = 0.f; s2[e] = 0.f; }

    const int ntiles = (n + NPB - 1) / NPB;
    for (int tile = blockIdx.x; tile < ntiles; tile += gridDim.x) {
        const int node = tile * NPB + nsub;
        if (node < n) {
            const int rb = rowptr[node], re = rowptr[node + 1];
            const float dd = dinv[node];
            float acc[8];
            unpack8(*(const uint4*)&y[(size_t)node * D + j0], acc);
            int k = rb;
            for (; k + 3 < re; k += 4) {
                const int sa = esrc[k], sb = esrc[k + 1];
                const int sc = esrc[k + 2], sd = esrc[k + 3];
                const uint4 r0 = *(const uint4*)&y[(size_t)sa * D + j0];
                const uint4 r1 = *(const uint4*)&y[(size_t)sb * D + j0];
                const uint4 r2 = *(const uint4*)&y[(size_t)sc * D + j0];
                const uint4 r3 = *(const uint4*)&y[(size_t)sd * D + j0];
                float v0[8], v1[8], v2[8], v3[8];
                unpack8(r0, v0); unpack8(r1, v1); unpack8(r2, v2); unpack8(r3, v3);
#pragma unroll
                for (int e = 0; e < 8; ++e) acc[e] += (v0[e] + v1[e]) + (v2[e] + v3[e]);
            }
            for (; k < re; ++k) {
                float va[8];
                unpack8(*(const uint4*)&y[(size_t)esrc[k] * D + j0], va);
#pragma unroll
                for (int e = 0; e < 8; ++e) acc[e] += va[e];
            }
            float o[8];
#pragma unroll
            for (int e = 0; e < 8; ++e) {
                o[e] = fmaf(acc[e], dd, bv[e]);
                s1[e] += o[e];
                s2[e] = fmaf(o[e], o[e], s2[e]);
            }
            *(float4*)&out[(size_t)node * D + j0]     = make_float4(o[0], o[1], o[2], o[3]);
            *(float4*)&out[(size_t)node * D + j0 + 4] = make_float4(o[4], o[5], o[6], o[7]);
        }
    }

    __shared__ float red[256][17];
#pragma unroll
    for (int e = 0; e < 8; ++e) { red[tid][e] = s1[e]; red[tid][8 + e] = s2[e]; }
    __syncthreads();
#pragma unroll
    for (int off = NPB / 2; off >= 1; off >>= 1) {
        if (nsub < off) {
#pragma unroll
            for (int e = 0; e < 16; ++e) red[tid][e] += red[tid + off * JT][e];
        }
        __syncthreads();
    }
    if (nsub == 0) {
        float* slot = statsP + (size_t)(blockIdx.x & (NSLOT - 1)) * 256;
#pragma unroll
        for (int e = 0; e < 8; ++e) {
            atomicAdd(&slot[j0 + e],     red[tid][e]);
            atomicAdd(&slot[D + j0 + e], red[tid][8 + e]);
        }
    }
}

// ---------------- CSR gather aggregation (pre-GEMM), bf16 table -> f32 out ----------------
template<int D>
__global__ __launch_bounds__(256) void gather_pre_kernel(
    const ushort_t* __restrict__ x, float* __restrict__ out,
    const int* __restrict__ rowptr, const int* __restrict__ esrc,
    const float* __restrict__ dinv, int n)
{
    constexpr int JT  = D / 8;
    constexpr int NPB = 256 / JT;
    const int tid  = threadIdx.x;
    const int jq   = tid % JT;
    const int nsub = tid / JT;
    const int j0   = jq * 8;

    const int ntiles = (n + NPB - 1) / NPB;
    for (int tile = blockIdx.x; tile < ntiles; tile += gridDim.x) {
        const int node = tile * NPB + nsub;
        if (node < n) {
            const int rb = rowptr[node], re = rowptr[node + 1];
            const float dd = dinv[node];
            float acc[8];
            unpack8(*(const uint4*)&x[(size_t)node * D + j0], acc);
            int k = rb;
            for (; k + 3 < re; k += 4) {
                const int sa = esrc[k], sb = esrc[k + 1];
                const int sc = esrc[k + 2], sd = esrc[k + 3];
                const uint4 r0 = *(const uint4*)&x[(size_t)sa * D + j0];
                const uint4 r1 = *(const uint4*)&x[(size_t)sb * D + j0];
                const uint4 r2 = *(const uint4*)&x[(size_t)sc * D + j0];
                const uint4 r3 = *(const uint4*)&x[(size_t)sd * D + j0];
                float v0[8], v1[8], v2[8], v3[8];
                unpack8(r0, v0); unpack8(r1, v1); unpack8(r2, v2); unpack8(r3, v3);
#pragma unroll
                for (int e = 0; e < 8; ++e) acc[e] += (v0[e] + v1[e]) + (v2[e] + v3[e]);
            }
            for (; k < re; ++k) {
                float va[8];
                unpack8(*(const uint4*)&x[(size_t)esrc[k] * D + j0], va);
#pragma unroll
                for (int e = 0; e < 8; ++e) acc[e] += va[e];
            }
            float o[8];
#pragma unroll
            for (int e = 0; e < 8; ++e) o[e] = acc[e] * dd;
            *(float4*)&out[(size_t)node * D + j0]     = make_float4(o[0], o[1], o[2], o[3]);
            *(float4*)&out[(size_t)node * D + j0 + 4] = make_float4(o[4], o[5], o[6], o[7]);
        }
    }
}

// ---------------- standalone column stats (f32 in) -> slots ----------------
template<int D>
__global__ __launch_bounds__(256) void gn_stats_kernel(const float* __restrict__ x,
                                                       float* __restrict__ statsP, int n)
{
    constexpr int JT   = D / 4;      // col blocks of 4
    constexpr int NPB  = 256 / JT;   // rows in parallel
    constexpr int ITER = 32;
    const int tid  = threadIdx.x;
    const int jb   = tid % JT;
    const int rsub = tid / JT;
    const int j0   = jb * 4;
    const int base = blockIdx.x * NPB * ITER;

    float s1[4] = {0.f, 0.f, 0.f, 0.f};
    float s2[4] = {0.f, 0.f, 0.f, 0.f};

#pragma unroll 4
    for (int i = 0; i < ITER; ++i) {
        int r = base + rsub + i * NPB;
        if (r < n) {
            float4 v = *(const float4*)&x[(size_t)r * D + j0];
            s1[0] += v.x; s1[1] += v.y; s1[2] += v.z; s1[3] += v.w;
            s2[0] = fmaf(v.x, v.x, s2[0]);
            s2[1] = fmaf(v.y, v.y, s2[1]);
            s2[2] = fmaf(v.z, v.z, s2[2]);
            s2[3] = fmaf(v.w, v.w, s2[3]);
        }
    }

    __shared__ float red[256][9];
#pragma unroll
    for (int e = 0; e < 4; ++e) { red[tid][e] = s1[e]; red[tid][4 + e] = s2[e]; }
    __syncthreads();
#pragma unroll
    for (int off = NPB / 2; off >= 1; off >>= 1) {
        if (rsub < off) {
#pragma unroll
            for (int e = 0; e < 8; ++e) red[tid][e] += red[tid + off * JT][e];
        }
        __syncthreads();
    }
    if (rsub == 0) {
        float* slot = statsP + (size_t)(blockIdx.x & (NSLOT - 1)) * 256;
#pragma unroll
        for (int e = 0; e < 4; ++e) {
            atomicAdd(&slot[j0 + e],     red[tid][e]);
            atomicAdd(&slot[D + j0 + e], red[tid][4 + e]);
        }
    }
}

// Reduce slots, turn (sum, sumsq) into the fused affine y = a*x + c
template<int D>
__global__ void gn_finalize_kernel(const float* __restrict__ part, float* __restrict__ ac,
                                   const float* __restrict__ gw, const float* __restrict__ gb,
                                   const float* __restrict__ gm, float inv_n)
{
    int j = threadIdx.x;
    if (j >= D) return;
    float s1 = 0.f, s2 = 0.f;
    for (int t = 0; t < NSLOT; ++t) {
        s1 += part[(size_t)t * 256 + j];
        s2 += part[(size_t)t * 256 + D + j];
    }
    float mean = s1 * inv_n;
    float ex2  = s2 * inv_n;
    float m    = gm[j];
    float var  = ex2 - (2.f * m - m * m) * mean * mean;
    float a    = gw[j] * rsqrtf(var + 1e-5f);
    float c    = gb[j] - a * m * mean;
    ac[j]     = a;
    ac[D + j] = c;
}

// ---------------- fused decoder tail: 64 -> relu32 -> relu16 -> sigmoid(1) ----------------
__global__ __launch_bounds__(256) void dec_tail_kernel(
    const float* __restrict__ in, const float* __restrict__ W1, const float* __restrict__ b1,
    const float* __restrict__ W2, const float* __restrict__ b2,
    const float* __restrict__ W3, const float* __restrict__ b3,
    float* __restrict__ out, int n)
{
    int t = blockIdx.x * THREADS + threadIdx.x;
    if (t >= n) return;

    float x[64];
#pragma unroll
    for (int q = 0; q < 16; ++q)
        *(float4*)&x[q * 4] = *(const float4*)&in[(size_t)t * 64 + q * 4];

    float h1[32];
#pragma unroll
    for (int j = 0; j < 32; ++j) h1[j] = b1[j];
#pragma unroll 8
    for (int k = 0; k < 64; ++k) {
        const float xk = x[k];
#pragma unroll
        for (int j = 0; j < 32; ++j) h1[j] = fmaf(xk, W1[k * 32 + j], h1[j]);
    }
#pragma unroll
    for (int j = 0; j < 32; ++j) h1[j] = fmaxf(h1[j], 0.f);

    float h2[16];
#pragma unroll
    for (int j = 0; j < 16; ++j) h2[j] = b2[j];
#pragma unroll 8
    for (int k = 0; k < 32; ++k) {
        const float hk = h1[k];
#pragma unroll
        for (int j = 0; j < 16; ++j) h2[j] = fmaf(hk, W2[k * 16 + j], h2[j]);
    }

    float acc = b3[0];
#pragma unroll
    for (int k = 0; k < 16; ++k) acc = fmaf(fmaxf(h2[k], 0.f), W3[k], acc);
    out[t] = 1.0f / (1.0f + expf(-acc));
}

// ---------------- launch ----------------

extern "C" void kernel_launch(void* const* d_in, const int* in_sizes, int n_in,
                              void* d_out, int out_size, void* d_ws, size_t ws_size,
                              hipStream_t stream)
{
    const float* local_x    = (const float*)d_in[0];
    const int*   local_type = (const int*)d_in[1];
    const float* voxel_x    = (const float*)d_in[2];
    const int*   voxel_type = (const int*)d_in[3];
    const int*   edge_index = (const int*)d_in[4];
    const float* label      = (const float*)d_in[5];
    const float* We1 = (const float*)d_in[6],  *be1 = (const float*)d_in[7];
    const float* We2 = (const float*)d_in[8],  *be2 = (const float*)d_in[9];
    const float *Wc[4], *bc[4], *gw[4], *gb[4], *gm[4];
    for (int i = 0; i < 4; ++i) {
        Wc[i] = (const float*)d_in[10 + i * 5];
        bc[i] = (const float*)d_in[11 + i * 5];
        gw[i] = (const float*)d_in[12 + i * 5];
        gb[i] = (const float*)d_in[13 + i * 5];
        gm[i] = (const float*)d_in[14 + i * 5];
    }
    const float* Wd0 = (const float*)d_in[30], *bd0 = (const float*)d_in[31];
    const float* Wd1 = (const float*)d_in[32], *bd1 = (const float*)d_in[33];
    const float* Wd2 = (const float*)d_in[34], *bd2 = (const float*)d_in[35];
    const float* Wd3 = (const float*)d_in[36], *bd3 = (const float*)d_in[37];

    const int n  = in_sizes[2] / 6;    // 200000
    const int E  = in_sizes[4] / 2;    // 1200000
    const int nl = in_sizes[0] / 19;   // 400
    const int* src = edge_index;
    const int* dst = edge_index + E;

    // Workspace (~237 MB, < proven-safe 257 MB):
    // [ac 4KB][means 4KB][blocksums 1KB][stats_part 256KB][rowptr n+1][dinv n][esrc E]
    // [A f32 n*128][B f32 n*128][Y bf16 n*64]; transient degi/cursor alias A.
    auto align256 = [](size_t x) { return (x + 255) & ~(size_t)255; };
    char* w = (char*)d_ws;
    float* ac_all = (float*)w;
    float* means  = (float*)(w + 4096);
    int* blocksums = (int*)(w + 8192);
    float* stats_part = (float*)(w + 8192 + 1024);
    size_t off = 8192 + 1024 + 4 * NSLOT * 256 * sizeof(float);
    int*   rowptr = (int*)(w + off);   off += align256((size_t)(n + 1) * 4);
    float* dinv   = (float*)(w + off); off += align256((size_t)n * 4);
    int*   esrc   = (int*)(w + off);   off += align256((size_t)E * 4);
    float* A  = (float*)(w + off);                 // n*128 f32
    float* B  = A + (size_t)n * 128;               // n*128 f32
    ushort_t* Y = (ushort_t*)(B + (size_t)n * 128); // n*64 bf16 gather table
    float* A2 = A + (size_t)n * 64;
    float* B2 = B + (size_t)n * 64;
    int*   degi   = (int*)A;                        // transient alias
    int*   cursor = (int*)A2;                       // transient alias

    const float inv_n = 1.0f / (float)n;
    auto cdiv = [](long long a, long long b) { return (int)((a + b - 1) / b); };
    const int nb = cdiv(n, 1024);

    float* part0 = stats_part + 0 * NSLOT * 256;
    float* part1 = stats_part + 1 * NSLOT * 256;
    float* part2 = stats_part + 2 * NSLOT * 256;
    float* part3 = stats_part + 3 * NSLOT * 256;
    float* ac0 = ac_all + 0, *ac1 = ac_all + 256, *ac2 = ac_all + 512, *ac3 = ac_all + 768;

    hipMemsetAsync(stats_part, 0, 4 * NSLOT * 256 * sizeof(float), stream);
    hipMemsetAsync(degi, 0, (size_t)n * sizeof(int), stream);

    local_means_kernel<<<1, 256, 0, stream>>>(local_x, local_type, means, nl);
    hist_kernel<<<cdiv(E, 256), 256, 0, stream>>>(dst, degi, E);
    scan_part1_kernel<<<nb, 256, 0, stream>>>(degi, blocksums, n);
    scan_part2_kernel<<<1, 256, 0, stream>>>(blocksums, nb);
    scan_part3_kernel<<<nb, 256, 0, stream>>>(degi, blocksums, rowptr, cursor, dinv, n, E);
    fill_kernel<<<cdiv(E, 256), 256, 0, stream>>>(src, dst, cursor, esrc, E);
    build_x0_kernel<<<cdiv((long long)n * 32, 256), 256, 0, stream>>>(means, voxel_type, voxel_x, label, B, n);

    const int gagg = 2048;

    // encoder: B(32) -> A(128) -> B(128)   [all f32]
    mlp_kernel<32, 128, 128, 8, true, true, false, false, false><<<cdiv(n, 128), 256, 0, stream>>>(B, A, We1, be1, nullptr, nullptr, n);
    mlp_kernel<128, 128, 128, 8, true, true, false, false, false><<<cdiv(n, 128), 256, 0, stream>>>(A, B, We2, be2, nullptr, nullptr, n);

    // conv0 (128->64, agg post-GEMM): B -> Y(bf16, dinv-scaled) -> agg A2(f32) [+stats0]
    mlp_kernel<128, 64, 256, 8, false, false, false, true, true><<<cdiv(n, 256), 256, 0, stream>>>(B, Y, Wc[0], nullptr, nullptr, dinv, n);
    gather_agg_kernel<64><<<gagg, 256, 0, stream>>>(Y, A2, rowptr, esrc, dinv, bc[0], part0, n);
    gn_finalize_kernel<64><<<1, 64, 0, stream>>>(part0, ac0, gw[0], gb[0], gm[0], inv_n);

    // conv1 (64->32, agg post-GEMM): A2(+GN) -> Y(bf16 32w) -> agg B2(f32) [+stats1]
    mlp_kernel<64, 32, 256, 4, false, false, true, true, true><<<cdiv(n, 256), 256, 0, stream>>>(A2, Y, Wc[1], nullptr, ac0, dinv, n);
    gather_agg_kernel<32><<<gagg, 256, 0, stream>>>(Y, B2, rowptr, esrc, dinv, bc[1], part1, n);
    gn_finalize_kernel<32><<<1, 32, 0, stream>>>(part1, ac1, gw[1], gb[1], gm[1], inv_n);

    // conv2 (32->64, agg PRE-GEMM): B2(+GN) -> Y(bf16 32w) -> agg A(f32 32w) -> GEMM A2(64) -> stats2
    transform_kernel<32><<<cdiv((long long)n * 4, 256), 256, 0, stream>>>(B2, Y, ac1, dinv, n);
    gather_pre_kernel<32><<<gagg, 256, 0, stream>>>(Y, A, rowptr, esrc, dinv, n);
    mlp_kernel<32, 64, 256, 8, false, true, false, false, false><<<cdiv(n, 256), 256, 0, stream>>>(A, A2, Wc[2], bc[2], nullptr, nullptr, n);
    gn_stats_kernel<64><<<cdiv(n, 512), 256, 0, stream>>>(A2, part2, n);
    gn_finalize_kernel<64><<<1, 64, 0, stream>>>(part2, ac2, gw[2], gb[2], gm[2], inv_n);

    // conv3 (64->128, agg PRE-GEMM): A2(+GN) -> Y(bf16 64w) -> agg B(f32 64w) -> GEMM A(128) -> stats3
    transform_kernel<64><<<cdiv((long long)n * 8, 256), 256, 0, stream>>>(A2, Y, ac2, dinv, n);
    gather_pre_kernel<64><<<gagg, 256, 0, stream>>>(Y, B, rowptr, esrc, dinv, n);
    mlp_kernel<64, 128, 128, 8, false, true, false, false, false><<<cdiv(n, 128), 256, 0, stream>>>(B, A, Wc[3], bc[3], nullptr, nullptr, n);
    gn_stats_kernel<128><<<cdiv(n, 256), 256, 0, stream>>>(A, part3, n);
    gn_finalize_kernel<128><<<1, 128, 0, stream>>>(part3, ac3, gw[3], gb[3], gm[3], inv_n);

    // decoder: A(128,+GN) -> B(64) -> fused tail -> out
    mlp_kernel<128, 64, 256, 8, true, true, true, false, false><<<cdiv(n, 256), 256, 0, stream>>>(A, B, Wd0, bd0, ac3, nullptr, n);
    dec_tail_kernel<<<cdiv(n, 256), 256, 0, stream>>>(B, Wd1, bd1, Wd2, bd2, Wd3, bd3, (float*)d_out, n);
}

// Round 12
// 732.560 us; speedup vs baseline: 1.2015x; 1.2015x over previous
//
#include <hip/hip_runtime.h>
#include <hip/hip_bf16.h>
#include <cstddef>

#define THREADS 256
#define NSLOT 64

typedef unsigned short ushort_t;
typedef unsigned int uint_t;
typedef __attribute__((ext_vector_type(8))) short bf16x8;
typedef __attribute__((ext_vector_type(4))) float f32x4;

__device__ __forceinline__ ushort_t f2b(float f) {
    uint_t i = __float_as_uint(f);
    uint_t r = i + 0x7fffu + ((i >> 16) & 1u);
    return (ushort_t)(r >> 16);
}

// ---------------- small kernels ----------------

__global__ __launch_bounds__(256) void local_means_kernel(const float* __restrict__ lx,
                                                          const int* __restrict__ lt,
                                                          float* __restrict__ means, int nl)
{
    __shared__ float slx[512 * 19];
    __shared__ int   slt[512];
    const int tid = threadIdx.x;
    for (int i = tid; i < nl * 19; i += 256) slx[i] = lx[i];
    for (int i = tid; i < nl; i += 256) slt[i] = lt[i];
    __syncthreads();
    if (tid >= 7 * 19) return;
    int c = tid / 19, dd = tid % 19;
    float s = 0.f; int cnt = 0;
    for (int i = 0; i < nl; ++i) {
        if (slt[i] == c) { s += slx[i * 19 + dd]; cnt++; }
    }
    means[tid] = cnt > 0 ? s / (float)cnt : 0.f;
}

__global__ void hist_kernel(const int* __restrict__ dst, int* __restrict__ degi, int E)
{
    int t = blockIdx.x * THREADS + threadIdx.x;
    if (t < E) atomicAdd(&degi[dst[t]], 1);
}

__global__ __launch_bounds__(256) void scan_part1_kernel(const int* __restrict__ degi,
                                                         int* __restrict__ blocksums, int n)
{
    const int tid = threadIdx.x;
    const int idx = blockIdx.x * 1024 + tid * 4;
    int v = 0;
    if (idx + 3 < n) {
        int4 d = *(const int4*)&degi[idx];
        v = d.x + d.y + d.z + d.w;
    } else {
        for (int i = 0; i < 4; ++i) if (idx + i < n) v += degi[idx + i];
    }
    __shared__ int s[256];
    s[tid] = v;
    __syncthreads();
    for (int off = 128; off >= 1; off >>= 1) {
        if (tid < off) s[tid] += s[tid + off];
        __syncthreads();
    }
    if (tid == 0) blocksums[blockIdx.x] = s[0];
}

__global__ __launch_bounds__(256) void scan_part2_kernel(int* __restrict__ blocksums, int nb)
{
    __shared__ int s[256];
    const int tid = threadIdx.x;
    int v = (tid < nb) ? blocksums[tid] : 0;
    s[tid] = v;
    __syncthreads();
    for (int off = 1; off < 256; off <<= 1) {
        int t = (tid >= off) ? s[tid - off] : 0;
        __syncthreads();
        s[tid] += t;
        __syncthreads();
    }
    if (tid < nb) blocksums[tid] = s[tid] - v;
}

__global__ __launch_bounds__(256) void scan_part3_kernel(const int* __restrict__ degi,
                                                         const int* __restrict__ blocksums,
                                                         int* __restrict__ rowptr,
                                                         int* __restrict__ cursor,
                                                         float* __restrict__ dinv, int n, int E)
{
    const int tid = threadIdx.x;
    const int idx = blockIdx.x * 1024 + tid * 4;
    int d0 = 0, d1 = 0, d2 = 0, d3 = 0;
    if (idx + 3 < n) {
        int4 d = *(const int4*)&degi[idx];
        d0 = d.x; d1 = d.y; d2 = d.z; d3 = d.w;
    } else {
        if (idx     < n) d0 = degi[idx];
        if (idx + 1 < n) d1 = degi[idx + 1];
        if (idx + 2 < n) d2 = degi[idx + 2];
        if (idx + 3 < n) d3 = degi[idx + 3];
    }
    const int v = d0 + d1 + d2 + d3;
    __shared__ int s[256];
    s[tid] = v;
    __syncthreads();
    for (int off = 1; off < 256; off <<= 1) {
        int t = (tid >= off) ? s[tid - off] : 0;
        __syncthreads();
        s[tid] += t;
        __syncthreads();
    }
    int run = blocksums[blockIdx.x] + s[tid] - v;
    if (idx + 3 < n) {
        int4 o;
        o.x = run; run += d0;
        o.y = run; run += d1;
        o.z = run; run += d2;
        o.w = run;
        *(int4*)&rowptr[idx] = o;
        *(int4*)&cursor[idx] = o;
        float4 dv;
        dv.x = rsqrtf((float)d0 + 1.0f);
        dv.y = rsqrtf((float)d1 + 1.0f);
        dv.z = rsqrtf((float)d2 + 1.0f);
        dv.w = rsqrtf((float)d3 + 1.0f);
        *(float4*)&dinv[idx] = dv;
    } else {
        if (idx     < n) { rowptr[idx]     = run; cursor[idx]     = run; dinv[idx]     = rsqrtf((float)d0 + 1.0f); run += d0; }
        if (idx + 1 < n) { rowptr[idx + 1] = run; cursor[idx + 1] = run; dinv[idx + 1] = rsqrtf((float)d1 + 1.0f); run += d1; }
        if (idx + 2 < n) { rowptr[idx + 2] = run; cursor[idx + 2] = run; dinv[idx + 2] = rsqrtf((float)d2 + 1.0f); run += d2; }
        if (idx + 3 < n) { rowptr[idx + 3] = run; cursor[idx + 3] = run; dinv[idx + 3] = rsqrtf((float)d3 + 1.0f); }
    }
    if (blockIdx.x == 0 && tid == 0) rowptr[n] = E;
}

__global__ void fill_kernel(const int* __restrict__ src, const int* __restrict__ dst,
                            int* __restrict__ cursor, int* __restrict__ esrc, int E)
{
    int t = blockIdx.x * THREADS + threadIdx.x;
    if (t >= E) return;
    int s = src[t], d = dst[t];
    int pos = atomicAdd(&cursor[d], 1);
    esrc[pos] = s;
}

__global__ void build_x0_kernel(const float* __restrict__ means,
                                const int* __restrict__ vt,
                                const float* __restrict__ vx,
                                const float* __restrict__ label,
                                float* __restrict__ out, int n)
{
    int tid = blockIdx.x * THREADS + threadIdx.x;
    int node = tid >> 5, c = tid & 31;
    if (node >= n) return;
    float v;
    if (c < 19)      v = means[vt[node] * 19 + c];
    else if (c < 25) v = vx[node * 6 + (c - 19)];
    else             v = label[node * 7 + (c - 25)];
    out[(size_t)node * 32 + c] = v;
}

// ---------------- elementwise GN-affine + ReLU + dinv row-scale (f32 -> f32) ----
template<int D>
__global__ void transform_kernel(const float* __restrict__ x, float* __restrict__ out,
                                 const float* __restrict__ tr, const float* __restrict__ dinv, int n)
{
    constexpr int Q = D / 4;
    int t = blockIdx.x * THREADS + threadIdx.x;
    int node = t / Q, q = t % Q;
    if (node >= n) return;
    float4 v = *(const float4*)&x[(size_t)node * D + q * 4];
    const float4 a = *(const float4*)&tr[q * 4];
    const float4 c = *(const float4*)&tr[D + q * 4];
    const float dd = dinv[node];
    float4 o;
    o.x = fmaxf(fmaf(v.x, a.x, c.x), 0.f) * dd;
    o.y = fmaxf(fmaf(v.y, a.y, c.y), 0.f) * dd;
    o.z = fmaxf(fmaf(v.z, a.z, c.z), 0.f) * dd;
    o.w = fmaxf(fmaf(v.w, a.w, c.w), 0.f) * dd;
    *(float4*)&out[(size_t)node * D + q * 4] = o;
}

// ---------------- f32 dense layer (split-J, proven 812-baseline form) ----------------
template<int DIN, int DOUT, int BN, int JPER, bool RELU, bool BIAS, bool TRANSFORM, bool SCALE>
__global__ __launch_bounds__(256) void mlp_kernel(
    const float* __restrict__ in, float* __restrict__ out,
    const float* __restrict__ W, const float* __restrict__ bias,
    const float* __restrict__ tr, const float* __restrict__ rowscale, int n)
{
    constexpr int KT  = 32;
    constexpr int TJ  = DOUT / JPER;
    constexpr int TN  = 256 / TJ;
    constexpr int NPT = BN / TN;
    constexpr int JQ  = JPER / 4;
    constexpr int CS  = 4 * TJ;
    constexpr int BNP = BN + 4;

    __shared__ float Wt[KT * DOUT];
    __shared__ float xT[KT][BNP];

    const int tid   = threadIdx.x;
    const int nbase = blockIdx.x * BN;
    const int tj = tid % TJ, tn = tid / TJ;
    const int j0 = tj * 4, n0 = tn * NPT;

    float acc[NPT][JPER];
#pragma unroll
    for (int p = 0; p < NPT; ++p)
#pragma unroll
        for (int j = 0; j < JPER; ++j) acc[p][j] = 0.f;

    for (int kt = 0; kt < DIN; kt += KT) {
        __syncthreads();
        for (int i = tid * 4; i < KT * DOUT; i += THREADS * 4) {
            *(float4*)&Wt[i] = *(const float4*)&W[(size_t)kt * DOUT + i];
        }
        for (int i = tid; i < BN * (KT / 4); i += THREADS) {
            int node = i / (KT / 4);
            int kq   = i % (KT / 4);
            int g    = nbase + node;
            float4 v = make_float4(0.f, 0.f, 0.f, 0.f);
            if (g < n) {
                v = *(const float4*)&in[(size_t)g * DIN + kt + kq * 4];
                if (TRANSFORM) {
                    const float4 a = *(const float4*)&tr[kt + kq * 4];
                    const float4 c = *(const float4*)&tr[DIN + kt + kq * 4];
                    v.x = fmaxf(fmaf(v.x, a.x, c.x), 0.f);
                    v.y = fmaxf(fmaf(v.y, a.y, c.y), 0.f);
                    v.z = fmaxf(fmaf(v.z, a.z, c.z), 0.f);
                    v.w = fmaxf(fmaf(v.w, a.w, c.w), 0.f);
                }
            }
            xT[kq * 4 + 0][node] = v.x;
            xT[kq * 4 + 1][node] = v.y;
            xT[kq * 4 + 2][node] = v.z;
            xT[kq * 4 + 3][node] = v.w;
        }
        __syncthreads();
#pragma unroll 4
        for (int kk = 0; kk < KT; ++kk) {
            float wv[JPER];
#pragma unroll
            for (int q = 0; q < JQ; ++q)
                *(float4*)&wv[q * 4] = *(const float4*)&Wt[kk * DOUT + q * CS + j0];
            float xv[NPT];
#pragma unroll
            for (int q = 0; q < NPT / 4; ++q)
                *(float4*)&xv[q * 4] = *(const float4*)&xT[kk][n0 + q * 4];
#pragma unroll
            for (int p = 0; p < NPT; ++p)
#pragma unroll
                for (int j = 0; j < JPER; ++j)
                    acc[p][j] = fmaf(xv[p], wv[j], acc[p][j]);
        }
    }

    float bv[JPER];
#pragma unroll
    for (int j = 0; j < JPER; ++j) bv[j] = 0.f;
    if (BIAS) {
#pragma unroll
        for (int q = 0; q < JQ; ++q)
            *(float4*)&bv[q * 4] = *(const float4*)&bias[q * CS + j0];
    }

#pragma unroll
    for (int p = 0; p < NPT; ++p) {
        const int g = nbase + n0 + p;
        if (g >= n) continue;
        float rs = 1.f;
        if (SCALE) rs = rowscale[g];
#pragma unroll
        for (int q = 0; q < JQ; ++q) {
            float4 o;
            o.x = acc[p][q * 4 + 0] + bv[q * 4 + 0];
            o.y = acc[p][q * 4 + 1] + bv[q * 4 + 1];
            o.z = acc[p][q * 4 + 2] + bv[q * 4 + 2];
            o.w = acc[p][q * 4 + 3] + bv[q * 4 + 3];
            if (RELU) {
                o.x = fmaxf(o.x, 0.f); o.y = fmaxf(o.y, 0.f);
                o.z = fmaxf(o.z, 0.f); o.w = fmaxf(o.w, 0.f);
            }
            if (SCALE) { o.x *= rs; o.y *= rs; o.z *= rs; o.w *= rs; }
            *(float4*)&out[(size_t)g * DOUT + q * CS + j0] = o;
        }
    }
}

// ---------------- bf16-MFMA dense layer (f32 io, bf16 operands, f32 accum) -------------
// A-frag: lane l holds x[row=l&15][k=(l>>4)*8+j]; B-frag: W^T[col=l&15][k=(l>>4)*8+j];
// C/D: col=lane&15, row=(lane>>4)*4+reg  [m89-verified mapping]
template<int DIN, int DOUT, bool RELU, bool BIAS, bool TRANSFORM, bool SCALE>
__global__ __launch_bounds__(256) void mfma_mlp_kernel(
    const float* __restrict__ in, float* __restrict__ out,
    const float* __restrict__ W, const float* __restrict__ bias,
    const float* __restrict__ tr, const float* __restrict__ rowscale, int n)
{
    constexpr int BN  = 128;
    constexpr int KT  = 32;
    constexpr int NT  = DIN / KT;
    constexpr int LDK = 40;            // bf16 row stride: 80B, 16B-aligned, 2-way banks
    constexpr int WM  = 2, WN = 2;
    constexpr int MW  = BN / WM;       // 64
    constexpr int NW  = DOUT / WN;     // 64 or 32
    constexpr int MR  = MW / 16;       // 4
    constexpr int NR  = NW / 16;       // 4 or 2

    __shared__ ushort_t xA[BN * LDK];
    __shared__ ushort_t wB[DOUT * LDK];

    const int tid   = threadIdx.x;
    const int wid   = tid >> 6;
    const int lane  = tid & 63;
    const int wm    = wid >> 1, wn = wid & 1;
    const int nbase = blockIdx.x * BN;
    const int l16   = lane & 15;
    const int lk8   = (lane >> 4) * 8;

    f32x4 acc[MR][NR];
#pragma unroll
    for (int mi = 0; mi < MR; ++mi)
#pragma unroll
        for (int ni = 0; ni < NR; ++ni)
#pragma unroll
            for (int j = 0; j < 4; ++j) acc[mi][ni][j] = 0.f;

    for (int t = 0; t < NT; ++t) {
        const int kt = t * KT;
        __syncthreads();
        // stage x tile: [BN][KT] f32 -> bf16, k-contiguous
        for (int i = tid; i < BN * (KT / 4); i += 256) {
            const int row = i / (KT / 4);
            const int kq  = (i % (KT / 4)) * 4;
            const int g   = nbase + row;
            float4 v = make_float4(0.f, 0.f, 0.f, 0.f);
            if (g < n) {
                v = *(const float4*)&in[(size_t)g * DIN + kt + kq];
                if (TRANSFORM) {
                    const float4 a = *(const float4*)&tr[kt + kq];
                    const float4 c = *(const float4*)&tr[DIN + kt + kq];
                    v.x = fmaxf(fmaf(v.x, a.x, c.x), 0.f);
                    v.y = fmaxf(fmaf(v.y, a.y, c.y), 0.f);
                    v.z = fmaxf(fmaf(v.z, a.z, c.z), 0.f);
                    v.w = fmaxf(fmaf(v.w, a.w, c.w), 0.f);
                }
            }
            ushort4 b;
            b.x = f2b(v.x); b.y = f2b(v.y); b.z = f2b(v.z); b.w = f2b(v.w);
            *(ushort4*)&xA[row * LDK + kq] = b;
        }
        // stage W^T tile: read W[k][c..c+3] coalesced, write wB[c][k]
        for (int i = tid; i < (KT * DOUT) / 4; i += 256) {
            const int k = (i * 4) / DOUT;
            const int c = (i * 4) % DOUT;
            float4 v = *(const float4*)&W[(size_t)(kt + k) * DOUT + c];
            wB[(c + 0) * LDK + k] = f2b(v.x);
            wB[(c + 1) * LDK + k] = f2b(v.y);
            wB[(c + 2) * LDK + k] = f2b(v.z);
            wB[(c + 3) * LDK + k] = f2b(v.w);
        }
        __syncthreads();

        bf16x8 af[MR], bf[NR];
#pragma unroll
        for (int mi = 0; mi < MR; ++mi)
            af[mi] = *(const bf16x8*)&xA[(wm * MW + mi * 16 + l16) * LDK + lk8];
#pragma unroll
        for (int ni = 0; ni < NR; ++ni)
            bf[ni] = *(const bf16x8*)&wB[(wn * NW + ni * 16 + l16) * LDK + lk8];
#pragma unroll
        for (int mi = 0; mi < MR; ++mi)
#pragma unroll
            for (int ni = 0; ni < NR; ++ni)
                acc[mi][ni] = __builtin_amdgcn_mfma_f32_16x16x32_bf16(
                    af[mi], bf[ni], acc[mi][ni], 0, 0, 0);
    }

    float bv[NR];
#pragma unroll
    for (int ni = 0; ni < NR; ++ni)
        bv[ni] = BIAS ? bias[wn * NW + ni * 16 + l16] : 0.f;

#pragma unroll
    for (int mi = 0; mi < MR; ++mi) {
#pragma unroll
        for (int j = 0; j < 4; ++j) {
            const int r = wm * MW + mi * 16 + (lane >> 4) * 4 + j;
            const int g = nbase + r;
            if (g >= n) continue;
            float rs = 1.f;
            if (SCALE) rs = rowscale[g];
#pragma unroll
            for (int ni = 0; ni < NR; ++ni) {
                const int col = wn * NW + ni * 16 + l16;
                float v = acc[mi][ni][j] + bv[ni];
                if (RELU) v = fmaxf(v, 0.f);
                if (SCALE) v *= rs;
                out[(size_t)g * DOUT + col] = v;
            }
        }
    }
}

// ---------------- CSR gather aggregation (post-GEMM), f32 table, fused bias+stats ----
template<int D>
__global__ __launch_bounds__(256) void gather_agg_kernel(
    const float* __restrict__ y, float* __restrict__ out,
    const int* __restrict__ rowptr, const int* __restrict__ esrc,
    const float* __restrict__ dinv,
    const float* __restrict__ bias, float* __restrict__ statsP, int n)
{
    constexpr int JT  = D / 8;
    constexpr int NPB = 256 / JT;
    const int tid  = threadIdx.x;
    const int jq   = tid % JT;
    const int nsub = tid / JT;
    const int j0   = jq * 8;

    float bv[8];
#pragma unroll
    for (int e = 0; e < 8; ++e) bv[e] = bias[j0 + e];

    float s1[8], s2[8];
#pragma unroll
    for (int e = 0; e < 8; ++e) { s1[e] = 0.f; s2[e] = 0.f; }

    const int ntiles = (n + NPB - 1) / NPB;
    for (int tile = blockIdx.x; tile < ntiles; tile += gridDim.x) {
        const int node = tile * NPB + nsub;
        if (node < n) {
            const int rb = rowptr[node], re = rowptr[node + 1];
            const float dd = dinv[node];
            float acc[8];
            *(float4*)&acc[0] = *(const float4*)&y[(size_t)node * D + j0];
            *(float4*)&acc[4] = *(const float4*)&y[(size_t)node * D + j0 + 4];
            int k = rb;
            for (; k + 1 < re; k += 2) {
                const int sa = esrc[k], sb = esrc[k + 1];
                float4 a0 = *(const float4*)&y[(size_t)sa * D + j0];
                float4 a1 = *(const float4*)&y[(size_t)sa * D + j0 + 4];
                float4 b0 = *(const float4*)&y[(size_t)sb * D + j0];
                float4 b1 = *(const float4*)&y[(size_t)sb * D + j0 + 4];
                acc[0] += a0.x + b0.x; acc[1] += a0.y + b0.y;
                acc[2] += a0.z + b0.z; acc[3] += a0.w + b0.w;
                acc[4] += a1.x + b1.x; acc[5] += a1.y + b1.y;
                acc[6] += a1.z + b1.z; acc[7] += a1.w + b1.w;
            }
            if (k < re) {
                const int sa = esrc[k];
                float4 a0 = *(const float4*)&y[(size_t)sa * D + j0];
                float4 a1 = *(const float4*)&y[(size_t)sa * D + j0 + 4];
                acc[0] += a0.x; acc[1] += a0.y; acc[2] += a0.z; acc[3] += a0.w;
                acc[4] += a1.x; acc[5] += a1.y; acc[6] += a1.z; acc[7] += a1.w;
            }
            float o[8];
#pragma unroll
            for (int e = 0; e < 8; ++e) {
                o[e] = fmaf(acc[e], dd, bv[e]);
                s1[e] += o[e];
                s2[e] = fmaf(o[e], o[e], s2[e]);
            }
            *(float4*)&out[(size_t)node * D + j0]     = make_float4(o[0], o[1], o[2], o[3]);
            *(float4*)&out[(size_t)node * D + j0 + 4] = make_float4(o[4], o[5], o[6], o[7]);
        }
    }

    __shared__ float red[256][17];
#pragma unroll
    for (int e = 0; e < 8; ++e) { red[tid][e] = s1[e]; red[tid][8 + e] = s2[e]; }
    __syncthreads();
#pragma unroll
    for (int off = NPB / 2; off >= 1; off >>= 1) {
        if (nsub < off) {
#pragma unroll
            for (int e = 0; e < 16; ++e) red[tid][e] += red[tid + off * JT][e];
        }
        __syncthreads();
    }
    if (nsub == 0) {
        float* slot = statsP + (size_t)(blockIdx.x & (NSLOT - 1)) * 256;
#pragma unroll
        for (int e = 0; e < 8; ++e) {
            atomicAdd(&slot[j0 + e],     red[tid][e]);
            atomicAdd(&slot[D + j0 + e], red[tid][8 + e]);
        }
    }
}

// ---------------- CSR gather aggregation (pre-GEMM), f32 table ----------------
template<int D>
__global__ __launch_bounds__(256) void gather_pre_kernel(
    const float* __restrict__ x, float* __restrict__ out,
    const int* __restrict__ rowptr, const int* __restrict__ esrc,
    const float* __restrict__ dinv, int n)
{
    constexpr int JT  = D / 8;
    constexpr int NPB = 256 / JT;
    const int tid  = threadIdx.x;
    const int jq   = tid % JT;
    const int nsub = tid / JT;
    const int j0   = jq * 8;

    const int ntiles = (n + NPB - 1) / NPB;
    for (int tile = blockIdx.x; tile < ntiles; tile += gridDim.x) {
        const int node = tile * NPB + nsub;
        if (node < n) {
            const int rb = rowptr[node], re = rowptr[node + 1];
            const float dd = dinv[node];
            float acc[8];
            *(float4*)&acc[0] = *(const float4*)&x[(size_t)node * D + j0];
            *(float4*)&acc[4] = *(const float4*)&x[(size_t)node * D + j0 + 4];
            int k = rb;
            for (; k + 1 < re; k += 2) {
                const int sa = esrc[k], sb = esrc[k + 1];
                float4 a0 = *(const float4*)&x[(size_t)sa * D + j0];
                float4 a1 = *(const float4*)&x[(size_t)sa * D + j0 + 4];
                float4 b0 = *(const float4*)&x[(size_t)sb * D + j0];
                float4 b1 = *(const float4*)&x[(size_t)sb * D + j0 + 4];
                acc[0] += a0.x + b0.x; acc[1] += a0.y + b0.y;
                acc[2] += a0.z + b0.z; acc[3] += a0.w + b0.w;
                acc[4] += a1.x + b1.x; acc[5] += a1.y + b1.y;
                acc[6] += a1.z + b1.z; acc[7] += a1.w + b1.w;
            }
            if (k < re) {
                const int sa = esrc[k];
                float4 a0 = *(const float4*)&x[(size_t)sa * D + j0];
                float4 a1 = *(const float4*)&x[(size_t)sa * D + j0 + 4];
                acc[0] += a0.x; acc[1] += a0.y; acc[2] += a0.z; acc[3] += a0.w;
                acc[4] += a1.x; acc[5] += a1.y; acc[6] += a1.z; acc[7] += a1.w;
            }
            float4 o0 = make_float4(acc[0] * dd, acc[1] * dd, acc[2] * dd, acc[3] * dd);
            float4 o1 = make_float4(acc[4] * dd, acc[5] * dd, acc[6] * dd, acc[7] * dd);
            *(float4*)&out[(size_t)node * D + j0]     = o0;
            *(float4*)&out[(size_t)node * D + j0 + 4] = o1;
        }
    }
}

// ---------------- standalone column stats (f32 in) -> slots ----------------
template<int D>
__global__ __launch_bounds__(256) void gn_stats_kernel(const float* __restrict__ x,
                                                       float* __restrict__ statsP, int n)
{
    constexpr int JT   = D / 4;
    constexpr int NPB  = 256 / JT;
    constexpr int ITER = 32;
    const int tid  = threadIdx.x;
    const int jb   = tid % JT;
    const int rsub = tid / JT;
    const int j0   = jb * 4;
    const int base = blockIdx.x * NPB * ITER;

    float s1[4] = {0.f, 0.f, 0.f, 0.f};
    float s2[4] = {0.f, 0.f, 0.f, 0.f};

#pragma unroll 4
    for (int i = 0; i < ITER; ++i) {
        int r = base + rsub + i * NPB;
        if (r < n) {
            float4 v = *(const float4*)&x[(size_t)r * D + j0];
            s1[0] += v.x; s1[1] += v.y; s1[2] += v.z; s1[3] += v.w;
            s2[0] = fmaf(v.x, v.x, s2[0]);
            s2[1] = fmaf(v.y, v.y, s2[1]);
            s2[2] = fmaf(v.z, v.z, s2[2]);
            s2[3] = fmaf(v.w, v.w, s2[3]);
        }
    }

    __shared__ float red[256][9];
#pragma unroll
    for (int e = 0; e < 4; ++e) { red[tid][e] = s1[e]; red[tid][4 + e] = s2[e]; }
    __syncthreads();
#pragma unroll
    for (int off = NPB / 2; off >= 1; off >>= 1) {
        if (rsub < off) {
#pragma unroll
            for (int e = 0; e < 8; ++e) red[tid][e] += red[tid + off * JT][e];
        }
        __syncthreads();
    }
    if (rsub == 0) {
        float* slot = statsP + (size_t)(blockIdx.x & (NSLOT - 1)) * 256;
#pragma unroll
        for (int e = 0; e < 4; ++e) {
            atomicAdd(&slot[j0 + e],     red[tid][e]);
            atomicAdd(&slot[D + j0 + e], red[tid][4 + e]);
        }
    }
}

template<int D>
__global__ void gn_finalize_kernel(const float* __restrict__ part, float* __restrict__ ac,
                                   const float* __restrict__ gw, const float* __restrict__ gb,
                                   const float* __restrict__ gm, float inv_n)
{
    int j = threadIdx.x;
    if (j >= D) return;
    float s1 = 0.f, s2 = 0.f;
    for (int t = 0; t < NSLOT; ++t) {
        s1 += part[(size_t)t * 256 + j];
        s2 += part[(size_t)t * 256 + D + j];
    }
    float mean = s1 * inv_n;
    float ex2  = s2 * inv_n;
    float m    = gm[j];
    float var  = ex2 - (2.f * m - m * m) * mean * mean;
    float a    = gw[j] * rsqrtf(var + 1e-5f);
    float c    = gb[j] - a * m * mean;
    ac[j]     = a;
    ac[D + j] = c;
}

// ---------------- fused decoder tail: 64 -> relu32 -> relu16 -> sigmoid(1) ----------------
__global__ __launch_bounds__(256) void dec_tail_kernel(
    const float* __restrict__ in, const float* __restrict__ W1, const float* __restrict__ b1,
    const float* __restrict__ W2, const float* __restrict__ b2,
    const float* __restrict__ W3, const float* __restrict__ b3,
    float* __restrict__ out, int n)
{
    int t = blockIdx.x * THREADS + threadIdx.x;
    if (t >= n) return;

    float x[64];
#pragma unroll
    for (int q = 0; q < 16; ++q)
        *(float4*)&x[q * 4] = *(const float4*)&in[(size_t)t * 64 + q * 4];

    float h1[32];
#pragma unroll
    for (int j = 0; j < 32; ++j) h1[j] = b1[j];
#pragma unroll 8
    for (int k = 0; k < 64; ++k) {
        const float xk = x[k];
#pragma unroll
        for (int j = 0; j < 32; ++j) h1[j] = fmaf(xk, W1[k * 32 + j], h1[j]);
    }
#pragma unroll
    for (int j = 0; j < 32; ++j) h1[j] = fmaxf(h1[j], 0.f);

    float h2[16];
#pragma unroll
    for (int j = 0; j < 16; ++j) h2[j] = b2[j];
#pragma unroll 8
    for (int k = 0; k < 32; ++k) {
        const float hk = h1[k];
#pragma unroll
        for (int j = 0; j < 16; ++j) h2[j] = fmaf(hk, W2[k * 16 + j], h2[j]);
    }

    float acc = b3[0];
#pragma unroll
    for (int k = 0; k < 16; ++k) acc = fmaf(fmaxf(h2[k], 0.f), W3[k], acc);
    out[t] = 1.0f / (1.0f + expf(-acc));
}

// ---------------- launch ----------------

extern "C" void kernel_launch(void* const* d_in, const int* in_sizes, int n_in,
                              void* d_out, int out_size, void* d_ws, size_t ws_size,
                              hipStream_t stream)
{
    const float* local_x    = (const float*)d_in[0];
    const int*   local_type = (const int*)d_in[1];
    const float* voxel_x    = (const float*)d_in[2];
    const int*   voxel_type = (const int*)d_in[3];
    const int*   edge_index = (const int*)d_in[4];
    const float* label      = (const float*)d_in[5];
    const float* We1 = (const float*)d_in[6],  *be1 = (const float*)d_in[7];
    const float* We2 = (const float*)d_in[8],  *be2 = (const float*)d_in[9];
    const float *Wc[4], *bc[4], *gw[4], *gb[4], *gm[4];
    for (int i = 0; i < 4; ++i) {
        Wc[i] = (const float*)d_in[10 + i * 5];
        bc[i] = (const float*)d_in[11 + i * 5];
        gw[i] = (const float*)d_in[12 + i * 5];
        gb[i] = (const float*)d_in[13 + i * 5];
        gm[i] = (const float*)d_in[14 + i * 5];
    }
    const float* Wd0 = (const float*)d_in[30], *bd0 = (const float*)d_in[31];
    const float* Wd1 = (const float*)d_in[32], *bd1 = (const float*)d_in[33];
    const float* Wd2 = (const float*)d_in[34], *bd2 = (const float*)d_in[35];
    const float* Wd3 = (const float*)d_in[36], *bd3 = (const float*)d_in[37];

    const int n  = in_sizes[2] / 6;    // 200000
    const int E  = in_sizes[4] / 2;    // 1200000
    const int nl = in_sizes[0] / 19;   // 400
    const int* src = edge_index;
    const int* dst = edge_index + E;

    // Workspace (~212 MB): [ac][means][blocksums][stats_part][rowptr][dinv][esrc]
    // [A f32 n*128][B f32 n*128]; all activations/tables live in A/B halves.
    auto align256 = [](size_t x) { return (x + 255) & ~(size_t)255; };
    char* w = (char*)d_ws;
    float* ac_all = (float*)w;
    float* means  = (float*)(w + 4096);
    int* blocksums = (int*)(w + 8192);
    float* stats_part = (float*)(w + 8192 + 1024);
    size_t off = 8192 + 1024 + 4 * NSLOT * 256 * sizeof(float);
    int*   rowptr = (int*)(w + off);   off += align256((size_t)(n + 1) * 4);
    float* dinv   = (float*)(w + off); off += align256((size_t)n * 4);
    int*   esrc   = (int*)(w + off);   off += align256((size_t)E * 4);
    float* A    = (float*)(w + off);
    float* B    = A + (size_t)n * 128;
    float* A_lo = A;                      // n*64 view
    float* A_hi = A + (size_t)n * 64;
    float* B_lo = B;
    float* B_hi = B + (size_t)n * 64;
    int*   degi   = (int*)A;              // transient alias (pre-enc1 only)
    int*   cursor = (int*)A_hi;           // transient alias

    const float inv_n = 1.0f / (float)n;
    auto cdiv = [](long long a, long long b) { return (int)((a + b - 1) / b); };
    const int nb = cdiv(n, 1024);

    float* part0 = stats_part + 0 * NSLOT * 256;
    float* part1 = stats_part + 1 * NSLOT * 256;
    float* part2 = stats_part + 2 * NSLOT * 256;
    float* part3 = stats_part + 3 * NSLOT * 256;
    float* ac0 = ac_all + 0, *ac1 = ac_all + 256, *ac2 = ac_all + 512, *ac3 = ac_all + 768;

    hipMemsetAsync(stats_part, 0, 4 * NSLOT * 256 * sizeof(float), stream);
    hipMemsetAsync(degi, 0, (size_t)n * sizeof(int), stream);

    local_means_kernel<<<1, 256, 0, stream>>>(local_x, local_type, means, nl);
    hist_kernel<<<cdiv(E, 256), 256, 0, stream>>>(dst, degi, E);
    scan_part1_kernel<<<nb, 256, 0, stream>>>(degi, blocksums, n);
    scan_part2_kernel<<<1, 256, 0, stream>>>(blocksums, nb);
    scan_part3_kernel<<<nb, 256, 0, stream>>>(degi, blocksums, rowptr, cursor, dinv, n, E);
    fill_kernel<<<cdiv(E, 256), 256, 0, stream>>>(src, dst, cursor, esrc, E);
    build_x0_kernel<<<cdiv((long long)n * 32, 256), 256, 0, stream>>>(means, voxel_type, voxel_x, label, B_lo, n);

    const int gagg  = 2048;
    const int gmfma = cdiv(n, 128);

    // enc1 (f32): X0=B_lo(32w) -> A(128)
    mlp_kernel<32, 128, 128, 8, true, true, false, false><<<cdiv(n, 128), 256, 0, stream>>>(B_lo, A, We1, be1, nullptr, nullptr, n);
    // enc2 (MFMA): A -> B
    mfma_mlp_kernel<128, 128, true, true, false, false><<<gmfma, 256, 0, stream>>>(A, B, We2, be2, nullptr, nullptr, n);

    // conv0: (MFMA) B -> T0=A_lo(64w, dinv-scaled); gather -> A_hi [+stats0]
    mfma_mlp_kernel<128, 64, false, false, false, true><<<gmfma, 256, 0, stream>>>(B, A_lo, Wc[0], nullptr, nullptr, dinv, n);
    gather_agg_kernel<64><<<gagg, 256, 0, stream>>>(A_lo, A_hi, rowptr, esrc, dinv, bc[0], part0, n);
    gn_finalize_kernel<64><<<1, 64, 0, stream>>>(part0, ac0, gw[0], gb[0], gm[0], inv_n);

    // conv1 (f32): A_hi(+GN ac0) -> T1=B_lo(32w, dinv-scaled); gather -> B_hi(32w) [+stats1]
    mlp_kernel<64, 32, 256, 4, false, false, true, true><<<cdiv(n, 256), 256, 0, stream>>>(A_hi, B_lo, Wc[1], nullptr, ac0, dinv, n);
    gather_agg_kernel<32><<<gagg, 256, 0, stream>>>(B_lo, B_hi, rowptr, esrc, dinv, bc[1], part1, n);
    gn_finalize_kernel<32><<<1, 32, 0, stream>>>(part1, ac1, gw[1], gb[1], gm[1], inv_n);

    // conv2 (agg pre-GEMM, f32 GEMM): B_hi(+GN ac1) -> T2=B_lo(32w); gather_pre -> G2=A_lo(32w);
    // GEMM G2 -> O2=B_hi(64w); stats2
    transform_kernel<32><<<cdiv((long long)n * 8, 256), 256, 0, stream>>>(B_hi, B_lo, ac1, dinv, n);
    gather_pre_kernel<32><<<gagg, 256, 0, stream>>>(B_lo, A_lo, rowptr, esrc, dinv, n);
    mlp_kernel<32, 64, 256, 8, false, true, false, false><<<cdiv(n, 256), 256, 0, stream>>>(A_lo, B_hi, Wc[2], bc[2], nullptr, nullptr, n);
    gn_stats_kernel<64><<<cdiv(n, 512), 256, 0, stream>>>(B_hi, part2, n);
    gn_finalize_kernel<64><<<1, 64, 0, stream>>>(part2, ac2, gw[2], gb[2], gm[2], inv_n);

    // conv3 (agg pre-GEMM, MFMA GEMM): B_hi(+GN ac2) -> T3=A_lo(64w); gather_pre -> G3=B_lo(64w);
    // MFMA G3 -> A(128); stats3
    transform_kernel<64><<<cdiv((long long)n * 16, 256), 256, 0, stream>>>(B_hi, A_lo, ac2, dinv, n);
    gather_pre_kernel<64><<<gagg, 256, 0, stream>>>(A_lo, B_lo, rowptr, esrc, dinv, n);
    mfma_mlp_kernel<64, 128, false, true, false, false><<<gmfma, 256, 0, stream>>>(B_lo, A, Wc[3], bc[3], nullptr, nullptr, n);
    gn_stats_kernel<128><<<cdiv(n, 256), 256, 0, stream>>>(A, part3, n);
    gn_finalize_kernel<128><<<1, 128, 0, stream>>>(part3, ac3, gw[3], gb[3], gm[3], inv_n);

    // dec0 (MFMA): A(+GN ac3) -> D0=B_lo(64w); fused tail -> out
    mfma_mlp_kernel<128, 64, true, true, true, false><<<gmfma, 256, 0, stream>>>(A, B_lo, Wd0, bd0, ac3, nullptr, n);
    dec_tail_kernel<<<cdiv(n, 256), 256, 0, stream>>>(B_lo, Wd1, bd1, Wd2, bd2, Wd3, bd3, (float*)d_out, n);
}

// Round 13
// 730.087 us; speedup vs baseline: 1.2055x; 1.0034x over previous
//
#include <hip/hip_runtime.h>
#include <hip/hip_bf16.h>
#include <cstddef>

#define THREADS 256
#define NSLOT 64

typedef unsigned short ushort_t;
typedef unsigned int uint_t;
typedef __attribute__((ext_vector_type(8))) short bf16x8;
typedef __attribute__((ext_vector_type(4))) float f32x4;

__device__ __forceinline__ ushort_t f2b(float f) {
    uint_t i = __float_as_uint(f);
    uint_t r = i + 0x7fffu + ((i >> 16) & 1u);
    return (ushort_t)(r >> 16);
}

// ---------------- small kernels ----------------

__global__ __launch_bounds__(256) void local_means_kernel(const float* __restrict__ lx,
                                                          const int* __restrict__ lt,
                                                          float* __restrict__ means, int nl)
{
    __shared__ float slx[512 * 19];
    __shared__ int   slt[512];
    const int tid = threadIdx.x;
    for (int i = tid; i < nl * 19; i += 256) slx[i] = lx[i];
    for (int i = tid; i < nl; i += 256) slt[i] = lt[i];
    __syncthreads();
    if (tid >= 7 * 19) return;
    int c = tid / 19, dd = tid % 19;
    float s = 0.f; int cnt = 0;
    for (int i = 0; i < nl; ++i) {
        if (slt[i] == c) { s += slx[i * 19 + dd]; cnt++; }
    }
    means[tid] = cnt > 0 ? s / (float)cnt : 0.f;
}

__global__ void hist_kernel(const int* __restrict__ dst, int* __restrict__ degi, int E)
{
    int t = blockIdx.x * THREADS + threadIdx.x;
    if (t < E) atomicAdd(&degi[dst[t]], 1);
}

__global__ __launch_bounds__(256) void scan_part1_kernel(const int* __restrict__ degi,
                                                         int* __restrict__ blocksums, int n)
{
    const int tid = threadIdx.x;
    const int idx = blockIdx.x * 1024 + tid * 4;
    int v = 0;
    if (idx + 3 < n) {
        int4 d = *(const int4*)&degi[idx];
        v = d.x + d.y + d.z + d.w;
    } else {
        for (int i = 0; i < 4; ++i) if (idx + i < n) v += degi[idx + i];
    }
    __shared__ int s[256];
    s[tid] = v;
    __syncthreads();
    for (int off = 128; off >= 1; off >>= 1) {
        if (tid < off) s[tid] += s[tid + off];
        __syncthreads();
    }
    if (tid == 0) blocksums[blockIdx.x] = s[0];
}

__global__ __launch_bounds__(256) void scan_part2_kernel(int* __restrict__ blocksums, int nb)
{
    __shared__ int s[256];
    const int tid = threadIdx.x;
    int v = (tid < nb) ? blocksums[tid] : 0;
    s[tid] = v;
    __syncthreads();
    for (int off = 1; off < 256; off <<= 1) {
        int t = (tid >= off) ? s[tid - off] : 0;
        __syncthreads();
        s[tid] += t;
        __syncthreads();
    }
    if (tid < nb) blocksums[tid] = s[tid] - v;
}

__global__ __launch_bounds__(256) void scan_part3_kernel(const int* __restrict__ degi,
                                                         const int* __restrict__ blocksums,
                                                         int* __restrict__ rowptr,
                                                         int* __restrict__ cursor,
                                                         float* __restrict__ dinv, int n, int E)
{
    const int tid = threadIdx.x;
    const int idx = blockIdx.x * 1024 + tid * 4;
    int d0 = 0, d1 = 0, d2 = 0, d3 = 0;
    if (idx + 3 < n) {
        int4 d = *(const int4*)&degi[idx];
        d0 = d.x; d1 = d.y; d2 = d.z; d3 = d.w;
    } else {
        if (idx     < n) d0 = degi[idx];
        if (idx + 1 < n) d1 = degi[idx + 1];
        if (idx + 2 < n) d2 = degi[idx + 2];
        if (idx + 3 < n) d3 = degi[idx + 3];
    }
    const int v = d0 + d1 + d2 + d3;
    __shared__ int s[256];
    s[tid] = v;
    __syncthreads();
    for (int off = 1; off < 256; off <<= 1) {
        int t = (tid >= off) ? s[tid - off] : 0;
        __syncthreads();
        s[tid] += t;
        __syncthreads();
    }
    int run = blocksums[blockIdx.x] + s[tid] - v;
    if (idx + 3 < n) {
        int4 o;
        o.x = run; run += d0;
        o.y = run; run += d1;
        o.z = run; run += d2;
        o.w = run;
        *(int4*)&rowptr[idx] = o;
        *(int4*)&cursor[idx] = o;
        float4 dv;
        dv.x = rsqrtf((float)d0 + 1.0f);
        dv.y = rsqrtf((float)d1 + 1.0f);
        dv.z = rsqrtf((float)d2 + 1.0f);
        dv.w = rsqrtf((float)d3 + 1.0f);
        *(float4*)&dinv[idx] = dv;
    } else {
        if (idx     < n) { rowptr[idx]     = run; cursor[idx]     = run; dinv[idx]     = rsqrtf((float)d0 + 1.0f); run += d0; }
        if (idx + 1 < n) { rowptr[idx + 1] = run; cursor[idx + 1] = run; dinv[idx + 1] = rsqrtf((float)d1 + 1.0f); run += d1; }
        if (idx + 2 < n) { rowptr[idx + 2] = run; cursor[idx + 2] = run; dinv[idx + 2] = rsqrtf((float)d2 + 1.0f); run += d2; }
        if (idx + 3 < n) { rowptr[idx + 3] = run; cursor[idx + 3] = run; dinv[idx + 3] = rsqrtf((float)d3 + 1.0f); }
    }
    if (blockIdx.x == 0 && tid == 0) rowptr[n] = E;
}

__global__ void fill_kernel(const int* __restrict__ src, const int* __restrict__ dst,
                            int* __restrict__ cursor, int* __restrict__ esrc, int E)
{
    int t = blockIdx.x * THREADS + threadIdx.x;
    if (t >= E) return;
    int s = src[t], d = dst[t];
    int pos = atomicAdd(&cursor[d], 1);
    esrc[pos] = s;
}

__global__ void build_x0_kernel(const float* __restrict__ means,
                                const int* __restrict__ vt,
                                const float* __restrict__ vx,
                                const float* __restrict__ label,
                                float* __restrict__ out, int n)
{
    int tid = blockIdx.x * THREADS + threadIdx.x;
    int node = tid >> 5, c = tid & 31;
    if (node >= n) return;
    float v;
    if (c < 19)      v = means[vt[node] * 19 + c];
    else if (c < 25) v = vx[node * 6 + (c - 19)];
    else             v = label[node * 7 + (c - 25)];
    out[(size_t)node * 32 + c] = v;
}

// one-time: W[DIN][DOUT] f32 -> WT[DOUT][DIN] bf16
__global__ void wtrans_kernel(const float* __restrict__ W, ushort_t* __restrict__ WT,
                              int din, int dout)
{
    int t = blockIdx.x * THREADS + threadIdx.x;
    if (t >= din * dout) return;
    int k = t / dout, c = t % dout;
    WT[(size_t)c * din + k] = f2b(W[t]);
}

// ---------------- elementwise GN-affine + ReLU + dinv row-scale (f32 -> f32) ----
template<int D>
__global__ void transform_kernel(const float* __restrict__ x, float* __restrict__ out,
                                 const float* __restrict__ tr, const float* __restrict__ dinv, int n)
{
    constexpr int Q = D / 4;
    int t = blockIdx.x * THREADS + threadIdx.x;
    int node = t / Q, q = t % Q;
    if (node >= n) return;
    float4 v = *(const float4*)&x[(size_t)node * D + q * 4];
    const float4 a = *(const float4*)&tr[q * 4];
    const float4 c = *(const float4*)&tr[D + q * 4];
    const float dd = dinv[node];
    float4 o;
    o.x = fmaxf(fmaf(v.x, a.x, c.x), 0.f) * dd;
    o.y = fmaxf(fmaf(v.y, a.y, c.y), 0.f) * dd;
    o.z = fmaxf(fmaf(v.z, a.z, c.z), 0.f) * dd;
    o.w = fmaxf(fmaf(v.w, a.w, c.w), 0.f) * dd;
    *(float4*)&out[(size_t)node * D + q * 4] = o;
}

// ---------------- f32 dense layer (split-J, proven baseline form) ----------------
template<int DIN, int DOUT, int BN, int JPER, bool RELU, bool BIAS, bool TRANSFORM, bool SCALE>
__global__ __launch_bounds__(256) void mlp_kernel(
    const float* __restrict__ in, float* __restrict__ out,
    const float* __restrict__ W, const float* __restrict__ bias,
    const float* __restrict__ tr, const float* __restrict__ rowscale, int n)
{
    constexpr int KT  = 32;
    constexpr int TJ  = DOUT / JPER;
    constexpr int TN  = 256 / TJ;
    constexpr int NPT = BN / TN;
    constexpr int JQ  = JPER / 4;
    constexpr int CS  = 4 * TJ;
    constexpr int BNP = BN + 4;

    __shared__ float Wt[KT * DOUT];
    __shared__ float xT[KT][BNP];

    const int tid   = threadIdx.x;
    const int nbase = blockIdx.x * BN;
    const int tj = tid % TJ, tn = tid / TJ;
    const int j0 = tj * 4, n0 = tn * NPT;

    float acc[NPT][JPER];
#pragma unroll
    for (int p = 0; p < NPT; ++p)
#pragma unroll
        for (int j = 0; j < JPER; ++j) acc[p][j] = 0.f;

    for (int kt = 0; kt < DIN; kt += KT) {
        __syncthreads();
        for (int i = tid * 4; i < KT * DOUT; i += THREADS * 4) {
            *(float4*)&Wt[i] = *(const float4*)&W[(size_t)kt * DOUT + i];
        }
        for (int i = tid; i < BN * (KT / 4); i += THREADS) {
            int node = i / (KT / 4);
            int kq   = i % (KT / 4);
            int g    = nbase + node;
            float4 v = make_float4(0.f, 0.f, 0.f, 0.f);
            if (g < n) {
                v = *(const float4*)&in[(size_t)g * DIN + kt + kq * 4];
                if (TRANSFORM) {
                    const float4 a = *(const float4*)&tr[kt + kq * 4];
                    const float4 c = *(const float4*)&tr[DIN + kt + kq * 4];
                    v.x = fmaxf(fmaf(v.x, a.x, c.x), 0.f);
                    v.y = fmaxf(fmaf(v.y, a.y, c.y), 0.f);
                    v.z = fmaxf(fmaf(v.z, a.z, c.z), 0.f);
                    v.w = fmaxf(fmaf(v.w, a.w, c.w), 0.f);
                }
            }
            xT[kq * 4 + 0][node] = v.x;
            xT[kq * 4 + 1][node] = v.y;
            xT[kq * 4 + 2][node] = v.z;
            xT[kq * 4 + 3][node] = v.w;
        }
        __syncthreads();
#pragma unroll 4
        for (int kk = 0; kk < KT; ++kk) {
            float wv[JPER];
#pragma unroll
            for (int q = 0; q < JQ; ++q)
                *(float4*)&wv[q * 4] = *(const float4*)&Wt[kk * DOUT + q * CS + j0];
            float xv[NPT];
#pragma unroll
            for (int q = 0; q < NPT / 4; ++q)
                *(float4*)&xv[q * 4] = *(const float4*)&xT[kk][n0 + q * 4];
#pragma unroll
            for (int p = 0; p < NPT; ++p)
#pragma unroll
                for (int j = 0; j < JPER; ++j)
                    acc[p][j] = fmaf(xv[p], wv[j], acc[p][j]);
        }
    }

    float bv[JPER];
#pragma unroll
    for (int j = 0; j < JPER; ++j) bv[j] = 0.f;
    if (BIAS) {
#pragma unroll
        for (int q = 0; q < JQ; ++q)
            *(float4*)&bv[q * 4] = *(const float4*)&bias[q * CS + j0];
    }

#pragma unroll
    for (int p = 0; p < NPT; ++p) {
        const int g = nbase + n0 + p;
        if (g >= n) continue;
        float rs = 1.f;
        if (SCALE) rs = rowscale[g];
#pragma unroll
        for (int q = 0; q < JQ; ++q) {
            float4 o;
            o.x = acc[p][q * 4 + 0] + bv[q * 4 + 0];
            o.y = acc[p][q * 4 + 1] + bv[q * 4 + 1];
            o.z = acc[p][q * 4 + 2] + bv[q * 4 + 2];
            o.w = acc[p][q * 4 + 3] + bv[q * 4 + 3];
            if (RELU) {
                o.x = fmaxf(o.x, 0.f); o.y = fmaxf(o.y, 0.f);
                o.z = fmaxf(o.z, 0.f); o.w = fmaxf(o.w, 0.f);
            }
            if (SCALE) { o.x *= rs; o.y *= rs; o.z *= rs; o.w *= rs; }
            *(float4*)&out[(size_t)g * DOUT + q * CS + j0] = o;
        }
    }
}

// ---------------- bf16-MFMA dense layer; WT pre-converted bf16 [DOUT][DIN] ----------
// A-frag: lane l holds x[row=l&15][k=(l>>4)*8+j]; B-frag: WT[col=l&15][k] from GLOBAL
// (weights L2-resident); C/D: col=lane&15, row=(lane>>4)*4+reg  [m89-verified]
template<int DIN, int DOUT, bool RELU, bool BIAS, bool TRANSFORM, bool SCALE>
__global__ __launch_bounds__(256) void mfma_mlp_kernel(
    const float* __restrict__ in, float* __restrict__ out,
    const ushort_t* __restrict__ WT, const float* __restrict__ bias,
    const float* __restrict__ tr, const float* __restrict__ rowscale, int n)
{
    constexpr int BN  = 128;
    constexpr int KT  = 32;
    constexpr int NT  = DIN / KT;
    constexpr int LDK = 40;            // bf16 row stride: 80B, 16B-aligned
    constexpr int WM  = 2, WN = 2;
    constexpr int MW  = BN / WM;       // 64
    constexpr int NW  = DOUT / WN;     // 64 or 32
    constexpr int MR  = MW / 16;       // 4
    constexpr int NR  = NW / 16;       // 4 or 2

    __shared__ ushort_t xA[BN * LDK];  // 10 KB

    const int tid   = threadIdx.x;
    const int wid   = tid >> 6;
    const int lane  = tid & 63;
    const int wm    = wid >> 1, wn = wid & 1;
    const int nbase = blockIdx.x * BN;
    const int l16   = lane & 15;
    const int lk8   = (lane >> 4) * 8;

    f32x4 acc[MR][NR];
#pragma unroll
    for (int mi = 0; mi < MR; ++mi)
#pragma unroll
        for (int ni = 0; ni < NR; ++ni)
#pragma unroll
            for (int j = 0; j < 4; ++j) acc[mi][ni][j] = 0.f;

    for (int t = 0; t < NT; ++t) {
        const int kt = t * KT;
        __syncthreads();
        // stage x tile: [BN][KT] f32 -> bf16, k-contiguous
        for (int i = tid; i < BN * (KT / 4); i += 256) {
            const int row = i / (KT / 4);
            const int kq  = (i % (KT / 4)) * 4;
            const int g   = nbase + row;
            float4 v = make_float4(0.f, 0.f, 0.f, 0.f);
            if (g < n) {
                v = *(const float4*)&in[(size_t)g * DIN + kt + kq];
                if (TRANSFORM) {
                    const float4 a = *(const float4*)&tr[kt + kq];
                    const float4 c = *(const float4*)&tr[DIN + kt + kq];
                    v.x = fmaxf(fmaf(v.x, a.x, c.x), 0.f);
                    v.y = fmaxf(fmaf(v.y, a.y, c.y), 0.f);
                    v.z = fmaxf(fmaf(v.z, a.z, c.z), 0.f);
                    v.w = fmaxf(fmaf(v.w, a.w, c.w), 0.f);
                }
            }
            ushort4 b;
            b.x = f2b(v.x); b.y = f2b(v.y); b.z = f2b(v.z); b.w = f2b(v.w);
            *(ushort4*)&xA[row * LDK + kq] = b;
        }
        __syncthreads();

        bf16x8 af[MR], bf[NR];
#pragma unroll
        for (int mi = 0; mi < MR; ++mi)
            af[mi] = *(const bf16x8*)&xA[(wm * MW + mi * 16 + l16) * LDK + lk8];
#pragma unroll
        for (int ni = 0; ni < NR; ++ni)
            bf[ni] = *(const bf16x8*)&WT[(size_t)(wn * NW + ni * 16 + l16) * DIN + kt + lk8];
#pragma unroll
        for (int mi = 0; mi < MR; ++mi)
#pragma unroll
            for (int ni = 0; ni < NR; ++ni)
                acc[mi][ni] = __builtin_amdgcn_mfma_f32_16x16x32_bf16(
                    af[mi], bf[ni], acc[mi][ni], 0, 0, 0);
    }

    float bv[NR];
#pragma unroll
    for (int ni = 0; ni < NR; ++ni)
        bv[ni] = BIAS ? bias[wn * NW + ni * 16 + l16] : 0.f;

#pragma unroll
    for (int mi = 0; mi < MR; ++mi) {
#pragma unroll
        for (int j = 0; j < 4; ++j) {
            const int r = wm * MW + mi * 16 + (lane >> 4) * 4 + j;
            const int g = nbase + r;
            if (g >= n) continue;
            float rs = 1.f;
            if (SCALE) rs = rowscale[g];
#pragma unroll
            for (int ni = 0; ni < NR; ++ni) {
                const int col = wn * NW + ni * 16 + l16;
                float v = acc[mi][ni][j] + bv[ni];
                if (RELU) v = fmaxf(v, 0.f);
                if (SCALE) v *= rs;
                out[(size_t)g * DOUT + col] = v;
            }
        }
    }
}

// ---------------- CSR gather aggregation (post-GEMM), f32 table, fused bias+stats ----
template<int D>
__global__ __launch_bounds__(256) void gather_agg_kernel(
    const float* __restrict__ y, float* __restrict__ out,
    const int* __restrict__ rowptr, const int* __restrict__ esrc,
    const float* __restrict__ dinv,
    const float* __restrict__ bias, float* __restrict__ statsP, int n)
{
    constexpr int JT  = D / 8;
    constexpr int NPB = 256 / JT;
    const int tid  = threadIdx.x;
    const int jq   = tid % JT;
    const int nsub = tid / JT;
    const int j0   = jq * 8;

    float bv[8];
#pragma unroll
    for (int e = 0; e < 8; ++e) bv[e] = bias[j0 + e];

    float s1[8], s2[8];
#pragma unroll
    for (int e = 0; e < 8; ++e) { s1[e] = 0.f; s2[e] = 0.f; }

    const int ntiles = (n + NPB - 1) / NPB;
    for (int tile = blockIdx.x; tile < ntiles; tile += gridDim.x) {
        const int node = tile * NPB + nsub;
        if (node < n) {
            const int rb = rowptr[node], re = rowptr[node + 1];
            const float dd = dinv[node];
            float acc[8];
            *(float4*)&acc[0] = *(const float4*)&y[(size_t)node * D + j0];
            *(float4*)&acc[4] = *(const float4*)&y[(size_t)node * D + j0 + 4];
            int k = rb;
            for (; k + 1 < re; k += 2) {
                const int sa = esrc[k], sb = esrc[k + 1];
                float4 a0 = *(const float4*)&y[(size_t)sa * D + j0];
                float4 a1 = *(const float4*)&y[(size_t)sa * D + j0 + 4];
                float4 b0 = *(const float4*)&y[(size_t)sb * D + j0];
                float4 b1 = *(const float4*)&y[(size_t)sb * D + j0 + 4];
                acc[0] += a0.x + b0.x; acc[1] += a0.y + b0.y;
                acc[2] += a0.z + b0.z; acc[3] += a0.w + b0.w;
                acc[4] += a1.x + b1.x; acc[5] += a1.y + b1.y;
                acc[6] += a1.z + b1.z; acc[7] += a1.w + b1.w;
            }
            if (k < re) {
                const int sa = esrc[k];
                float4 a0 = *(const float4*)&y[(size_t)sa * D + j0];
                float4 a1 = *(const float4*)&y[(size_t)sa * D + j0 + 4];
                acc[0] += a0.x; acc[1] += a0.y; acc[2] += a0.z; acc[3] += a0.w;
                acc[4] += a1.x; acc[5] += a1.y; acc[6] += a1.z; acc[7] += a1.w;
            }
            float o[8];
#pragma unroll
            for (int e = 0; e < 8; ++e) {
                o[e] = fmaf(acc[e], dd, bv[e]);
                s1[e] += o[e];
                s2[e] = fmaf(o[e], o[e], s2[e]);
            }
            *(float4*)&out[(size_t)node * D + j0]     = make_float4(o[0], o[1], o[2], o[3]);
            *(float4*)&out[(size_t)node * D + j0 + 4] = make_float4(o[4], o[5], o[6], o[7]);
        }
    }

    __shared__ float red[256][17];
#pragma unroll
    for (int e = 0; e < 8; ++e) { red[tid][e] = s1[e]; red[tid][8 + e] = s2[e]; }
    __syncthreads();
#pragma unroll
    for (int off = NPB / 2; off >= 1; off >>= 1) {
        if (nsub < off) {
#pragma unroll
            for (int e = 0; e < 16; ++e) red[tid][e] += red[tid + off * JT][e];
        }
        __syncthreads();
    }
    if (nsub == 0) {
        float* slot = statsP + (size_t)(blockIdx.x & (NSLOT - 1)) * 256;
#pragma unroll
        for (int e = 0; e < 8; ++e) {
            atomicAdd(&slot[j0 + e],     red[tid][e]);
            atomicAdd(&slot[D + j0 + e], red[tid][8 + e]);
        }
    }
}

// ---------------- CSR gather aggregation (pre-GEMM), f32 table ----------------
template<int D>
__global__ __launch_bounds__(256) void gather_pre_kernel(
    const float* __restrict__ x, float* __restrict__ out,
    const int* __restrict__ rowptr, const int* __restrict__ esrc,
    const float* __restrict__ dinv, int n)
{
    constexpr int JT  = D / 8;
    constexpr int NPB = 256 / JT;
    const int tid  = threadIdx.x;
    const int jq   = tid % JT;
    const int nsub = tid / JT;
    const int j0   = jq * 8;

    const int ntiles = (n + NPB - 1) / NPB;
    for (int tile = blockIdx.x; tile < ntiles; tile += gridDim.x) {
        const int node = tile * NPB + nsub;
        if (node < n) {
            const int rb = rowptr[node], re = rowptr[node + 1];
            const float dd = dinv[node];
            float acc[8];
            *(float4*)&acc[0] = *(const float4*)&x[(size_t)node * D + j0];
            *(float4*)&acc[4] = *(const float4*)&x[(size_t)node * D + j0 + 4];
            int k = rb;
            for (; k + 1 < re; k += 2) {
                const int sa = esrc[k], sb = esrc[k + 1];
                float4 a0 = *(const float4*)&x[(size_t)sa * D + j0];
                float4 a1 = *(const float4*)&x[(size_t)sa * D + j0 + 4];
                float4 b0 = *(const float4*)&x[(size_t)sb * D + j0];
                float4 b1 = *(const float4*)&x[(size_t)sb * D + j0 + 4];
                acc[0] += a0.x + b0.x; acc[1] += a0.y + b0.y;
                acc[2] += a0.z + b0.z; acc[3] += a0.w + b0.w;
                acc[4] += a1.x + b1.x; acc[5] += a1.y + b1.y;
                acc[6] += a1.z + b1.z; acc[7] += a1.w + b1.w;
            }
            if (k < re) {
                const int sa = esrc[k];
                float4 a0 = *(const float4*)&x[(size_t)sa * D + j0];
                float4 a1 = *(const float4*)&x[(size_t)sa * D + j0 + 4];
                acc[0] += a0.x; acc[1] += a0.y; acc[2] += a0.z; acc[3] += a0.w;
                acc[4] += a1.x; acc[5] += a1.y; acc[6] += a1.z; acc[7] += a1.w;
            }
            float4 o0 = make_float4(acc[0] * dd, acc[1] * dd, acc[2] * dd, acc[3] * dd);
            float4 o1 = make_float4(acc[4] * dd, acc[5] * dd, acc[6] * dd, acc[7] * dd);
            *(float4*)&out[(size_t)node * D + j0]     = o0;
            *(float4*)&out[(size_t)node * D + j0 + 4] = o1;
        }
    }
}

// ---------------- standalone column stats (f32 in) -> slots ----------------
template<int D>
__global__ __launch_bounds__(256) void gn_stats_kernel(const float* __restrict__ x,
                                                       float* __restrict__ statsP, int n)
{
    constexpr int JT   = D / 4;
    constexpr int NPB  = 256 / JT;
    constexpr int ITER = 32;
    const int tid  = threadIdx.x;
    const int jb   = tid % JT;
    const int rsub = tid / JT;
    const int j0   = jb * 4;
    const int base = blockIdx.x * NPB * ITER;

    float s1[4] = {0.f, 0.f, 0.f, 0.f};
    float s2[4] = {0.f, 0.f, 0.f, 0.f};

#pragma unroll 4
    for (int i = 0; i < ITER; ++i) {
        int r = base + rsub + i * NPB;
        if (r < n) {
            float4 v = *(const float4*)&x[(size_t)r * D + j0];
            s1[0] += v.x; s1[1] += v.y; s1[2] += v.z; s1[3] += v.w;
            s2[0] = fmaf(v.x, v.x, s2[0]);
            s2[1] = fmaf(v.y, v.y, s2[1]);
            s2[2] = fmaf(v.z, v.z, s2[2]);
            s2[3] = fmaf(v.w, v.w, s2[3]);
        }
    }

    __shared__ float red[256][9];
#pragma unroll
    for (int e = 0; e < 4; ++e) { red[tid][e] = s1[e]; red[tid][4 + e] = s2[e]; }
    __syncthreads();
#pragma unroll
    for (int off = NPB / 2; off >= 1; off >>= 1) {
        if (rsub < off) {
#pragma unroll
            for (int e = 0; e < 8; ++e) red[tid][e] += red[tid + off * JT][e];
        }
        __syncthreads();
    }
    if (rsub == 0) {
        float* slot = statsP + (size_t)(blockIdx.x & (NSLOT - 1)) * 256;
#pragma unroll
        for (int e = 0; e < 4; ++e) {
            atomicAdd(&slot[j0 + e],     red[tid][e]);
            atomicAdd(&slot[D + j0 + e], red[tid][4 + e]);
        }
    }
}

template<int D>
__global__ void gn_finalize_kernel(const float* __restrict__ part, float* __restrict__ ac,
                                   const float* __restrict__ gw, const float* __restrict__ gb,
                                   const float* __restrict__ gm, float inv_n)
{
    int j = threadIdx.x;
    if (j >= D) return;
    float s1 = 0.f, s2 = 0.f;
    for (int t = 0; t < NSLOT; ++t) {
        s1 += part[(size_t)t * 256 + j];
        s2 += part[(size_t)t * 256 + D + j];
    }
    float mean = s1 * inv_n;
    float ex2  = s2 * inv_n;
    float m    = gm[j];
    float var  = ex2 - (2.f * m - m * m) * mean * mean;
    float a    = gw[j] * rsqrtf(var + 1e-5f);
    float c    = gb[j] - a * m * mean;
    ac[j]     = a;
    ac[D + j] = c;
}

// ---------------- fused decoder tail: 64 -> relu32 -> relu16 -> sigmoid(1) ----------------
__global__ __launch_bounds__(256) void dec_tail_kernel(
    const float* __restrict__ in, const float* __restrict__ W1, const float* __restrict__ b1,
    const float* __restrict__ W2, const float* __restrict__ b2,
    const float* __restrict__ W3, const float* __restrict__ b3,
    float* __restrict__ out, int n)
{
    int t = blockIdx.x * THREADS + threadIdx.x;
    if (t >= n) return;

    float x[64];
#pragma unroll
    for (int q = 0; q < 16; ++q)
        *(float4*)&x[q * 4] = *(const float4*)&in[(size_t)t * 64 + q * 4];

    float h1[32];
#pragma unroll
    for (int j = 0; j < 32; ++j) h1[j] = b1[j];
#pragma unroll 8
    for (int k = 0; k < 64; ++k) {
        const float xk = x[k];
#pragma unroll
        for (int j = 0; j < 32; ++j) h1[j] = fmaf(xk, W1[k * 32 + j], h1[j]);
    }
#pragma unroll
    for (int j = 0; j < 32; ++j) h1[j] = fmaxf(h1[j], 0.f);

    float h2[16];
#pragma unroll
    for (int j = 0; j < 16; ++j) h2[j] = b2[j];
#pragma unroll 8
    for (int k = 0; k < 32; ++k) {
        const float hk = h1[k];
#pragma unroll
        for (int j = 0; j < 16; ++j) h2[j] = fmaf(hk, W2[k * 16 + j], h2[j]);
    }

    float acc = b3[0];
#pragma unroll
    for (int k = 0; k < 16; ++k) acc = fmaf(fmaxf(h2[k], 0.f), W3[k], acc);
    out[t] = 1.0f / (1.0f + expf(-acc));
}

// ---------------- launch ----------------

extern "C" void kernel_launch(void* const* d_in, const int* in_sizes, int n_in,
                              void* d_out, int out_size, void* d_ws, size_t ws_size,
                              hipStream_t stream)
{
    const float* local_x    = (const float*)d_in[0];
    const int*   local_type = (const int*)d_in[1];
    const float* voxel_x    = (const float*)d_in[2];
    const int*   voxel_type = (const int*)d_in[3];
    const int*   edge_index = (const int*)d_in[4];
    const float* label      = (const float*)d_in[5];
    const float* We1 = (const float*)d_in[6],  *be1 = (const float*)d_in[7];
    const float* We2 = (const float*)d_in[8],  *be2 = (const float*)d_in[9];
    const float *Wc[4], *bc[4], *gw[4], *gb[4], *gm[4];
    for (int i = 0; i < 4; ++i) {
        Wc[i] = (const float*)d_in[10 + i * 5];
        bc[i] = (const float*)d_in[11 + i * 5];
        gw[i] = (const float*)d_in[12 + i * 5];
        gb[i] = (const float*)d_in[13 + i * 5];
        gm[i] = (const float*)d_in[14 + i * 5];
    }
    const float* Wd0 = (const float*)d_in[30], *bd0 = (const float*)d_in[31];
    const float* Wd1 = (const float*)d_in[32], *bd1 = (const float*)d_in[33];
    const float* Wd2 = (const float*)d_in[34], *bd2 = (const float*)d_in[35];
    const float* Wd3 = (const float*)d_in[36], *bd3 = (const float*)d_in[37];

    const int n  = in_sizes[2] / 6;    // 200000
    const int E  = in_sizes[4] / 2;    // 1200000
    const int nl = in_sizes[0] / 19;   // 400
    const int* src = edge_index;
    const int* dst = edge_index + E;

    // Workspace (~212 MB): [ac][means][blocksums][stats_part][WT0..3][rowptr][dinv][esrc]
    // [A f32 n*128][B f32 n*128]
    auto align256 = [](size_t x) { return (x + 255) & ~(size_t)255; };
    char* w = (char*)d_ws;
    float* ac_all = (float*)w;
    float* means  = (float*)(w + 4096);
    int* blocksums = (int*)(w + 8192);
    float* stats_part = (float*)(w + 8192 + 1024);
    size_t off = 8192 + 1024 + 4 * NSLOT * 256 * sizeof(float);
    ushort_t* wt0 = (ushort_t*)(w + off); off += align256(16384 * 2);  // We2^T 128x128
    ushort_t* wt1 = (ushort_t*)(w + off); off += align256(8192 * 2);   // Wc0^T 64x128
    ushort_t* wt2 = (ushort_t*)(w + off); off += align256(8192 * 2);   // Wc3^T 128x64
    ushort_t* wt3 = (ushort_t*)(w + off); off += align256(8192 * 2);   // Wd0^T 64x128
    int*   rowptr = (int*)(w + off);   off += align256((size_t)(n + 1) * 4);
    float* dinv   = (float*)(w + off); off += align256((size_t)n * 4);
    int*   esrc   = (int*)(w + off);   off += align256((size_t)E * 4);
    float* A    = (float*)(w + off);
    float* B    = A + (size_t)n * 128;
    float* A_lo = A;
    float* A_hi = A + (size_t)n * 64;
    float* B_lo = B;
    float* B_hi = B + (size_t)n * 64;
    int*   degi   = (int*)A;              // transient alias (pre-enc1 only)
    int*   cursor = (int*)A_hi;           // transient alias

    const float inv_n = 1.0f / (float)n;
    auto cdiv = [](long long a, long long b) { return (int)((a + b - 1) / b); };
    const int nb = cdiv(n, 1024);

    float* part0 = stats_part + 0 * NSLOT * 256;
    float* part1 = stats_part + 1 * NSLOT * 256;
    float* part2 = stats_part + 2 * NSLOT * 256;
    float* part3 = stats_part + 3 * NSLOT * 256;
    float* ac0 = ac_all + 0, *ac1 = ac_all + 256, *ac2 = ac_all + 512, *ac3 = ac_all + 768;

    hipMemsetAsync(stats_part, 0, 4 * NSLOT * 256 * sizeof(float), stream);
    hipMemsetAsync(degi, 0, (size_t)n * sizeof(int), stream);

    // one-time bf16 W^T prep (L2-resident afterwards)
    wtrans_kernel<<<cdiv(128 * 128, 256), 256, 0, stream>>>(We2,   wt0, 128, 128);
    wtrans_kernel<<<cdiv(128 * 64, 256), 256, 0, stream>>>(Wc[0], wt1, 128, 64);
    wtrans_kernel<<<cdiv(64 * 128, 256), 256, 0, stream>>>(Wc[3], wt2, 64, 128);
    wtrans_kernel<<<cdiv(128 * 64, 256), 256, 0, stream>>>(Wd0,   wt3, 128, 64);

    local_means_kernel<<<1, 256, 0, stream>>>(local_x, local_type, means, nl);
    hist_kernel<<<cdiv(E, 256), 256, 0, stream>>>(dst, degi, E);
    scan_part1_kernel<<<nb, 256, 0, stream>>>(degi, blocksums, n);
    scan_part2_kernel<<<1, 256, 0, stream>>>(blocksums, nb);
    scan_part3_kernel<<<nb, 256, 0, stream>>>(degi, blocksums, rowptr, cursor, dinv, n, E);
    fill_kernel<<<cdiv(E, 256), 256, 0, stream>>>(src, dst, cursor, esrc, E);
    build_x0_kernel<<<cdiv((long long)n * 32, 256), 256, 0, stream>>>(means, voxel_type, voxel_x, label, B_lo, n);

    const int gagg  = 2048;
    const int gmfma = cdiv(n, 128);

    // enc1 (f32): X0=B_lo(32w) -> A(128)
    mlp_kernel<32, 128, 128, 8, true, true, false, false><<<cdiv(n, 128), 256, 0, stream>>>(B_lo, A, We1, be1, nullptr, nullptr, n);
    // enc2 (MFMA): A -> B
    mfma_mlp_kernel<128, 128, true, true, false, false><<<gmfma, 256, 0, stream>>>(A, B, wt0, be2, nullptr, nullptr, n);

    // conv0 (MFMA): B -> T0=A_lo(64w, dinv-scaled); gather -> A_hi [+stats0]
    mfma_mlp_kernel<128, 64, false, false, false, true><<<gmfma, 256, 0, stream>>>(B, A_lo, wt1, nullptr, nullptr, dinv, n);
    gather_agg_kernel<64><<<gagg, 256, 0, stream>>>(A_lo, A_hi, rowptr, esrc, dinv, bc[0], part0, n);
    gn_finalize_kernel<64><<<1, 64, 0, stream>>>(part0, ac0, gw[0], gb[0], gm[0], inv_n);

    // conv1 (f32): A_hi(+GN ac0) -> T1=B_lo(32w, dinv-scaled); gather -> B_hi(32w) [+stats1]
    mlp_kernel<64, 32, 256, 4, false, false, true, true><<<cdiv(n, 256), 256, 0, stream>>>(A_hi, B_lo, Wc[1], nullptr, ac0, dinv, n);
    gather_agg_kernel<32><<<gagg, 256, 0, stream>>>(B_lo, B_hi, rowptr, esrc, dinv, bc[1], part1, n);
    gn_finalize_kernel<32><<<1, 32, 0, stream>>>(part1, ac1, gw[1], gb[1], gm[1], inv_n);

    // conv2 (agg pre-GEMM, f32 GEMM): B_hi(+GN ac1) -> T2=B_lo(32w); gather_pre -> G2=A_lo(32w);
    // GEMM -> O2=B_hi(64w); stats2
    transform_kernel<32><<<cdiv((long long)n * 8, 256), 256, 0, stream>>>(B_hi, B_lo, ac1, dinv, n);
    gather_pre_kernel<32><<<gagg, 256, 0, stream>>>(B_lo, A_lo, rowptr, esrc, dinv, n);
    mlp_kernel<32, 64, 256, 8, false, true, false, false><<<cdiv(n, 256), 256, 0, stream>>>(A_lo, B_hi, Wc[2], bc[2], nullptr, nullptr, n);
    gn_stats_kernel<64><<<cdiv(n, 512), 256, 0, stream>>>(B_hi, part2, n);
    gn_finalize_kernel<64><<<1, 64, 0, stream>>>(part2, ac2, gw[2], gb[2], gm[2], inv_n);

    // conv3 (agg pre-GEMM, MFMA): B_hi(+GN ac2) -> T3=A_lo(64w); gather_pre -> G3=B_lo(64w);
    // MFMA -> A(128); stats3
    transform_kernel<64><<<cdiv((long long)n * 16, 256), 256, 0, stream>>>(B_hi, A_lo, ac2, dinv, n);
    gather_pre_kernel<64><<<gagg, 256, 0, stream>>>(A_lo, B_lo, rowptr, esrc, dinv, n);
    mfma_mlp_kernel<64, 128, false, true, false, false><<<gmfma, 256, 0, stream>>>(B_lo, A, wt2, bc[3], nullptr, nullptr, n);
    gn_stats_kernel<128><<<cdiv(n, 256), 256, 0, stream>>>(A, part3, n);
    gn_finalize_kernel<128><<<1, 128, 0, stream>>>(part3, ac3, gw[3], gb[3], gm[3], inv_n);

    // dec0 (MFMA): A(+GN ac3) -> D0=B_lo(64w); fused tail -> out
    mfma_mlp_kernel<128, 64, true, true, true, false><<<gmfma, 256, 0, stream>>>(A, B_lo, wt3, bd0, ac3, nullptr, n);
    dec_tail_kernel<<<cdiv(n, 256), 256, 0, stream>>>(B_lo, Wd1, bd1, Wd2, bd2, Wd3, bd3, (float*)d_out, n);
}

// Round 14
// 664.966 us; speedup vs baseline: 1.3236x; 1.0979x over previous
//
#include <hip/hip_runtime.h>
#include <hip/hip_bf16.h>
#include <cstddef>

#define THREADS 256
#define NSLOT 64

typedef unsigned short ushort_t;
typedef unsigned int uint_t;
typedef __attribute__((ext_vector_type(8))) short bf16x8;
typedef __attribute__((ext_vector_type(4))) float f32x4;

__device__ __forceinline__ ushort_t f2b(float f) {
    uint_t i = __float_as_uint(f);
    uint_t r = i + 0x7fffu + ((i >> 16) & 1u);
    return (ushort_t)(r >> 16);
}

// ---------------- small kernels ----------------

__global__ __launch_bounds__(256) void local_means_kernel(const float* __restrict__ lx,
                                                          const int* __restrict__ lt,
                                                          float* __restrict__ means, int nl)
{
    __shared__ float slx[512 * 19];
    __shared__ int   slt[512];
    const int tid = threadIdx.x;
    for (int i = tid; i < nl * 19; i += 256) slx[i] = lx[i];
    for (int i = tid; i < nl; i += 256) slt[i] = lt[i];
    __syncthreads();
    if (tid >= 7 * 19) return;
    int c = tid / 19, dd = tid % 19;
    float s = 0.f; int cnt = 0;
    for (int i = 0; i < nl; ++i) {
        if (slt[i] == c) { s += slx[i * 19 + dd]; cnt++; }
    }
    means[tid] = cnt > 0 ? s / (float)cnt : 0.f;
}

// hist + per-edge slot index (q-trick): qpos[t] = this edge's rank within its dst
__global__ void hist_kernel(const int* __restrict__ dst, int* __restrict__ degi,
                            int* __restrict__ qpos, int E)
{
    int t = blockIdx.x * THREADS + threadIdx.x;
    if (t < E) qpos[t] = atomicAdd(&degi[dst[t]], 1);
}

__global__ __launch_bounds__(256) void scan_part1_kernel(const int* __restrict__ degi,
                                                         int* __restrict__ blocksums, int n)
{
    const int tid = threadIdx.x;
    const int idx = blockIdx.x * 1024 + tid * 4;
    int v = 0;
    if (idx + 3 < n) {
        int4 d = *(const int4*)&degi[idx];
        v = d.x + d.y + d.z + d.w;
    } else {
        for (int i = 0; i < 4; ++i) if (idx + i < n) v += degi[idx + i];
    }
    __shared__ int s[256];
    s[tid] = v;
    __syncthreads();
    for (int off = 128; off >= 1; off >>= 1) {
        if (tid < off) s[tid] += s[tid + off];
        __syncthreads();
    }
    if (tid == 0) blocksums[blockIdx.x] = s[0];
}

__global__ __launch_bounds__(256) void scan_part2_kernel(int* __restrict__ blocksums, int nb)
{
    __shared__ int s[256];
    const int tid = threadIdx.x;
    int v = (tid < nb) ? blocksums[tid] : 0;
    s[tid] = v;
    __syncthreads();
    for (int off = 1; off < 256; off <<= 1) {
        int t = (tid >= off) ? s[tid - off] : 0;
        __syncthreads();
        s[tid] += t;
        __syncthreads();
    }
    if (tid < nb) blocksums[tid] = s[tid] - v;
}

// writes rowptr + dinv (fused); no cursor needed anymore
__global__ __launch_bounds__(256) void scan_part3_kernel(const int* __restrict__ degi,
                                                         const int* __restrict__ blocksums,
                                                         int* __restrict__ rowptr,
                                                         float* __restrict__ dinv, int n, int E)
{
    const int tid = threadIdx.x;
    const int idx = blockIdx.x * 1024 + tid * 4;
    int d0 = 0, d1 = 0, d2 = 0, d3 = 0;
    if (idx + 3 < n) {
        int4 d = *(const int4*)&degi[idx];
        d0 = d.x; d1 = d.y; d2 = d.z; d3 = d.w;
    } else {
        if (idx     < n) d0 = degi[idx];
        if (idx + 1 < n) d1 = degi[idx + 1];
        if (idx + 2 < n) d2 = degi[idx + 2];
        if (idx + 3 < n) d3 = degi[idx + 3];
    }
    const int v = d0 + d1 + d2 + d3;
    __shared__ int s[256];
    s[tid] = v;
    __syncthreads();
    for (int off = 1; off < 256; off <<= 1) {
        int t = (tid >= off) ? s[tid - off] : 0;
        __syncthreads();
        s[tid] += t;
        __syncthreads();
    }
    int run = blocksums[blockIdx.x] + s[tid] - v;
    if (idx + 3 < n) {
        int4 o;
        o.x = run; run += d0;
        o.y = run; run += d1;
        o.z = run; run += d2;
        o.w = run;
        *(int4*)&rowptr[idx] = o;
        float4 dv;
        dv.x = rsqrtf((float)d0 + 1.0f);
        dv.y = rsqrtf((float)d1 + 1.0f);
        dv.z = rsqrtf((float)d2 + 1.0f);
        dv.w = rsqrtf((float)d3 + 1.0f);
        *(float4*)&dinv[idx] = dv;
    } else {
        if (idx     < n) { rowptr[idx]     = run; dinv[idx]     = rsqrtf((float)d0 + 1.0f); run += d0; }
        if (idx + 1 < n) { rowptr[idx + 1] = run; dinv[idx + 1] = rsqrtf((float)d1 + 1.0f); run += d1; }
        if (idx + 2 < n) { rowptr[idx + 2] = run; dinv[idx + 2] = rsqrtf((float)d2 + 1.0f); run += d2; }
        if (idx + 3 < n) { rowptr[idx + 3] = run; dinv[idx + 3] = rsqrtf((float)d3 + 1.0f); }
    }
    if (blockIdx.x == 0 && tid == 0) rowptr[n] = E;
}

// atomic-free CSR fill: pos = rowptr[dst] + qpos
__global__ void fill_kernel(const int* __restrict__ src, const int* __restrict__ dst,
                            const int* __restrict__ qpos, const int* __restrict__ rowptr,
                            int* __restrict__ esrc, int E)
{
    int t = blockIdx.x * THREADS + threadIdx.x;
    if (t >= E) return;
    esrc[rowptr[dst[t]] + qpos[t]] = src[t];
}

__global__ void build_x0_kernel(const float* __restrict__ means,
                                const int* __restrict__ vt,
                                const float* __restrict__ vx,
                                const float* __restrict__ label,
                                float* __restrict__ out, int n)
{
    int tid = blockIdx.x * THREADS + threadIdx.x;
    int node = tid >> 5, c = tid & 31;
    if (node >= n) return;
    float v;
    if (c < 19)      v = means[vt[node] * 19 + c];
    else if (c < 25) v = vx[node * 6 + (c - 19)];
    else             v = label[node * 7 + (c - 25)];
    out[(size_t)node * 32 + c] = v;
}

// one-time: W[DIN][DOUT] f32 -> WT[DOUT][DIN] bf16
__global__ void wtrans_kernel(const float* __restrict__ W, ushort_t* __restrict__ WT,
                              int din, int dout)
{
    int t = blockIdx.x * THREADS + threadIdx.x;
    if (t >= din * dout) return;
    int k = t / dout, c = t % dout;
    WT[(size_t)c * din + k] = f2b(W[t]);
}

// ---------------- f32 dense layer (split-J, proven baseline form) ----------------
template<int DIN, int DOUT, int BN, int JPER, bool RELU, bool BIAS, bool TRANSFORM, bool SCALE>
__global__ __launch_bounds__(256) void mlp_kernel(
    const float* __restrict__ in, float* __restrict__ out,
    const float* __restrict__ W, const float* __restrict__ bias,
    const float* __restrict__ tr, const float* __restrict__ rowscale, int n)
{
    constexpr int KT  = 32;
    constexpr int TJ  = DOUT / JPER;
    constexpr int TN  = 256 / TJ;
    constexpr int NPT = BN / TN;
    constexpr int JQ  = JPER / 4;
    constexpr int CS  = 4 * TJ;
    constexpr int BNP = BN + 4;

    __shared__ float Wt[KT * DOUT];
    __shared__ float xT[KT][BNP];

    const int tid   = threadIdx.x;
    const int nbase = blockIdx.x * BN;
    const int tj = tid % TJ, tn = tid / TJ;
    const int j0 = tj * 4, n0 = tn * NPT;

    float acc[NPT][JPER];
#pragma unroll
    for (int p = 0; p < NPT; ++p)
#pragma unroll
        for (int j = 0; j < JPER; ++j) acc[p][j] = 0.f;

    for (int kt = 0; kt < DIN; kt += KT) {
        __syncthreads();
        for (int i = tid * 4; i < KT * DOUT; i += THREADS * 4) {
            *(float4*)&Wt[i] = *(const float4*)&W[(size_t)kt * DOUT + i];
        }
        for (int i = tid; i < BN * (KT / 4); i += THREADS) {
            int node = i / (KT / 4);
            int kq   = i % (KT / 4);
            int g    = nbase + node;
            float4 v = make_float4(0.f, 0.f, 0.f, 0.f);
            if (g < n) {
                v = *(const float4*)&in[(size_t)g * DIN + kt + kq * 4];
                if (TRANSFORM) {
                    const float4 a = *(const float4*)&tr[kt + kq * 4];
                    const float4 c = *(const float4*)&tr[DIN + kt + kq * 4];
                    v.x = fmaxf(fmaf(v.x, a.x, c.x), 0.f);
                    v.y = fmaxf(fmaf(v.y, a.y, c.y), 0.f);
                    v.z = fmaxf(fmaf(v.z, a.z, c.z), 0.f);
                    v.w = fmaxf(fmaf(v.w, a.w, c.w), 0.f);
                }
            }
            xT[kq * 4 + 0][node] = v.x;
            xT[kq * 4 + 1][node] = v.y;
            xT[kq * 4 + 2][node] = v.z;
            xT[kq * 4 + 3][node] = v.w;
        }
        __syncthreads();
#pragma unroll 4
        for (int kk = 0; kk < KT; ++kk) {
            float wv[JPER];
#pragma unroll
            for (int q = 0; q < JQ; ++q)
                *(float4*)&wv[q * 4] = *(const float4*)&Wt[kk * DOUT + q * CS + j0];
            float xv[NPT];
#pragma unroll
            for (int q = 0; q < NPT / 4; ++q)
                *(float4*)&xv[q * 4] = *(const float4*)&xT[kk][n0 + q * 4];
#pragma unroll
            for (int p = 0; p < NPT; ++p)
#pragma unroll
                for (int j = 0; j < JPER; ++j)
                    acc[p][j] = fmaf(xv[p], wv[j], acc[p][j]);
        }
    }

    float bv[JPER];
#pragma unroll
    for (int j = 0; j < JPER; ++j) bv[j] = 0.f;
    if (BIAS) {
#pragma unroll
        for (int q = 0; q < JQ; ++q)
            *(float4*)&bv[q * 4] = *(const float4*)&bias[q * CS + j0];
    }

#pragma unroll
    for (int p = 0; p < NPT; ++p) {
        const int g = nbase + n0 + p;
        if (g >= n) continue;
        float rs = 1.f;
        if (SCALE) rs = rowscale[g];
#pragma unroll
        for (int q = 0; q < JQ; ++q) {
            float4 o;
            o.x = acc[p][q * 4 + 0] + bv[q * 4 + 0];
            o.y = acc[p][q * 4 + 1] + bv[q * 4 + 1];
            o.z = acc[p][q * 4 + 2] + bv[q * 4 + 2];
            o.w = acc[p][q * 4 + 3] + bv[q * 4 + 3];
            if (RELU) {
                o.x = fmaxf(o.x, 0.f); o.y = fmaxf(o.y, 0.f);
                o.z = fmaxf(o.z, 0.f); o.w = fmaxf(o.w, 0.f);
            }
            if (SCALE) { o.x *= rs; o.y *= rs; o.z *= rs; o.w *= rs; }
            *(float4*)&out[(size_t)g * DOUT + q * CS + j0] = o;
        }
    }
}

// ---------------- bf16-MFMA dense layer; WT pre-converted bf16 [DOUT][DIN] ----------
template<int DIN, int DOUT, bool RELU, bool BIAS, bool TRANSFORM, bool SCALE>
__global__ __launch_bounds__(256) void mfma_mlp_kernel(
    const float* __restrict__ in, float* __restrict__ out,
    const ushort_t* __restrict__ WT, const float* __restrict__ bias,
    const float* __restrict__ tr, const float* __restrict__ rowscale, int n)
{
    constexpr int BN  = 128;
    constexpr int KT  = 32;
    constexpr int NT  = DIN / KT;
    constexpr int LDK = 40;
    constexpr int WM  = 2, WN = 2;
    constexpr int MW  = BN / WM;
    constexpr int NW  = DOUT / WN;
    constexpr int MR  = MW / 16;
    constexpr int NR  = NW / 16;

    __shared__ ushort_t xA[BN * LDK];

    const int tid   = threadIdx.x;
    const int wid   = tid >> 6;
    const int lane  = tid & 63;
    const int wm    = wid >> 1, wn = wid & 1;
    const int nbase = blockIdx.x * BN;
    const int l16   = lane & 15;
    const int lk8   = (lane >> 4) * 8;

    f32x4 acc[MR][NR];
#pragma unroll
    for (int mi = 0; mi < MR; ++mi)
#pragma unroll
        for (int ni = 0; ni < NR; ++ni)
#pragma unroll
            for (int j = 0; j < 4; ++j) acc[mi][ni][j] = 0.f;

    for (int t = 0; t < NT; ++t) {
        const int kt = t * KT;
        __syncthreads();
        for (int i = tid; i < BN * (KT / 4); i += 256) {
            const int row = i / (KT / 4);
            const int kq  = (i % (KT / 4)) * 4;
            const int g   = nbase + row;
            float4 v = make_float4(0.f, 0.f, 0.f, 0.f);
            if (g < n) {
                v = *(const float4*)&in[(size_t)g * DIN + kt + kq];
                if (TRANSFORM) {
                    const float4 a = *(const float4*)&tr[kt + kq];
                    const float4 c = *(const float4*)&tr[DIN + kt + kq];
                    v.x = fmaxf(fmaf(v.x, a.x, c.x), 0.f);
                    v.y = fmaxf(fmaf(v.y, a.y, c.y), 0.f);
                    v.z = fmaxf(fmaf(v.z, a.z, c.z), 0.f);
                    v.w = fmaxf(fmaf(v.w, a.w, c.w), 0.f);
                }
            }
            ushort4 b;
            b.x = f2b(v.x); b.y = f2b(v.y); b.z = f2b(v.z); b.w = f2b(v.w);
            *(ushort4*)&xA[row * LDK + kq] = b;
        }
        __syncthreads();

        bf16x8 af[MR], bf[NR];
#pragma unroll
        for (int mi = 0; mi < MR; ++mi)
            af[mi] = *(const bf16x8*)&xA[(wm * MW + mi * 16 + l16) * LDK + lk8];
#pragma unroll
        for (int ni = 0; ni < NR; ++ni)
            bf[ni] = *(const bf16x8*)&WT[(size_t)(wn * NW + ni * 16 + l16) * DIN + kt + lk8];
#pragma unroll
        for (int mi = 0; mi < MR; ++mi)
#pragma unroll
            for (int ni = 0; ni < NR; ++ni)
                acc[mi][ni] = __builtin_amdgcn_mfma_f32_16x16x32_bf16(
                    af[mi], bf[ni], acc[mi][ni], 0, 0, 0);
    }

    float bv[NR];
#pragma unroll
    for (int ni = 0; ni < NR; ++ni)
        bv[ni] = BIAS ? bias[wn * NW + ni * 16 + l16] : 0.f;

#pragma unroll
    for (int mi = 0; mi < MR; ++mi) {
#pragma unroll
        for (int j = 0; j < 4; ++j) {
            const int r = wm * MW + mi * 16 + (lane >> 4) * 4 + j;
            const int g = nbase + r;
            if (g >= n) continue;
            float rs = 1.f;
            if (SCALE) rs = rowscale[g];
#pragma unroll
            for (int ni = 0; ni < NR; ++ni) {
                const int col = wn * NW + ni * 16 + l16;
                float v = acc[mi][ni][j] + bv[ni];
                if (RELU) v = fmaxf(v, 0.f);
                if (SCALE) v *= rs;
                out[(size_t)g * DOUT + col] = v;
            }
        }
    }
}

// ---------------- CSR gather aggregation (post-GEMM), f32 table, fused bias+stats ----
template<int D>
__global__ __launch_bounds__(256) void gather_agg_kernel(
    const float* __restrict__ y, float* __restrict__ out,
    const int* __restrict__ rowptr, const int* __restrict__ esrc,
    const float* __restrict__ dinv,
    const float* __restrict__ bias, float* __restrict__ statsP, int n)
{
    constexpr int JT  = D / 8;
    constexpr int NPB = 256 / JT;
    const int tid  = threadIdx.x;
    const int jq   = tid % JT;
    const int nsub = tid / JT;
    const int j0   = jq * 8;

    float bv[8];
#pragma unroll
    for (int e = 0; e < 8; ++e) bv[e] = bias[j0 + e];

    float s1[8], s2[8];
#pragma unroll
    for (int e = 0; e < 8; ++e) { s1[e] = 0.f; s2[e] = 0.f; }

    const int ntiles = (n + NPB - 1) / NPB;
    for (int tile = blockIdx.x; tile < ntiles; tile += gridDim.x) {
        const int node = tile * NPB + nsub;
        if (node < n) {
            const int rb = rowptr[node], re = rowptr[node + 1];
            const float dd = dinv[node];
            float acc[8];
            *(float4*)&acc[0] = *(const float4*)&y[(size_t)node * D + j0];
            *(float4*)&acc[4] = *(const float4*)&y[(size_t)node * D + j0 + 4];
            int k = rb;
            for (; k + 3 < re; k += 4) {
                const int sa = esrc[k], sb = esrc[k + 1];
                const int sc = esrc[k + 2], sd = esrc[k + 3];
                float4 a0 = *(const float4*)&y[(size_t)sa * D + j0];
                float4 a1 = *(const float4*)&y[(size_t)sa * D + j0 + 4];
                float4 b0 = *(const float4*)&y[(size_t)sb * D + j0];
                float4 b1 = *(const float4*)&y[(size_t)sb * D + j0 + 4];
                float4 c0 = *(const float4*)&y[(size_t)sc * D + j0];
                float4 c1 = *(const float4*)&y[(size_t)sc * D + j0 + 4];
                float4 e0 = *(const float4*)&y[(size_t)sd * D + j0];
                float4 e1 = *(const float4*)&y[(size_t)sd * D + j0 + 4];
                acc[0] += (a0.x + b0.x) + (c0.x + e0.x);
                acc[1] += (a0.y + b0.y) + (c0.y + e0.y);
                acc[2] += (a0.z + b0.z) + (c0.z + e0.z);
                acc[3] += (a0.w + b0.w) + (c0.w + e0.w);
                acc[4] += (a1.x + b1.x) + (c1.x + e1.x);
                acc[5] += (a1.y + b1.y) + (c1.y + e1.y);
                acc[6] += (a1.z + b1.z) + (c1.z + e1.z);
                acc[7] += (a1.w + b1.w) + (c1.w + e1.w);
            }
            for (; k < re; ++k) {
                const int sa = esrc[k];
                float4 a0 = *(const float4*)&y[(size_t)sa * D + j0];
                float4 a1 = *(const float4*)&y[(size_t)sa * D + j0 + 4];
                acc[0] += a0.x; acc[1] += a0.y; acc[2] += a0.z; acc[3] += a0.w;
                acc[4] += a1.x; acc[5] += a1.y; acc[6] += a1.z; acc[7] += a1.w;
            }
            float o[8];
#pragma unroll
            for (int e = 0; e < 8; ++e) {
                o[e] = fmaf(acc[e], dd, bv[e]);
                s1[e] += o[e];
                s2[e] = fmaf(o[e], o[e], s2[e]);
            }
            *(float4*)&out[(size_t)node * D + j0]     = make_float4(o[0], o[1], o[2], o[3]);
            *(float4*)&out[(size_t)node * D + j0 + 4] = make_float4(o[4], o[5], o[6], o[7]);
        }
    }

    __shared__ float red[256][17];
#pragma unroll
    for (int e = 0; e < 8; ++e) { red[tid][e] = s1[e]; red[tid][8 + e] = s2[e]; }
    __syncthreads();
#pragma unroll
    for (int off = NPB / 2; off >= 1; off >>= 1) {
        if (nsub < off) {
#pragma unroll
            for (int e = 0; e < 16; ++e) red[tid][e] += red[tid + off * JT][e];
        }
        __syncthreads();
    }
    if (nsub == 0) {
        float* slot = statsP + (size_t)(blockIdx.x & (NSLOT - 1)) * 256;
#pragma unroll
        for (int e = 0; e < 8; ++e) {
            atomicAdd(&slot[j0 + e],     red[tid][e]);
            atomicAdd(&slot[D + j0 + e], red[tid][8 + e]);
        }
    }
}

// ---------------- CSR gather aggregation (pre-GEMM), f32 table, fused GN+ReLU+dinv ----
// row value f(s) = relu(a*x[s]+c)*dinv[s]; out[d] = dinv[d]*(f(d) + sum f(esrc))
template<int D>
__global__ __launch_bounds__(256) void gather_pre_kernel(
    const float* __restrict__ x, float* __restrict__ out,
    const int* __restrict__ rowptr, const int* __restrict__ esrc,
    const float* __restrict__ dinv, const float* __restrict__ tr, int n)
{
    constexpr int JT  = D / 8;
    constexpr int NPB = 256 / JT;
    const int tid  = threadIdx.x;
    const int jq   = tid % JT;
    const int nsub = tid / JT;
    const int j0   = jq * 8;

    float av[8], cv[8];
#pragma unroll
    for (int e = 0; e < 8; ++e) { av[e] = tr[j0 + e]; cv[e] = tr[D + j0 + e]; }

    const int ntiles = (n + NPB - 1) / NPB;
    for (int tile = blockIdx.x; tile < ntiles; tile += gridDim.x) {
        const int node = tile * NPB + nsub;
        if (node < n) {
            const int rb = rowptr[node], re = rowptr[node + 1];
            const float dd = dinv[node];
            float acc[8], v[8];
            *(float4*)&v[0] = *(const float4*)&x[(size_t)node * D + j0];
            *(float4*)&v[4] = *(const float4*)&x[(size_t)node * D + j0 + 4];
#pragma unroll
            for (int e = 0; e < 8; ++e)
                acc[e] = fmaxf(fmaf(v[e], av[e], cv[e]), 0.f) * dd;
            int k = rb;
            for (; k + 3 < re; k += 4) {
                const int sa = esrc[k], sb = esrc[k + 1];
                const int sc = esrc[k + 2], sd = esrc[k + 3];
                const float da = dinv[sa], db = dinv[sb];
                const float dc = dinv[sc], de = dinv[sd];
                float va[8], vb[8], vc[8], ve[8];
                *(float4*)&va[0] = *(const float4*)&x[(size_t)sa * D + j0];
                *(float4*)&va[4] = *(const float4*)&x[(size_t)sa * D + j0 + 4];
                *(float4*)&vb[0] = *(const float4*)&x[(size_t)sb * D + j0];
                *(float4*)&vb[4] = *(const float4*)&x[(size_t)sb * D + j0 + 4];
                *(float4*)&vc[0] = *(const float4*)&x[(size_t)sc * D + j0];
                *(float4*)&vc[4] = *(const float4*)&x[(size_t)sc * D + j0 + 4];
                *(float4*)&ve[0] = *(const float4*)&x[(size_t)sd * D + j0];
                *(float4*)&ve[4] = *(const float4*)&x[(size_t)sd * D + j0 + 4];
#pragma unroll
                for (int e = 0; e < 8; ++e) {
                    float fa = fmaxf(fmaf(va[e], av[e], cv[e]), 0.f) * da;
                    float fb = fmaxf(fmaf(vb[e], av[e], cv[e]), 0.f) * db;
                    float fc = fmaxf(fmaf(vc[e], av[e], cv[e]), 0.f) * dc;
                    float fe = fmaxf(fmaf(ve[e], av[e], cv[e]), 0.f) * de;
                    acc[e] += (fa + fb) + (fc + fe);
                }
            }
            for (; k < re; ++k) {
                const int sa = esrc[k];
                const float da = dinv[sa];
                float va[8];
                *(float4*)&va[0] = *(const float4*)&x[(size_t)sa * D + j0];
                *(float4*)&va[4] = *(const float4*)&x[(size_t)sa * D + j0 + 4];
#pragma unroll
                for (int e = 0; e < 8; ++e)
                    acc[e] += fmaxf(fmaf(va[e], av[e], cv[e]), 0.f) * da;
            }
            float4 o0 = make_float4(acc[0] * dd, acc[1] * dd, acc[2] * dd, acc[3] * dd);
            float4 o1 = make_float4(acc[4] * dd, acc[5] * dd, acc[6] * dd, acc[7] * dd);
            *(float4*)&out[(size_t)node * D + j0]     = o0;
            *(float4*)&out[(size_t)node * D + j0 + 4] = o1;
        }
    }
}

// ---------------- standalone column stats (f32 in) -> slots ----------------
template<int D>
__global__ __launch_bounds__(256) void gn_stats_kernel(const float* __restrict__ x,
                                                       float* __restrict__ statsP, int n)
{
    constexpr int JT   = D / 4;
    constexpr int NPB  = 256 / JT;
    constexpr int ITER = 32;
    const int tid  = threadIdx.x;
    const int jb   = tid % JT;
    const int rsub = tid / JT;
    const int j0   = jb * 4;
    const int base = blockIdx.x * NPB * ITER;

    float s1[4] = {0.f, 0.f, 0.f, 0.f};
    float s2[4] = {0.f, 0.f, 0.f, 0.f};

#pragma unroll 4
    for (int i = 0; i < ITER; ++i) {
        int r = base + rsub + i * NPB;
        if (r < n) {
            float4 v = *(const float4*)&x[(size_t)r * D + j0];
            s1[0] += v.x; s1[1] += v.y; s1[2] += v.z; s1[3] += v.w;
            s2[0] = fmaf(v.x, v.x, s2[0]);
            s2[1] = fmaf(v.y, v.y, s2[1]);
            s2[2] = fmaf(v.z, v.z, s2[2]);
            s2[3] = fmaf(v.w, v.w, s2[3]);
        }
    }

    __shared__ float red[256][9];
#pragma unroll
    for (int e = 0; e < 4; ++e) { red[tid][e] = s1[e]; red[tid][4 + e] = s2[e]; }
    __syncthreads();
#pragma unroll
    for (int off = NPB / 2; off >= 1; off >>= 1) {
        if (rsub < off) {
#pragma unroll
            for (int e = 0; e < 8; ++e) red[tid][e] += red[tid + off * JT][e];
        }
        __syncthreads();
    }
    if (rsub == 0) {
        float* slot = statsP + (size_t)(blockIdx.x & (NSLOT - 1)) * 256;
#pragma unroll
        for (int e = 0; e < 4; ++e) {
            atomicAdd(&slot[j0 + e],     red[tid][e]);
            atomicAdd(&slot[D + j0 + e], red[tid][4 + e]);
        }
    }
}

template<int D>
__global__ void gn_finalize_kernel(const float* __restrict__ part, float* __restrict__ ac,
                                   const float* __restrict__ gw, const float* __restrict__ gb,
                                   const float* __restrict__ gm, float inv_n)
{
    int j = threadIdx.x;
    if (j >= D) return;
    float s1 = 0.f, s2 = 0.f;
    for (int t = 0; t < NSLOT; ++t) {
        s1 += part[(size_t)t * 256 + j];
        s2 += part[(size_t)t * 256 + D + j];
    }
    float mean = s1 * inv_n;
    float ex2  = s2 * inv_n;
    float m    = gm[j];
    float var  = ex2 - (2.f * m - m * m) * mean * mean;
    float a    = gw[j] * rsqrtf(var + 1e-5f);
    float c    = gb[j] - a * m * mean;
    ac[j]     = a;
    ac[D + j] = c;
}

// ---------------- fused decoder tail: 64 -> relu32 -> relu16 -> sigmoid(1) ----------------
__global__ __launch_bounds__(256) void dec_tail_kernel(
    const float* __restrict__ in, const float* __restrict__ W1, const float* __restrict__ b1,
    const float* __restrict__ W2, const float* __restrict__ b2,
    const float* __restrict__ W3, const float* __restrict__ b3,
    float* __restrict__ out, int n)
{
    int t = blockIdx.x * THREADS + threadIdx.x;
    if (t >= n) return;

    float x[64];
#pragma unroll
    for (int q = 0; q < 16; ++q)
        *(float4*)&x[q * 4] = *(const float4*)&in[(size_t)t * 64 + q * 4];

    float h1[32];
#pragma unroll
    for (int j = 0; j < 32; ++j) h1[j] = b1[j];
#pragma unroll 8
    for (int k = 0; k < 64; ++k) {
        const float xk = x[k];
#pragma unroll
        for (int j = 0; j < 32; ++j) h1[j] = fmaf(xk, W1[k * 32 + j], h1[j]);
    }
#pragma unroll
    for (int j = 0; j < 32; ++j) h1[j] = fmaxf(h1[j], 0.f);

    float h2[16];
#pragma unroll
    for (int j = 0; j < 16; ++j) h2[j] = b2[j];
#pragma unroll 8
    for (int k = 0; k < 32; ++k) {
        const float hk = h1[k];
#pragma unroll
        for (int j = 0; j < 16; ++j) h2[j] = fmaf(hk, W2[k * 16 + j], h2[j]);
    }

    float acc = b3[0];
#pragma unroll
    for (int k = 0; k < 16; ++k) acc = fmaf(fmaxf(h2[k], 0.f), W3[k], acc);
    out[t] = 1.0f / (1.0f + expf(-acc));
}

// ---------------- launch ----------------

extern "C" void kernel_launch(void* const* d_in, const int* in_sizes, int n_in,
                              void* d_out, int out_size, void* d_ws, size_t ws_size,
                              hipStream_t stream)
{
    const float* local_x    = (const float*)d_in[0];
    const int*   local_type = (const int*)d_in[1];
    const float* voxel_x    = (const float*)d_in[2];
    const int*   voxel_type = (const int*)d_in[3];
    const int*   edge_index = (const int*)d_in[4];
    const float* label      = (const float*)d_in[5];
    const float* We1 = (const float*)d_in[6],  *be1 = (const float*)d_in[7];
    const float* We2 = (const float*)d_in[8],  *be2 = (const float*)d_in[9];
    const float *Wc[4], *bc[4], *gw[4], *gb[4], *gm[4];
    for (int i = 0; i < 4; ++i) {
        Wc[i] = (const float*)d_in[10 + i * 5];
        bc[i] = (const float*)d_in[11 + i * 5];
        gw[i] = (const float*)d_in[12 + i * 5];
        gb[i] = (const float*)d_in[13 + i * 5];
        gm[i] = (const float*)d_in[14 + i * 5];
    }
    const float* Wd0 = (const float*)d_in[30], *bd0 = (const float*)d_in[31];
    const float* Wd1 = (const float*)d_in[32], *bd1 = (const float*)d_in[33];
    const float* Wd2 = (const float*)d_in[34], *bd2 = (const float*)d_in[35];
    const float* Wd3 = (const float*)d_in[36], *bd3 = (const float*)d_in[37];

    const int n  = in_sizes[2] / 6;    // 200000
    const int E  = in_sizes[4] / 2;    // 1200000
    const int nl = in_sizes[0] / 19;   // 400
    const int* src = edge_index;
    const int* dst = edge_index + E;

    // Workspace (~217 MB): [ac][means][blocksums][stats_part][WT0..3][rowptr][dinv]
    // [esrc E][qpos E][A f32 n*128][B f32 n*128]
    auto align256 = [](size_t x) { return (x + 255) & ~(size_t)255; };
    char* w = (char*)d_ws;
    float* ac_all = (float*)w;
    float* means  = (float*)(w + 4096);
    int* blocksums = (int*)(w + 8192);
    float* stats_part = (float*)(w + 8192 + 1024);
    size_t off = 8192 + 1024 + 4 * NSLOT * 256 * sizeof(float);
    ushort_t* wt0 = (ushort_t*)(w + off); off += align256(16384 * 2);  // We2^T 128x128
    ushort_t* wt1 = (ushort_t*)(w + off); off += align256(8192 * 2);   // Wc0^T
    ushort_t* wt2 = (ushort_t*)(w + off); off += align256(8192 * 2);   // Wc3^T
    ushort_t* wt3 = (ushort_t*)(w + off); off += align256(8192 * 2);   // Wd0^T
    int*   rowptr = (int*)(w + off);   off += align256((size_t)(n + 1) * 4);
    float* dinv   = (float*)(w + off); off += align256((size_t)n * 4);
    int*   esrc   = (int*)(w + off);   off += align256((size_t)E * 4);
    int*   qpos   = (int*)(w + off);   off += align256((size_t)E * 4);
    float* A    = (float*)(w + off);
    float* B    = A + (size_t)n * 128;
    float* A_lo = A;
    float* A_hi = A + (size_t)n * 64;
    float* B_lo = B;
    float* B_hi = B + (size_t)n * 64;
    int*   degi = (int*)A;               // transient alias (pre-enc1 only)

    const float inv_n = 1.0f / (float)n;
    auto cdiv = [](long long a, long long b) { return (int)((a + b - 1) / b); };
    const int nb = cdiv(n, 1024);

    float* part0 = stats_part + 0 * NSLOT * 256;
    float* part1 = stats_part + 1 * NSLOT * 256;
    float* part2 = stats_part + 2 * NSLOT * 256;
    float* part3 = stats_part + 3 * NSLOT * 256;
    float* ac0 = ac_all + 0, *ac1 = ac_all + 256, *ac2 = ac_all + 512, *ac3 = ac_all + 768;

    hipMemsetAsync(stats_part, 0, 4 * NSLOT * 256 * sizeof(float), stream);
    hipMemsetAsync(degi, 0, (size_t)n * sizeof(int), stream);

    // one-time bf16 W^T prep (L2-resident afterwards)
    wtrans_kernel<<<cdiv(128 * 128, 256), 256, 0, stream>>>(We2,   wt0, 128, 128);
    wtrans_kernel<<<cdiv(128 * 64, 256), 256, 0, stream>>>(Wc[0], wt1, 128, 64);
    wtrans_kernel<<<cdiv(64 * 128, 256), 256, 0, stream>>>(Wc[3], wt2, 64, 128);
    wtrans_kernel<<<cdiv(128 * 64, 256), 256, 0, stream>>>(Wd0,   wt3, 128, 64);

    local_means_kernel<<<1, 256, 0, stream>>>(local_x, local_type, means, nl);
    hist_kernel<<<cdiv(E, 256), 256, 0, stream>>>(dst, degi, qpos, E);
    scan_part1_kernel<<<nb, 256, 0, stream>>>(degi, blocksums, n);
    scan_part2_kernel<<<1, 256, 0, stream>>>(blocksums, nb);
    scan_part3_kernel<<<nb, 256, 0, stream>>>(degi, blocksums, rowptr, dinv, n, E);
    fill_kernel<<<cdiv(E, 256), 256, 0, stream>>>(src, dst, qpos, rowptr, esrc, E);
    build_x0_kernel<<<cdiv((long long)n * 32, 256), 256, 0, stream>>>(means, voxel_type, voxel_x, label, B_lo, n);

    const int gagg  = 2048;
    const int gmfma = cdiv(n, 128);

    // enc1 (f32): X0=B_lo(32w) -> A(128)
    mlp_kernel<32, 128, 128, 8, true, true, false, false><<<cdiv(n, 128), 256, 0, stream>>>(B_lo, A, We1, be1, nullptr, nullptr, n);
    // enc2 (MFMA): A -> B
    mfma_mlp_kernel<128, 128, true, true, false, false><<<gmfma, 256, 0, stream>>>(A, B, wt0, be2, nullptr, nullptr, n);

    // conv0 (MFMA): B -> T0=A_lo(64w, dinv-scaled); gather -> A_hi [+stats0]
    mfma_mlp_kernel<128, 64, false, false, false, true><<<gmfma, 256, 0, stream>>>(B, A_lo, wt1, nullptr, nullptr, dinv, n);
    gather_agg_kernel<64><<<gagg, 256, 0, stream>>>(A_lo, A_hi, rowptr, esrc, dinv, bc[0], part0, n);
    gn_finalize_kernel<64><<<1, 64, 0, stream>>>(part0, ac0, gw[0], gb[0], gm[0], inv_n);

    // conv1 (f32): A_hi(+GN ac0) -> T1=B_lo(32w, dinv-scaled); gather -> B_hi(32w) [+stats1]
    mlp_kernel<64, 32, 256, 4, false, false, true, true><<<cdiv(n, 256), 256, 0, stream>>>(A_hi, B_lo, Wc[1], nullptr, ac0, dinv, n);
    gather_agg_kernel<32><<<gagg, 256, 0, stream>>>(B_lo, B_hi, rowptr, esrc, dinv, bc[1], part1, n);
    gn_finalize_kernel<32><<<1, 32, 0, stream>>>(part1, ac1, gw[1], gb[1], gm[1], inv_n);

    // conv2 (agg pre-GEMM, fused transform): gather_pre<32>(B_hi,+GN ac1) -> G2=A_lo(32w);
    // f32 GEMM -> O2=B_hi(64w); stats2
    gather_pre_kernel<32><<<gagg, 256, 0, stream>>>(B_hi, A_lo, rowptr, esrc, dinv, ac1, n);
    mlp_kernel<32, 64, 256, 8, false, true, false, false><<<cdiv(n, 256), 256, 0, stream>>>(A_lo, B_hi, Wc[2], bc[2], nullptr, nullptr, n);
    gn_stats_kernel<64><<<cdiv(n, 512), 256, 0, stream>>>(B_hi, part2, n);
    gn_finalize_kernel<64><<<1, 64, 0, stream>>>(part2, ac2, gw[2], gb[2], gm[2], inv_n);

    // conv3 (agg pre-GEMM, fused transform): gather_pre<64>(B_hi,+GN ac2) -> G3=B_lo(64w);
    // MFMA -> A(128); stats3
    gather_pre_kernel<64><<<gagg, 256, 0, stream>>>(B_hi, B_lo, rowptr, esrc, dinv, ac2, n);
    mfma_mlp_kernel<64, 128, false, true, false, false><<<gmfma, 256, 0, stream>>>(B_lo, A, wt2, bc[3], nullptr, nullptr, n);
    gn_stats_kernel<128><<<cdiv(n, 256), 256, 0, stream>>>(A, part3, n);
    gn_finalize_kernel<128><<<1, 128, 0, stream>>>(part3, ac3, gw[3], gb[3], gm[3], inv_n);

    // dec0 (MFMA): A(+GN ac3) -> D0=B_lo(64w); fused tail -> out
    mfma_mlp_kernel<128, 64, true, true, true, false><<<gmfma, 256, 0, stream>>>(A, B_lo, wt3, bd0, ac3, nullptr, n);
    dec_tail_kernel<<<cdiv(n, 256), 256, 0, stream>>>(B_lo, Wd1, bd1, Wd2, bd2, Wd3, bd3, (float*)d_out, n);
}

// Round 15
// 654.212 us; speedup vs baseline: 1.3453x; 1.0164x over previous
//
#include <hip/hip_runtime.h>
#include <hip/hip_bf16.h>
#include <cstddef>

#define THREADS 256
#define NSLOT 64

typedef unsigned short ushort_t;
typedef unsigned int uint_t;
typedef __attribute__((ext_vector_type(8))) short bf16x8;
typedef __attribute__((ext_vector_type(4))) float f32x4;

__device__ __forceinline__ ushort_t f2b(float f) {
    uint_t i = __float_as_uint(f);
    uint_t r = i + 0x7fffu + ((i >> 16) & 1u);
    return (ushort_t)(r >> 16);
}

// ---------------- small kernels ----------------

__global__ __launch_bounds__(256) void local_means_kernel(const float* __restrict__ lx,
                                                          const int* __restrict__ lt,
                                                          float* __restrict__ means, int nl)
{
    __shared__ float slx[512 * 19];
    __shared__ int   slt[512];
    const int tid = threadIdx.x;
    for (int i = tid; i < nl * 19; i += 256) slx[i] = lx[i];
    for (int i = tid; i < nl; i += 256) slt[i] = lt[i];
    __syncthreads();
    if (tid >= 7 * 19) return;
    int c = tid / 19, dd = tid % 19;
    float s = 0.f; int cnt = 0;
    for (int i = 0; i < nl; ++i) {
        if (slt[i] == c) { s += slx[i * 19 + dd]; cnt++; }
    }
    means[tid] = cnt > 0 ? s / (float)cnt : 0.f;
}

// hist + per-edge slot index (q-trick)
__global__ void hist_kernel(const int* __restrict__ dst, int* __restrict__ degi,
                            int* __restrict__ qpos, int E)
{
    int t = blockIdx.x * THREADS + threadIdx.x;
    if (t < E) qpos[t] = atomicAdd(&degi[dst[t]], 1);
}

__global__ __launch_bounds__(256) void scan_part1_kernel(const int* __restrict__ degi,
                                                         int* __restrict__ blocksums, int n)
{
    const int tid = threadIdx.x;
    const int idx = blockIdx.x * 1024 + tid * 4;
    int v = 0;
    if (idx + 3 < n) {
        int4 d = *(const int4*)&degi[idx];
        v = d.x + d.y + d.z + d.w;
    } else {
        for (int i = 0; i < 4; ++i) if (idx + i < n) v += degi[idx + i];
    }
    __shared__ int s[256];
    s[tid] = v;
    __syncthreads();
    for (int off = 128; off >= 1; off >>= 1) {
        if (tid < off) s[tid] += s[tid + off];
        __syncthreads();
    }
    if (tid == 0) blocksums[blockIdx.x] = s[0];
}

__global__ __launch_bounds__(256) void scan_part2_kernel(int* __restrict__ blocksums, int nb)
{
    __shared__ int s[256];
    const int tid = threadIdx.x;
    int v = (tid < nb) ? blocksums[tid] : 0;
    s[tid] = v;
    __syncthreads();
    for (int off = 1; off < 256; off <<= 1) {
        int t = (tid >= off) ? s[tid - off] : 0;
        __syncthreads();
        s[tid] += t;
        __syncthreads();
    }
    if (tid < nb) blocksums[tid] = s[tid] - v;
}

__global__ __launch_bounds__(256) void scan_part3_kernel(const int* __restrict__ degi,
                                                         const int* __restrict__ blocksums,
                                                         int* __restrict__ rowptr,
                                                         float* __restrict__ dinv, int n, int E)
{
    const int tid = threadIdx.x;
    const int idx = blockIdx.x * 1024 + tid * 4;
    int d0 = 0, d1 = 0, d2 = 0, d3 = 0;
    if (idx + 3 < n) {
        int4 d = *(const int4*)&degi[idx];
        d0 = d.x; d1 = d.y; d2 = d.z; d3 = d.w;
    } else {
        if (idx     < n) d0 = degi[idx];
        if (idx + 1 < n) d1 = degi[idx + 1];
        if (idx + 2 < n) d2 = degi[idx + 2];
        if (idx + 3 < n) d3 = degi[idx + 3];
    }
    const int v = d0 + d1 + d2 + d3;
    __shared__ int s[256];
    s[tid] = v;
    __syncthreads();
    for (int off = 1; off < 256; off <<= 1) {
        int t = (tid >= off) ? s[tid - off] : 0;
        __syncthreads();
        s[tid] += t;
        __syncthreads();
    }
    int run = blocksums[blockIdx.x] + s[tid] - v;
    if (idx + 3 < n) {
        int4 o;
        o.x = run; run += d0;
        o.y = run; run += d1;
        o.z = run; run += d2;
        o.w = run;
        *(int4*)&rowptr[idx] = o;
        float4 dv;
        dv.x = rsqrtf((float)d0 + 1.0f);
        dv.y = rsqrtf((float)d1 + 1.0f);
        dv.z = rsqrtf((float)d2 + 1.0f);
        dv.w = rsqrtf((float)d3 + 1.0f);
        *(float4*)&dinv[idx] = dv;
    } else {
        if (idx     < n) { rowptr[idx]     = run; dinv[idx]     = rsqrtf((float)d0 + 1.0f); run += d0; }
        if (idx + 1 < n) { rowptr[idx + 1] = run; dinv[idx + 1] = rsqrtf((float)d1 + 1.0f); run += d1; }
        if (idx + 2 < n) { rowptr[idx + 2] = run; dinv[idx + 2] = rsqrtf((float)d2 + 1.0f); run += d2; }
        if (idx + 3 < n) { rowptr[idx + 3] = run; dinv[idx + 3] = rsqrtf((float)d3 + 1.0f); }
    }
    if (blockIdx.x == 0 && tid == 0) rowptr[n] = E;
}

__global__ void fill_kernel(const int* __restrict__ src, const int* __restrict__ dst,
                            const int* __restrict__ qpos, const int* __restrict__ rowptr,
                            int* __restrict__ esrc, int E)
{
    int t = blockIdx.x * THREADS + threadIdx.x;
    if (t >= E) return;
    esrc[rowptr[dst[t]] + qpos[t]] = src[t];
}

__global__ void build_x0_kernel(const float* __restrict__ means,
                                const int* __restrict__ vt,
                                const float* __restrict__ vx,
                                const float* __restrict__ label,
                                float* __restrict__ out, int n)
{
    int tid = blockIdx.x * THREADS + threadIdx.x;
    int node = tid >> 5, c = tid & 31;
    if (node >= n) return;
    float v;
    if (c < 19)      v = means[vt[node] * 19 + c];
    else if (c < 25) v = vx[node * 6 + (c - 19)];
    else             v = label[node * 7 + (c - 25)];
    out[(size_t)node * 32 + c] = v;
}

__global__ void wtrans_kernel(const float* __restrict__ W, ushort_t* __restrict__ WT,
                              int din, int dout)
{
    int t = blockIdx.x * THREADS + threadIdx.x;
    if (t >= din * dout) return;
    int k = t / dout, c = t % dout;
    WT[(size_t)c * din + k] = f2b(W[t]);
}

// ---------------- f32 dense layer (split-J), optional fused slot-replicated stats ----
template<int DIN, int DOUT, int BN, int JPER, bool RELU, bool BIAS, bool TRANSFORM, bool SCALE, bool STATS>
__global__ __launch_bounds__(256) void mlp_kernel(
    const float* __restrict__ in, float* __restrict__ out,
    const float* __restrict__ W, const float* __restrict__ bias,
    const float* __restrict__ tr, const float* __restrict__ rowscale,
    float* __restrict__ statsP, int n)
{
    constexpr int KT  = 32;
    constexpr int TJ  = DOUT / JPER;
    constexpr int TN  = 256 / TJ;
    constexpr int NPT = BN / TN;
    constexpr int JQ  = JPER / 4;
    constexpr int CS  = 4 * TJ;
    constexpr int BNP = BN + 4;

    __shared__ float Wt[KT * DOUT];
    __shared__ float xT[KT][BNP];

    const int tid   = threadIdx.x;
    const int nbase = blockIdx.x * BN;
    const int tj = tid % TJ, tn = tid / TJ;
    const int j0 = tj * 4, n0 = tn * NPT;

    float acc[NPT][JPER];
#pragma unroll
    for (int p = 0; p < NPT; ++p)
#pragma unroll
        for (int j = 0; j < JPER; ++j) acc[p][j] = 0.f;

    for (int kt = 0; kt < DIN; kt += KT) {
        __syncthreads();
        for (int i = tid * 4; i < KT * DOUT; i += THREADS * 4) {
            *(float4*)&Wt[i] = *(const float4*)&W[(size_t)kt * DOUT + i];
        }
        for (int i = tid; i < BN * (KT / 4); i += THREADS) {
            int node = i / (KT / 4);
            int kq   = i % (KT / 4);
            int g    = nbase + node;
            float4 v = make_float4(0.f, 0.f, 0.f, 0.f);
            if (g < n) {
                v = *(const float4*)&in[(size_t)g * DIN + kt + kq * 4];
                if (TRANSFORM) {
                    const float4 a = *(const float4*)&tr[kt + kq * 4];
                    const float4 c = *(const float4*)&tr[DIN + kt + kq * 4];
                    v.x = fmaxf(fmaf(v.x, a.x, c.x), 0.f);
                    v.y = fmaxf(fmaf(v.y, a.y, c.y), 0.f);
                    v.z = fmaxf(fmaf(v.z, a.z, c.z), 0.f);
                    v.w = fmaxf(fmaf(v.w, a.w, c.w), 0.f);
                }
            }
            xT[kq * 4 + 0][node] = v.x;
            xT[kq * 4 + 1][node] = v.y;
            xT[kq * 4 + 2][node] = v.z;
            xT[kq * 4 + 3][node] = v.w;
        }
        __syncthreads();
#pragma unroll 4
        for (int kk = 0; kk < KT; ++kk) {
            float wv[JPER];
#pragma unroll
            for (int q = 0; q < JQ; ++q)
                *(float4*)&wv[q * 4] = *(const float4*)&Wt[kk * DOUT + q * CS + j0];
            float xv[NPT];
#pragma unroll
            for (int q = 0; q < NPT / 4; ++q)
                *(float4*)&xv[q * 4] = *(const float4*)&xT[kk][n0 + q * 4];
#pragma unroll
            for (int p = 0; p < NPT; ++p)
#pragma unroll
                for (int j = 0; j < JPER; ++j)
                    acc[p][j] = fmaf(xv[p], wv[j], acc[p][j]);
        }
    }

    float bv[JPER];
#pragma unroll
    for (int j = 0; j < JPER; ++j) bv[j] = 0.f;
    if (BIAS) {
#pragma unroll
        for (int q = 0; q < JQ; ++q)
            *(float4*)&bv[q * 4] = *(const float4*)&bias[q * CS + j0];
    }

    float s1[JPER], s2[JPER];
#pragma unroll
    for (int j = 0; j < JPER; ++j) { s1[j] = 0.f; s2[j] = 0.f; }

#pragma unroll
    for (int p = 0; p < NPT; ++p) {
        const int g = nbase + n0 + p;
        if (g >= n) continue;
        float rs = 1.f;
        if (SCALE) rs = rowscale[g];
#pragma unroll
        for (int q = 0; q < JQ; ++q) {
            float4 o;
            o.x = acc[p][q * 4 + 0] + bv[q * 4 + 0];
            o.y = acc[p][q * 4 + 1] + bv[q * 4 + 1];
            o.z = acc[p][q * 4 + 2] + bv[q * 4 + 2];
            o.w = acc[p][q * 4 + 3] + bv[q * 4 + 3];
            if (RELU) {
                o.x = fmaxf(o.x, 0.f); o.y = fmaxf(o.y, 0.f);
                o.z = fmaxf(o.z, 0.f); o.w = fmaxf(o.w, 0.f);
            }
            if (SCALE) { o.x *= rs; o.y *= rs; o.z *= rs; o.w *= rs; }
            if (STATS) {
                s1[q * 4 + 0] += o.x; s2[q * 4 + 0] = fmaf(o.x, o.x, s2[q * 4 + 0]);
                s1[q * 4 + 1] += o.y; s2[q * 4 + 1] = fmaf(o.y, o.y, s2[q * 4 + 1]);
                s1[q * 4 + 2] += o.z; s2[q * 4 + 2] = fmaf(o.z, o.z, s2[q * 4 + 2]);
                s1[q * 4 + 3] += o.w; s2[q * 4 + 3] = fmaf(o.w, o.w, s2[q * 4 + 3]);
            }
            *(float4*)&out[(size_t)g * DOUT + q * CS + j0] = o;
        }
    }

    if constexpr (STATS) {
        __shared__ float red[256][2 * JPER + 1];
#pragma unroll
        for (int j = 0; j < JPER; ++j) { red[tid][j] = s1[j]; red[tid][JPER + j] = s2[j]; }
        __syncthreads();
#pragma unroll
        for (int off = TN / 2; off >= 1; off >>= 1) {
            if (tn < off) {
#pragma unroll
                for (int j = 0; j < 2 * JPER; ++j) red[tid][j] += red[tid + off * TJ][j];
            }
            __syncthreads();
        }
        if (tn == 0) {
            float* slot = statsP + (size_t)(blockIdx.x & (NSLOT - 1)) * 256;
#pragma unroll
            for (int q = 0; q < JQ; ++q)
#pragma unroll
                for (int e = 0; e < 4; ++e) {
                    atomicAdd(&slot[q * CS + j0 + e],        red[tid][q * 4 + e]);
                    atomicAdd(&slot[DOUT + q * CS + j0 + e], red[tid][JPER + q * 4 + e]);
                }
        }
    }
}

// ---------------- bf16-MFMA dense layer; WT pre-converted bf16 [DOUT][DIN];
// optional fused slot-replicated stats on written output ----------
template<int DIN, int DOUT, bool RELU, bool BIAS, bool TRANSFORM, bool SCALE, bool STATS>
__global__ __launch_bounds__(256) void mfma_mlp_kernel(
    const float* __restrict__ in, float* __restrict__ out,
    const ushort_t* __restrict__ WT, const float* __restrict__ bias,
    const float* __restrict__ tr, const float* __restrict__ rowscale,
    float* __restrict__ statsP, int n)
{
    constexpr int BN  = 128;
    constexpr int KT  = 32;
    constexpr int NT  = DIN / KT;
    constexpr int LDK = 40;
    constexpr int WM  = 2, WN = 2;
    constexpr int MW  = BN / WM;
    constexpr int NW  = DOUT / WN;
    constexpr int MR  = MW / 16;
    constexpr int NR  = NW / 16;

    __shared__ ushort_t xA[BN * LDK];

    const int tid   = threadIdx.x;
    const int wid   = tid >> 6;
    const int lane  = tid & 63;
    const int wm    = wid >> 1, wn = wid & 1;
    const int nbase = blockIdx.x * BN;
    const int l16   = lane & 15;
    const int lk8   = (lane >> 4) * 8;

    f32x4 acc[MR][NR];
#pragma unroll
    for (int mi = 0; mi < MR; ++mi)
#pragma unroll
        for (int ni = 0; ni < NR; ++ni)
#pragma unroll
            for (int j = 0; j < 4; ++j) acc[mi][ni][j] = 0.f;

    for (int t = 0; t < NT; ++t) {
        const int kt = t * KT;
        __syncthreads();
        for (int i = tid; i < BN * (KT / 4); i += 256) {
            const int row = i / (KT / 4);
            const int kq  = (i % (KT / 4)) * 4;
            const int g   = nbase + row;
            float4 v = make_float4(0.f, 0.f, 0.f, 0.f);
            if (g < n) {
                v = *(const float4*)&in[(size_t)g * DIN + kt + kq];
                if (TRANSFORM) {
                    const float4 a = *(const float4*)&tr[kt + kq];
                    const float4 c = *(const float4*)&tr[DIN + kt + kq];
                    v.x = fmaxf(fmaf(v.x, a.x, c.x), 0.f);
                    v.y = fmaxf(fmaf(v.y, a.y, c.y), 0.f);
                    v.z = fmaxf(fmaf(v.z, a.z, c.z), 0.f);
                    v.w = fmaxf(fmaf(v.w, a.w, c.w), 0.f);
                }
            }
            ushort4 b;
            b.x = f2b(v.x); b.y = f2b(v.y); b.z = f2b(v.z); b.w = f2b(v.w);
            *(ushort4*)&xA[row * LDK + kq] = b;
        }
        __syncthreads();

        bf16x8 af[MR], bf[NR];
#pragma unroll
        for (int mi = 0; mi < MR; ++mi)
            af[mi] = *(const bf16x8*)&xA[(wm * MW + mi * 16 + l16) * LDK + lk8];
#pragma unroll
        for (int ni = 0; ni < NR; ++ni)
            bf[ni] = *(const bf16x8*)&WT[(size_t)(wn * NW + ni * 16 + l16) * DIN + kt + lk8];
#pragma unroll
        for (int mi = 0; mi < MR; ++mi)
#pragma unroll
            for (int ni = 0; ni < NR; ++ni)
                acc[mi][ni] = __builtin_amdgcn_mfma_f32_16x16x32_bf16(
                    af[mi], bf[ni], acc[mi][ni], 0, 0, 0);
    }

    float bv[NR];
#pragma unroll
    for (int ni = 0; ni < NR; ++ni)
        bv[ni] = BIAS ? bias[wn * NW + ni * 16 + l16] : 0.f;

    float s1[NR], s2[NR];
#pragma unroll
    for (int ni = 0; ni < NR; ++ni) { s1[ni] = 0.f; s2[ni] = 0.f; }

#pragma unroll
    for (int mi = 0; mi < MR; ++mi) {
#pragma unroll
        for (int j = 0; j < 4; ++j) {
            const int r = wm * MW + mi * 16 + (lane >> 4) * 4 + j;
            const int g = nbase + r;
            if (g >= n) continue;
            float rs = 1.f;
            if (SCALE) rs = rowscale[g];
#pragma unroll
            for (int ni = 0; ni < NR; ++ni) {
                const int col = wn * NW + ni * 16 + l16;
                float v = acc[mi][ni][j] + bv[ni];
                if (RELU) v = fmaxf(v, 0.f);
                if (SCALE) v *= rs;
                if (STATS) { s1[ni] += v; s2[ni] = fmaf(v, v, s2[ni]); }
                out[(size_t)g * DOUT + col] = v;
            }
        }
    }

    if constexpr (STATS) {
        __shared__ float sred[2][DOUT];
        for (int i = tid; i < 2 * DOUT; i += 256) ((float*)sred)[i] = 0.f;
        __syncthreads();
#pragma unroll
        for (int ni = 0; ni < NR; ++ni) {
            const int col = wn * NW + ni * 16 + l16;
            atomicAdd(&sred[0][col], s1[ni]);
            atomicAdd(&sred[1][col], s2[ni]);
        }
        __syncthreads();
        if (tid < DOUT) {
            float* slot = statsP + (size_t)(blockIdx.x & (NSLOT - 1)) * 256;
            atomicAdd(&slot[tid],        sred[0][tid]);
            atomicAdd(&slot[DOUT + tid], sred[1][tid]);
        }
    }
}

// ---------------- CSR gather aggregation (post-GEMM), one tile per block ----
template<int D>
__global__ __launch_bounds__(256) void gather_agg_kernel(
    const float* __restrict__ y, float* __restrict__ out,
    const int* __restrict__ rowptr, const int* __restrict__ esrc,
    const float* __restrict__ dinv,
    const float* __restrict__ bias, float* __restrict__ statsP, int n)
{
    constexpr int JT  = D / 8;
    constexpr int NPB = 256 / JT;
    const int tid  = threadIdx.x;
    const int jq   = tid % JT;
    const int nsub = tid / JT;
    const int j0   = jq * 8;

    float bv[8];
#pragma unroll
    for (int e = 0; e < 8; ++e) bv[e] = bias[j0 + e];

    float s1[8], s2[8];
#pragma unroll
    for (int e = 0; e < 8; ++e) { s1[e] = 0.f; s2[e] = 0.f; }

    const int node = blockIdx.x * NPB + nsub;
    if (node < n) {
        const int rb = rowptr[node], re = rowptr[node + 1];
        const float dd = dinv[node];
        float acc[8];
        *(float4*)&acc[0] = *(const float4*)&y[(size_t)node * D + j0];
        *(float4*)&acc[4] = *(const float4*)&y[(size_t)node * D + j0 + 4];
        int k = rb;
        for (; k + 3 < re; k += 4) {
            const int sa = esrc[k], sb = esrc[k + 1];
            const int sc = esrc[k + 2], sd = esrc[k + 3];
            float4 a0 = *(const float4*)&y[(size_t)sa * D + j0];
            float4 a1 = *(const float4*)&y[(size_t)sa * D + j0 + 4];
            float4 b0 = *(const float4*)&y[(size_t)sb * D + j0];
            float4 b1 = *(const float4*)&y[(size_t)sb * D + j0 + 4];
            float4 c0 = *(const float4*)&y[(size_t)sc * D + j0];
            float4 c1 = *(const float4*)&y[(size_t)sc * D + j0 + 4];
            float4 e0 = *(const float4*)&y[(size_t)sd * D + j0];
            float4 e1 = *(const float4*)&y[(size_t)sd * D + j0 + 4];
            acc[0] += (a0.x + b0.x) + (c0.x + e0.x);
            acc[1] += (a0.y + b0.y) + (c0.y + e0.y);
            acc[2] += (a0.z + b0.z) + (c0.z + e0.z);
            acc[3] += (a0.w + b0.w) + (c0.w + e0.w);
            acc[4] += (a1.x + b1.x) + (c1.x + e1.x);
            acc[5] += (a1.y + b1.y) + (c1.y + e1.y);
            acc[6] += (a1.z + b1.z) + (c1.z + e1.z);
            acc[7] += (a1.w + b1.w) + (c1.w + e1.w);
        }
        for (; k < re; ++k) {
            const int sa = esrc[k];
            float4 a0 = *(const float4*)&y[(size_t)sa * D + j0];
            float4 a1 = *(const float4*)&y[(size_t)sa * D + j0 + 4];
            acc[0] += a0.x; acc[1] += a0.y; acc[2] += a0.z; acc[3] += a0.w;
            acc[4] += a1.x; acc[5] += a1.y; acc[6] += a1.z; acc[7] += a1.w;
        }
        float o[8];
#pragma unroll
        for (int e = 0; e < 8; ++e) {
            o[e] = fmaf(acc[e], dd, bv[e]);
            s1[e] += o[e];
            s2[e] = fmaf(o[e], o[e], s2[e]);
        }
        *(float4*)&out[(size_t)node * D + j0]     = make_float4(o[0], o[1], o[2], o[3]);
        *(float4*)&out[(size_t)node * D + j0 + 4] = make_float4(o[4], o[5], o[6], o[7]);
    }

    __shared__ float red[256][17];
#pragma unroll
    for (int e = 0; e < 8; ++e) { red[tid][e] = s1[e]; red[tid][8 + e] = s2[e]; }
    __syncthreads();
#pragma unroll
    for (int off = NPB / 2; off >= 1; off >>= 1) {
        if (nsub < off) {
#pragma unroll
            for (int e = 0; e < 16; ++e) red[tid][e] += red[tid + off * JT][e];
        }
        __syncthreads();
    }
    if (nsub == 0) {
        float* slot = statsP + (size_t)(blockIdx.x & (NSLOT - 1)) * 256;
#pragma unroll
        for (int e = 0; e < 8; ++e) {
            atomicAdd(&slot[j0 + e],     red[tid][e]);
            atomicAdd(&slot[D + j0 + e], red[tid][8 + e]);
        }
    }
}

// ---------------- CSR gather aggregation (pre-GEMM), fused GN+ReLU+dinv, 1 tile/block ----
template<int D>
__global__ __launch_bounds__(256) void gather_pre_kernel(
    const float* __restrict__ x, float* __restrict__ out,
    const int* __restrict__ rowptr, const int* __restrict__ esrc,
    const float* __restrict__ dinv, const float* __restrict__ tr, int n)
{
    constexpr int JT  = D / 8;
    constexpr int NPB = 256 / JT;
    const int tid  = threadIdx.x;
    const int jq   = tid % JT;
    const int nsub = tid / JT;
    const int j0   = jq * 8;

    float av[8], cv[8];
#pragma unroll
    for (int e = 0; e < 8; ++e) { av[e] = tr[j0 + e]; cv[e] = tr[D + j0 + e]; }

    const int node = blockIdx.x * NPB + nsub;
    if (node >= n) return;
    const int rb = rowptr[node], re = rowptr[node + 1];
    const float dd = dinv[node];
    float acc[8], v[8];
    *(float4*)&v[0] = *(const float4*)&x[(size_t)node * D + j0];
    *(float4*)&v[4] = *(const float4*)&x[(size_t)node * D + j0 + 4];
#pragma unroll
    for (int e = 0; e < 8; ++e)
        acc[e] = fmaxf(fmaf(v[e], av[e], cv[e]), 0.f) * dd;
    int k = rb;
    for (; k + 3 < re; k += 4) {
        const int sa = esrc[k], sb = esrc[k + 1];
        const int sc = esrc[k + 2], sd = esrc[k + 3];
        const float da = dinv[sa], db = dinv[sb];
        const float dc = dinv[sc], de = dinv[sd];
        float va[8], vb[8], vc[8], ve[8];
        *(float4*)&va[0] = *(const float4*)&x[(size_t)sa * D + j0];
        *(float4*)&va[4] = *(const float4*)&x[(size_t)sa * D + j0 + 4];
        *(float4*)&vb[0] = *(const float4*)&x[(size_t)sb * D + j0];
        *(float4*)&vb[4] = *(const float4*)&x[(size_t)sb * D + j0 + 4];
        *(float4*)&vc[0] = *(const float4*)&x[(size_t)sc * D + j0];
        *(float4*)&vc[4] = *(const float4*)&x[(size_t)sc * D + j0 + 4];
        *(float4*)&ve[0] = *(const float4*)&x[(size_t)sd * D + j0];
        *(float4*)&ve[4] = *(const float4*)&x[(size_t)sd * D + j0 + 4];
#pragma unroll
        for (int e = 0; e < 8; ++e) {
            float fa = fmaxf(fmaf(va[e], av[e], cv[e]), 0.f) * da;
            float fb = fmaxf(fmaf(vb[e], av[e], cv[e]), 0.f) * db;
            float fc = fmaxf(fmaf(vc[e], av[e], cv[e]), 0.f) * dc;
            float fe = fmaxf(fmaf(ve[e], av[e], cv[e]), 0.f) * de;
            acc[e] += (fa + fb) + (fc + fe);
        }
    }
    for (; k < re; ++k) {
        const int sa = esrc[k];
        const float da = dinv[sa];
        float va[8];
        *(float4*)&va[0] = *(const float4*)&x[(size_t)sa * D + j0];
        *(float4*)&va[4] = *(const float4*)&x[(size_t)sa * D + j0 + 4];
#pragma unroll
        for (int e = 0; e < 8; ++e)
            acc[e] += fmaxf(fmaf(va[e], av[e], cv[e]), 0.f) * da;
    }
    float4 o0 = make_float4(acc[0] * dd, acc[1] * dd, acc[2] * dd, acc[3] * dd);
    float4 o1 = make_float4(acc[4] * dd, acc[5] * dd, acc[6] * dd, acc[7] * dd);
    *(float4*)&out[(size_t)node * D + j0]     = o0;
    *(float4*)&out[(size_t)node * D + j0 + 4] = o1;
}

template<int D>
__global__ void gn_finalize_kernel(const float* __restrict__ part, float* __restrict__ ac,
                                   const float* __restrict__ gw, const float* __restrict__ gb,
                                   const float* __restrict__ gm, float inv_n)
{
    int j = threadIdx.x;
    if (j >= D) return;
    float s1 = 0.f, s2 = 0.f;
    for (int t = 0; t < NSLOT; ++t) {
        s1 += part[(size_t)t * 256 + j];
        s2 += part[(size_t)t * 256 + D + j];
    }
    float mean = s1 * inv_n;
    float ex2  = s2 * inv_n;
    float m    = gm[j];
    float var  = ex2 - (2.f * m - m * m) * mean * mean;
    float a    = gw[j] * rsqrtf(var + 1e-5f);
    float c    = gb[j] - a * m * mean;
    ac[j]     = a;
    ac[D + j] = c;
}

// ---------------- fused decoder tail ----------------
__global__ __launch_bounds__(256) void dec_tail_kernel(
    const float* __restrict__ in, const float* __restrict__ W1, const float* __restrict__ b1,
    const float* __restrict__ W2, const float* __restrict__ b2,
    const float* __restrict__ W3, const float* __restrict__ b3,
    float* __restrict__ out, int n)
{
    int t = blockIdx.x * THREADS + threadIdx.x;
    if (t >= n) return;

    float x[64];
#pragma unroll
    for (int q = 0; q < 16; ++q)
        *(float4*)&x[q * 4] = *(const float4*)&in[(size_t)t * 64 + q * 4];

    float h1[32];
#pragma unroll
    for (int j = 0; j < 32; ++j) h1[j] = b1[j];
#pragma unroll 8
    for (int k = 0; k < 64; ++k) {
        const float xk = x[k];
#pragma unroll
        for (int j = 0; j < 32; ++j) h1[j] = fmaf(xk, W1[k * 32 + j], h1[j]);
    }
#pragma unroll
    for (int j = 0; j < 32; ++j) h1[j] = fmaxf(h1[j], 0.f);

    float h2[16];
#pragma unroll
    for (int j = 0; j < 16; ++j) h2[j] = b2[j];
#pragma unroll 8
    for (int k = 0; k < 32; ++k) {
        const float hk = h1[k];
#pragma unroll
        for (int j = 0; j < 16; ++j) h2[j] = fmaf(hk, W2[k * 16 + j], h2[j]);
    }

    float acc = b3[0];
#pragma unroll
    for (int k = 0; k < 16; ++k) acc = fmaf(fmaxf(h2[k], 0.f), W3[k], acc);
    out[t] = 1.0f / (1.0f + expf(-acc));
}

// ---------------- launch ----------------

extern "C" void kernel_launch(void* const* d_in, const int* in_sizes, int n_in,
                              void* d_out, int out_size, void* d_ws, size_t ws_size,
                              hipStream_t stream)
{
    const float* local_x    = (const float*)d_in[0];
    const int*   local_type = (const int*)d_in[1];
    const float* voxel_x    = (const float*)d_in[2];
    const int*   voxel_type = (const int*)d_in[3];
    const int*   edge_index = (const int*)d_in[4];
    const float* label      = (const float*)d_in[5];
    const float* We1 = (const float*)d_in[6],  *be1 = (const float*)d_in[7];
    const float* We2 = (const float*)d_in[8],  *be2 = (const float*)d_in[9];
    const float *Wc[4], *bc[4], *gw[4], *gb[4], *gm[4];
    for (int i = 0; i < 4; ++i) {
        Wc[i] = (const float*)d_in[10 + i * 5];
        bc[i] = (const float*)d_in[11 + i * 5];
        gw[i] = (const float*)d_in[12 + i * 5];
        gb[i] = (const float*)d_in[13 + i * 5];
        gm[i] = (const float*)d_in[14 + i * 5];
    }
    const float* Wd0 = (const float*)d_in[30], *bd0 = (const float*)d_in[31];
    const float* Wd1 = (const float*)d_in[32], *bd1 = (const float*)d_in[33];
    const float* Wd2 = (const float*)d_in[34], *bd2 = (const float*)d_in[35];
    const float* Wd3 = (const float*)d_in[36], *bd3 = (const float*)d_in[37];

    const int n  = in_sizes[2] / 6;    // 200000
    const int E  = in_sizes[4] / 2;    // 1200000
    const int nl = in_sizes[0] / 19;   // 400
    const int* src = edge_index;
    const int* dst = edge_index + E;

    auto align256 = [](size_t x) { return (x + 255) & ~(size_t)255; };
    char* w = (char*)d_ws;
    float* ac_all = (float*)w;
    float* means  = (float*)(w + 4096);
    int* blocksums = (int*)(w + 8192);
    float* stats_part = (float*)(w + 8192 + 1024);
    size_t off = 8192 + 1024 + 4 * NSLOT * 256 * sizeof(float);
    ushort_t* wt0 = (ushort_t*)(w + off); off += align256(16384 * 2);
    ushort_t* wt1 = (ushort_t*)(w + off); off += align256(8192 * 2);
    ushort_t* wt2 = (ushort_t*)(w + off); off += align256(8192 * 2);
    ushort_t* wt3 = (ushort_t*)(w + off); off += align256(8192 * 2);
    int*   rowptr = (int*)(w + off);   off += align256((size_t)(n + 1) * 4);
    float* dinv   = (float*)(w + off); off += align256((size_t)n * 4);
    int*   esrc   = (int*)(w + off);   off += align256((size_t)E * 4);
    int*   qpos   = (int*)(w + off);   off += align256((size_t)E * 4);
    float* A    = (float*)(w + off);
    float* B    = A + (size_t)n * 128;
    float* A_lo = A;
    float* A_hi = A + (size_t)n * 64;
    float* B_lo = B;
    float* B_hi = B + (size_t)n * 64;
    int*   degi = (int*)A;

    const float inv_n = 1.0f / (float)n;
    auto cdiv = [](long long a, long long b) { return (int)((a + b - 1) / b); };
    const int nb = cdiv(n, 1024);

    float* part0 = stats_part + 0 * NSLOT * 256;
    float* part1 = stats_part + 1 * NSLOT * 256;
    float* part2 = stats_part + 2 * NSLOT * 256;
    float* part3 = stats_part + 3 * NSLOT * 256;
    float* ac0 = ac_all + 0, *ac1 = ac_all + 256, *ac2 = ac_all + 512, *ac3 = ac_all + 768;

    hipMemsetAsync(stats_part, 0, 4 * NSLOT * 256 * sizeof(float), stream);
    hipMemsetAsync(degi, 0, (size_t)n * sizeof(int), stream);

    wtrans_kernel<<<cdiv(128 * 128, 256), 256, 0, stream>>>(We2,   wt0, 128, 128);
    wtrans_kernel<<<cdiv(128 * 64, 256), 256, 0, stream>>>(Wc[0], wt1, 128, 64);
    wtrans_kernel<<<cdiv(64 * 128, 256), 256, 0, stream>>>(Wc[3], wt2, 64, 128);
    wtrans_kernel<<<cdiv(128 * 64, 256), 256, 0, stream>>>(Wd0,   wt3, 128, 64);

    local_means_kernel<<<1, 256, 0, stream>>>(local_x, local_type, means, nl);
    hist_kernel<<<cdiv(E, 256), 256, 0, stream>>>(dst, degi, qpos, E);
    scan_part1_kernel<<<nb, 256, 0, stream>>>(degi, blocksums, n);
    scan_part2_kernel<<<1, 256, 0, stream>>>(blocksums, nb);
    scan_part3_kernel<<<nb, 256, 0, stream>>>(degi, blocksums, rowptr, dinv, n, E);
    fill_kernel<<<cdiv(E, 256), 256, 0, stream>>>(src, dst, qpos, rowptr, esrc, E);
    build_x0_kernel<<<cdiv((long long)n * 32, 256), 256, 0, stream>>>(means, voxel_type, voxel_x, label, B_lo, n);

    const int g64 = cdiv(n, 32);   // one 32-node tile per block (D=64)
    const int g32 = cdiv(n, 64);   // one 64-node tile per block (D=32)
    const int gmfma = cdiv(n, 128);

    // enc1 (f32): X0=B_lo(32w) -> A(128)
    mlp_kernel<32, 128, 128, 8, true, true, false, false, false><<<cdiv(n, 128), 256, 0, stream>>>(B_lo, A, We1, be1, nullptr, nullptr, nullptr, n);
    // enc2 (MFMA): A -> B
    mfma_mlp_kernel<128, 128, true, true, false, false, false><<<gmfma, 256, 0, stream>>>(A, B, wt0, be2, nullptr, nullptr, nullptr, n);

    // conv0 (MFMA): B -> T0=A_lo(64w, dinv-scaled); gather -> A_hi [+stats0]
    mfma_mlp_kernel<128, 64, false, false, false, true, false><<<gmfma, 256, 0, stream>>>(B, A_lo, wt1, nullptr, nullptr, dinv, nullptr, n);
    gather_agg_kernel<64><<<g64, 256, 0, stream>>>(A_lo, A_hi, rowptr, esrc, dinv, bc[0], part0, n);
    gn_finalize_kernel<64><<<1, 64, 0, stream>>>(part0, ac0, gw[0], gb[0], gm[0], inv_n);

    // conv1 (f32): A_hi(+GN ac0) -> T1=B_lo(32w, dinv-scaled); gather -> B_hi(32w) [+stats1]
    mlp_kernel<64, 32, 256, 4, false, false, true, true, false><<<cdiv(n, 256), 256, 0, stream>>>(A_hi, B_lo, Wc[1], nullptr, ac0, dinv, nullptr, n);
    gather_agg_kernel<32><<<g32, 256, 0, stream>>>(B_lo, B_hi, rowptr, esrc, dinv, bc[1], part1, n);
    gn_finalize_kernel<32><<<1, 32, 0, stream>>>(part1, ac1, gw[1], gb[1], gm[1], inv_n);

    // conv2: gather_pre<32>(B_hi,+GN ac1) -> G2=A_lo(32w); f32 GEMM -> B_hi(64w) [+stats2 fused]
    gather_pre_kernel<32><<<g32, 256, 0, stream>>>(B_hi, A_lo, rowptr, esrc, dinv, ac1, n);
    mlp_kernel<32, 64, 256, 8, false, true, false, false, true><<<cdiv(n, 256), 256, 0, stream>>>(A_lo, B_hi, Wc[2], bc[2], nullptr, nullptr, part2, n);
    gn_finalize_kernel<64><<<1, 64, 0, stream>>>(part2, ac2, gw[2], gb[2], gm[2], inv_n);

    // conv3: gather_pre<64>(B_hi,+GN ac2) -> G3=B_lo(64w); MFMA -> A(128) [+stats3 fused]
    gather_pre_kernel<64><<<g64, 256, 0, stream>>>(B_hi, B_lo, rowptr, esrc, dinv, ac2, n);
    mfma_mlp_kernel<64, 128, false, true, false, false, true><<<gmfma, 256, 0, stream>>>(B_lo, A, wt2, bc[3], nullptr, nullptr, part3, n);
    gn_finalize_kernel<128><<<1, 128, 0, stream>>>(part3, ac3, gw[3], gb[3], gm[3], inv_n);

    // dec0 (MFMA): A(+GN ac3) -> D0=B_lo(64w); fused tail -> out
    mfma_mlp_kernel<128, 64, true, true, true, false, false><<<gmfma, 256, 0, stream>>>(A, B_lo, wt3, bd0, ac3, nullptr, nullptr, n);
    dec_tail_kernel<<<cdiv(n, 256), 256, 0, stream>>>(B_lo, Wd1, bd1, Wd2, bd2, Wd3, bd3, (float*)d_out, n);
}

// Round 16
// 654.191 us; speedup vs baseline: 1.3454x; 1.0000x over previous
//
#include <hip/hip_runtime.h>
#include <hip/hip_bf16.h>
#include <cstddef>

#define THREADS 256
#define NSLOT 64

typedef unsigned short ushort_t;
typedef unsigned int uint_t;
typedef __attribute__((ext_vector_type(8))) short bf16x8;
typedef __attribute__((ext_vector_type(4))) float f32x4;

__device__ __forceinline__ ushort_t f2b(float f) {
    uint_t i = __float_as_uint(f);
    uint_t r = i + 0x7fffu + ((i >> 16) & 1u);
    return (ushort_t)(r >> 16);
}

// ---------------- small kernels ----------------

__global__ __launch_bounds__(256) void local_means_kernel(const float* __restrict__ lx,
                                                          const int* __restrict__ lt,
                                                          float* __restrict__ means, int nl)
{
    __shared__ float slx[512 * 19];
    __shared__ int   slt[512];
    const int tid = threadIdx.x;
    for (int i = tid; i < nl * 19; i += 256) slx[i] = lx[i];
    for (int i = tid; i < nl; i += 256) slt[i] = lt[i];
    __syncthreads();
    if (tid >= 7 * 19) return;
    int c = tid / 19, dd = tid % 19;
    float s = 0.f; int cnt = 0;
    for (int i = 0; i < nl; ++i) {
        if (slt[i] == c) { s += slx[i * 19 + dd]; cnt++; }
    }
    means[tid] = cnt > 0 ? s / (float)cnt : 0.f;
}

// hist + per-edge slot index (q-trick)
__global__ void hist_kernel(const int* __restrict__ dst, int* __restrict__ degi,
                            int* __restrict__ qpos, int E)
{
    int t = blockIdx.x * THREADS + threadIdx.x;
    if (t < E) qpos[t] = atomicAdd(&degi[dst[t]], 1);
}

__global__ __launch_bounds__(256) void scan_part1_kernel(const int* __restrict__ degi,
                                                         int* __restrict__ blocksums, int n)
{
    const int tid = threadIdx.x;
    const int idx = blockIdx.x * 1024 + tid * 4;
    int v = 0;
    if (idx + 3 < n) {
        int4 d = *(const int4*)&degi[idx];
        v = d.x + d.y + d.z + d.w;
    } else {
        for (int i = 0; i < 4; ++i) if (idx + i < n) v += degi[idx + i];
    }
    __shared__ int s[256];
    s[tid] = v;
    __syncthreads();
    for (int off = 128; off >= 1; off >>= 1) {
        if (tid < off) s[tid] += s[tid + off];
        __syncthreads();
    }
    if (tid == 0) blocksums[blockIdx.x] = s[0];
}

__global__ __launch_bounds__(256) void scan_part2_kernel(int* __restrict__ blocksums, int nb)
{
    __shared__ int s[256];
    const int tid = threadIdx.x;
    int v = (tid < nb) ? blocksums[tid] : 0;
    s[tid] = v;
    __syncthreads();
    for (int off = 1; off < 256; off <<= 1) {
        int t = (tid >= off) ? s[tid - off] : 0;
        __syncthreads();
        s[tid] += t;
        __syncthreads();
    }
    if (tid < nb) blocksums[tid] = s[tid] - v;
}

__global__ __launch_bounds__(256) void scan_part3_kernel(const int* __restrict__ degi,
                                                         const int* __restrict__ blocksums,
                                                         int* __restrict__ rowptr,
                                                         float* __restrict__ dinv, int n, int E)
{
    const int tid = threadIdx.x;
    const int idx = blockIdx.x * 1024 + tid * 4;
    int d0 = 0, d1 = 0, d2 = 0, d3 = 0;
    if (idx + 3 < n) {
        int4 d = *(const int4*)&degi[idx];
        d0 = d.x; d1 = d.y; d2 = d.z; d3 = d.w;
    } else {
        if (idx     < n) d0 = degi[idx];
        if (idx + 1 < n) d1 = degi[idx + 1];
        if (idx + 2 < n) d2 = degi[idx + 2];
        if (idx + 3 < n) d3 = degi[idx + 3];
    }
    const int v = d0 + d1 + d2 + d3;
    __shared__ int s[256];
    s[tid] = v;
    __syncthreads();
    for (int off = 1; off < 256; off <<= 1) {
        int t = (tid >= off) ? s[tid - off] : 0;
        __syncthreads();
        s[tid] += t;
        __syncthreads();
    }
    int run = blocksums[blockIdx.x] + s[tid] - v;
    if (idx + 3 < n) {
        int4 o;
        o.x = run; run += d0;
        o.y = run; run += d1;
        o.z = run; run += d2;
        o.w = run;
        *(int4*)&rowptr[idx] = o;
        float4 dv;
        dv.x = rsqrtf((float)d0 + 1.0f);
        dv.y = rsqrtf((float)d1 + 1.0f);
        dv.z = rsqrtf((float)d2 + 1.0f);
        dv.w = rsqrtf((float)d3 + 1.0f);
        *(float4*)&dinv[idx] = dv;
    } else {
        if (idx     < n) { rowptr[idx]     = run; dinv[idx]     = rsqrtf((float)d0 + 1.0f); run += d0; }
        if (idx + 1 < n) { rowptr[idx + 1] = run; dinv[idx + 1] = rsqrtf((float)d1 + 1.0f); run += d1; }
        if (idx + 2 < n) { rowptr[idx + 2] = run; dinv[idx + 2] = rsqrtf((float)d2 + 1.0f); run += d2; }
        if (idx + 3 < n) { rowptr[idx + 3] = run; dinv[idx + 3] = rsqrtf((float)d3 + 1.0f); }
    }
    if (blockIdx.x == 0 && tid == 0) rowptr[n] = E;
}

__global__ void fill_kernel(const int* __restrict__ src, const int* __restrict__ dst,
                            const int* __restrict__ qpos, const int* __restrict__ rowptr,
                            int* __restrict__ esrc, int E)
{
    int t = blockIdx.x * THREADS + threadIdx.x;
    if (t >= E) return;
    esrc[rowptr[dst[t]] + qpos[t]] = src[t];
}

__global__ void build_x0_kernel(const float* __restrict__ means,
                                const int* __restrict__ vt,
                                const float* __restrict__ vx,
                                const float* __restrict__ label,
                                float* __restrict__ out, int n)
{
    int tid = blockIdx.x * THREADS + threadIdx.x;
    int node = tid >> 5, c = tid & 31;
    if (node >= n) return;
    float v;
    if (c < 19)      v = means[vt[node] * 19 + c];
    else if (c < 25) v = vx[node * 6 + (c - 19)];
    else             v = label[node * 7 + (c - 25)];
    out[(size_t)node * 32 + c] = v;
}

__global__ void wtrans_kernel(const float* __restrict__ W, ushort_t* __restrict__ WT,
                              int din, int dout)
{
    int t = blockIdx.x * THREADS + threadIdx.x;
    if (t >= din * dout) return;
    int k = t / dout, c = t % dout;
    WT[(size_t)c * din + k] = f2b(W[t]);
}

// ---------------- f32 dense layer (split-J), optional fused slot-replicated stats ----
template<int DIN, int DOUT, int BN, int JPER, bool RELU, bool BIAS, bool TRANSFORM, bool SCALE, bool STATS>
__global__ __launch_bounds__(256) void mlp_kernel(
    const float* __restrict__ in, float* __restrict__ out,
    const float* __restrict__ W, const float* __restrict__ bias,
    const float* __restrict__ tr, const float* __restrict__ rowscale,
    float* __restrict__ statsP, int n)
{
    constexpr int KT  = 32;
    constexpr int TJ  = DOUT / JPER;
    constexpr int TN  = 256 / TJ;
    constexpr int NPT = BN / TN;
    constexpr int JQ  = JPER / 4;
    constexpr int CS  = 4 * TJ;
    constexpr int BNP = BN + 4;

    __shared__ float Wt[KT * DOUT];
    __shared__ float xT[KT][BNP];

    const int tid   = threadIdx.x;
    const int nbase = blockIdx.x * BN;
    const int tj = tid % TJ, tn = tid / TJ;
    const int j0 = tj * 4, n0 = tn * NPT;

    float acc[NPT][JPER];
#pragma unroll
    for (int p = 0; p < NPT; ++p)
#pragma unroll
        for (int j = 0; j < JPER; ++j) acc[p][j] = 0.f;

    for (int kt = 0; kt < DIN; kt += KT) {
        __syncthreads();
        for (int i = tid * 4; i < KT * DOUT; i += THREADS * 4) {
            *(float4*)&Wt[i] = *(const float4*)&W[(size_t)kt * DOUT + i];
        }
        for (int i = tid; i < BN * (KT / 4); i += THREADS) {
            int node = i / (KT / 4);
            int kq   = i % (KT / 4);
            int g    = nbase + node;
            float4 v = make_float4(0.f, 0.f, 0.f, 0.f);
            if (g < n) {
                v = *(const float4*)&in[(size_t)g * DIN + kt + kq * 4];
                if (TRANSFORM) {
                    const float4 a = *(const float4*)&tr[kt + kq * 4];
                    const float4 c = *(const float4*)&tr[DIN + kt + kq * 4];
                    v.x = fmaxf(fmaf(v.x, a.x, c.x), 0.f);
                    v.y = fmaxf(fmaf(v.y, a.y, c.y), 0.f);
                    v.z = fmaxf(fmaf(v.z, a.z, c.z), 0.f);
                    v.w = fmaxf(fmaf(v.w, a.w, c.w), 0.f);
                }
            }
            xT[kq * 4 + 0][node] = v.x;
            xT[kq * 4 + 1][node] = v.y;
            xT[kq * 4 + 2][node] = v.z;
            xT[kq * 4 + 3][node] = v.w;
        }
        __syncthreads();
#pragma unroll 4
        for (int kk = 0; kk < KT; ++kk) {
            float wv[JPER];
#pragma unroll
            for (int q = 0; q < JQ; ++q)
                *(float4*)&wv[q * 4] = *(const float4*)&Wt[kk * DOUT + q * CS + j0];
            float xv[NPT];
#pragma unroll
            for (int q = 0; q < NPT / 4; ++q)
                *(float4*)&xv[q * 4] = *(const float4*)&xT[kk][n0 + q * 4];
#pragma unroll
            for (int p = 0; p < NPT; ++p)
#pragma unroll
                for (int j = 0; j < JPER; ++j)
                    acc[p][j] = fmaf(xv[p], wv[j], acc[p][j]);
        }
    }

    float bv[JPER];
#pragma unroll
    for (int j = 0; j < JPER; ++j) bv[j] = 0.f;
    if (BIAS) {
#pragma unroll
        for (int q = 0; q < JQ; ++q)
            *(float4*)&bv[q * 4] = *(const float4*)&bias[q * CS + j0];
    }

    float s1[JPER], s2[JPER];
#pragma unroll
    for (int j = 0; j < JPER; ++j) { s1[j] = 0.f; s2[j] = 0.f; }

#pragma unroll
    for (int p = 0; p < NPT; ++p) {
        const int g = nbase + n0 + p;
        if (g >= n) continue;
        float rs = 1.f;
        if (SCALE) rs = rowscale[g];
#pragma unroll
        for (int q = 0; q < JQ; ++q) {
            float4 o;
            o.x = acc[p][q * 4 + 0] + bv[q * 4 + 0];
            o.y = acc[p][q * 4 + 1] + bv[q * 4 + 1];
            o.z = acc[p][q * 4 + 2] + bv[q * 4 + 2];
            o.w = acc[p][q * 4 + 3] + bv[q * 4 + 3];
            if (RELU) {
                o.x = fmaxf(o.x, 0.f); o.y = fmaxf(o.y, 0.f);
                o.z = fmaxf(o.z, 0.f); o.w = fmaxf(o.w, 0.f);
            }
            if (SCALE) { o.x *= rs; o.y *= rs; o.z *= rs; o.w *= rs; }
            if (STATS) {
                s1[q * 4 + 0] += o.x; s2[q * 4 + 0] = fmaf(o.x, o.x, s2[q * 4 + 0]);
                s1[q * 4 + 1] += o.y; s2[q * 4 + 1] = fmaf(o.y, o.y, s2[q * 4 + 1]);
                s1[q * 4 + 2] += o.z; s2[q * 4 + 2] = fmaf(o.z, o.z, s2[q * 4 + 2]);
                s1[q * 4 + 3] += o.w; s2[q * 4 + 3] = fmaf(o.w, o.w, s2[q * 4 + 3]);
            }
            *(float4*)&out[(size_t)g * DOUT + q * CS + j0] = o;
        }
    }

    if constexpr (STATS) {
        __shared__ float red[256][2 * JPER + 1];
#pragma unroll
        for (int j = 0; j < JPER; ++j) { red[tid][j] = s1[j]; red[tid][JPER + j] = s2[j]; }
        __syncthreads();
#pragma unroll
        for (int off = TN / 2; off >= 1; off >>= 1) {
            if (tn < off) {
#pragma unroll
                for (int j = 0; j < 2 * JPER; ++j) red[tid][j] += red[tid + off * TJ][j];
            }
            __syncthreads();
        }
        if (tn == 0) {
            float* slot = statsP + (size_t)(blockIdx.x & (NSLOT - 1)) * 256;
#pragma unroll
            for (int q = 0; q < JQ; ++q)
#pragma unroll
                for (int e = 0; e < 4; ++e) {
                    atomicAdd(&slot[q * CS + j0 + e],        red[tid][q * 4 + e]);
                    atomicAdd(&slot[DOUT + q * CS + j0 + e], red[tid][JPER + q * 4 + e]);
                }
        }
    }
}

// ---------------- bf16-MFMA dense layer; WT pre-converted bf16 [DOUT][DIN];
// optional fused slot-replicated stats on written output ----------
template<int DIN, int DOUT, bool RELU, bool BIAS, bool TRANSFORM, bool SCALE, bool STATS>
__global__ __launch_bounds__(256) void mfma_mlp_kernel(
    const float* __restrict__ in, float* __restrict__ out,
    const ushort_t* __restrict__ WT, const float* __restrict__ bias,
    const float* __restrict__ tr, const float* __restrict__ rowscale,
    float* __restrict__ statsP, int n)
{
    constexpr int BN  = 128;
    constexpr int KT  = 32;
    constexpr int NT  = DIN / KT;
    constexpr int LDK = 40;
    constexpr int WM  = 2, WN = 2;
    constexpr int MW  = BN / WM;
    constexpr int NW  = DOUT / WN;
    constexpr int MR  = MW / 16;
    constexpr int NR  = NW / 16;

    __shared__ ushort_t xA[BN * LDK];

    const int tid   = threadIdx.x;
    const int wid   = tid >> 6;
    const int lane  = tid & 63;
    const int wm    = wid >> 1, wn = wid & 1;
    const int nbase = blockIdx.x * BN;
    const int l16   = lane & 15;
    const int lk8   = (lane >> 4) * 8;

    f32x4 acc[MR][NR];
#pragma unroll
    for (int mi = 0; mi < MR; ++mi)
#pragma unroll
        for (int ni = 0; ni < NR; ++ni)
#pragma unroll
            for (int j = 0; j < 4; ++j) acc[mi][ni][j] = 0.f;

    for (int t = 0; t < NT; ++t) {
        const int kt = t * KT;
        __syncthreads();
        for (int i = tid; i < BN * (KT / 4); i += 256) {
            const int row = i / (KT / 4);
            const int kq  = (i % (KT / 4)) * 4;
            const int g   = nbase + row;
            float4 v = make_float4(0.f, 0.f, 0.f, 0.f);
            if (g < n) {
                v = *(const float4*)&in[(size_t)g * DIN + kt + kq];
                if (TRANSFORM) {
                    const float4 a = *(const float4*)&tr[kt + kq];
                    const float4 c = *(const float4*)&tr[DIN + kt + kq];
                    v.x = fmaxf(fmaf(v.x, a.x, c.x), 0.f);
                    v.y = fmaxf(fmaf(v.y, a.y, c.y), 0.f);
                    v.z = fmaxf(fmaf(v.z, a.z, c.z), 0.f);
                    v.w = fmaxf(fmaf(v.w, a.w, c.w), 0.f);
                }
            }
            ushort4 b;
            b.x = f2b(v.x); b.y = f2b(v.y); b.z = f2b(v.z); b.w = f2b(v.w);
            *(ushort4*)&xA[row * LDK + kq] = b;
        }
        __syncthreads();

        bf16x8 af[MR], bf[NR];
#pragma unroll
        for (int mi = 0; mi < MR; ++mi)
            af[mi] = *(const bf16x8*)&xA[(wm * MW + mi * 16 + l16) * LDK + lk8];
#pragma unroll
        for (int ni = 0; ni < NR; ++ni)
            bf[ni] = *(const bf16x8*)&WT[(size_t)(wn * NW + ni * 16 + l16) * DIN + kt + lk8];
#pragma unroll
        for (int mi = 0; mi < MR; ++mi)
#pragma unroll
            for (int ni = 0; ni < NR; ++ni)
                acc[mi][ni] = __builtin_amdgcn_mfma_f32_16x16x32_bf16(
                    af[mi], bf[ni], acc[mi][ni], 0, 0, 0);
    }

    float bv[NR];
#pragma unroll
    for (int ni = 0; ni < NR; ++ni)
        bv[ni] = BIAS ? bias[wn * NW + ni * 16 + l16] : 0.f;

    float s1[NR], s2[NR];
#pragma unroll
    for (int ni = 0; ni < NR; ++ni) { s1[ni] = 0.f; s2[ni] = 0.f; }

#pragma unroll
    for (int mi = 0; mi < MR; ++mi) {
#pragma unroll
        for (int j = 0; j < 4; ++j) {
            const int r = wm * MW + mi * 16 + (lane >> 4) * 4 + j;
            const int g = nbase + r;
            if (g >= n) continue;
            float rs = 1.f;
            if (SCALE) rs = rowscale[g];
#pragma unroll
            for (int ni = 0; ni < NR; ++ni) {
                const int col = wn * NW + ni * 16 + l16;
                float v = acc[mi][ni][j] + bv[ni];
                if (RELU) v = fmaxf(v, 0.f);
                if (SCALE) v *= rs;
                if (STATS) { s1[ni] += v; s2[ni] = fmaf(v, v, s2[ni]); }
                out[(size_t)g * DOUT + col] = v;
            }
        }
    }

    if constexpr (STATS) {
        __shared__ float sred[2][DOUT];
        for (int i = tid; i < 2 * DOUT; i += 256) ((float*)sred)[i] = 0.f;
        __syncthreads();
#pragma unroll
        for (int ni = 0; ni < NR; ++ni) {
            const int col = wn * NW + ni * 16 + l16;
            atomicAdd(&sred[0][col], s1[ni]);
            atomicAdd(&sred[1][col], s2[ni]);
        }
        __syncthreads();
        if (tid < DOUT) {
            float* slot = statsP + (size_t)(blockIdx.x & (NSLOT - 1)) * 256;
            atomicAdd(&slot[tid],        sred[0][tid]);
            atomicAdd(&slot[DOUT + tid], sred[1][tid]);
        }
    }
}

// ---------------- CSR gather aggregation (post-GEMM), persistent grid-stride ----
template<int D>
__global__ __launch_bounds__(256) void gather_agg_kernel(
    const float* __restrict__ y, float* __restrict__ out,
    const int* __restrict__ rowptr, const int* __restrict__ esrc,
    const float* __restrict__ dinv,
    const float* __restrict__ bias, float* __restrict__ statsP, int n)
{
    constexpr int JT  = D / 8;
    constexpr int NPB = 256 / JT;
    const int tid  = threadIdx.x;
    const int jq   = tid % JT;
    const int nsub = tid / JT;
    const int j0   = jq * 8;

    float bv[8];
#pragma unroll
    for (int e = 0; e < 8; ++e) bv[e] = bias[j0 + e];

    float s1[8], s2[8];
#pragma unroll
    for (int e = 0; e < 8; ++e) { s1[e] = 0.f; s2[e] = 0.f; }

    const int ntiles = (n + NPB - 1) / NPB;
    for (int tile = blockIdx.x; tile < ntiles; tile += gridDim.x) {
        const int node = tile * NPB + nsub;
        if (node < n) {
            const int rb = rowptr[node], re = rowptr[node + 1];
            const float dd = dinv[node];
            float acc[8];
            *(float4*)&acc[0] = *(const float4*)&y[(size_t)node * D + j0];
            *(float4*)&acc[4] = *(const float4*)&y[(size_t)node * D + j0 + 4];
            int k = rb;
            for (; k + 3 < re; k += 4) {
                const int sa = esrc[k], sb = esrc[k + 1];
                const int sc = esrc[k + 2], sd = esrc[k + 3];
                float4 a0 = *(const float4*)&y[(size_t)sa * D + j0];
                float4 a1 = *(const float4*)&y[(size_t)sa * D + j0 + 4];
                float4 b0 = *(const float4*)&y[(size_t)sb * D + j0];
                float4 b1 = *(const float4*)&y[(size_t)sb * D + j0 + 4];
                float4 c0 = *(const float4*)&y[(size_t)sc * D + j0];
                float4 c1 = *(const float4*)&y[(size_t)sc * D + j0 + 4];
                float4 e0 = *(const float4*)&y[(size_t)sd * D + j0];
                float4 e1 = *(const float4*)&y[(size_t)sd * D + j0 + 4];
                acc[0] += (a0.x + b0.x) + (c0.x + e0.x);
                acc[1] += (a0.y + b0.y) + (c0.y + e0.y);
                acc[2] += (a0.z + b0.z) + (c0.z + e0.z);
                acc[3] += (a0.w + b0.w) + (c0.w + e0.w);
                acc[4] += (a1.x + b1.x) + (c1.x + e1.x);
                acc[5] += (a1.y + b1.y) + (c1.y + e1.y);
                acc[6] += (a1.z + b1.z) + (c1.z + e1.z);
                acc[7] += (a1.w + b1.w) + (c1.w + e1.w);
            }
            for (; k < re; ++k) {
                const int sa = esrc[k];
                float4 a0 = *(const float4*)&y[(size_t)sa * D + j0];
                float4 a1 = *(const float4*)&y[(size_t)sa * D + j0 + 4];
                acc[0] += a0.x; acc[1] += a0.y; acc[2] += a0.z; acc[3] += a0.w;
                acc[4] += a1.x; acc[5] += a1.y; acc[6] += a1.z; acc[7] += a1.w;
            }
            float o[8];
#pragma unroll
            for (int e = 0; e < 8; ++e) {
                o[e] = fmaf(acc[e], dd, bv[e]);
                s1[e] += o[e];
                s2[e] = fmaf(o[e], o[e], s2[e]);
            }
            *(float4*)&out[(size_t)node * D + j0]     = make_float4(o[0], o[1], o[2], o[3]);
            *(float4*)&out[(size_t)node * D + j0 + 4] = make_float4(o[4], o[5], o[6], o[7]);
        }
    }

    __shared__ float red[256][17];
#pragma unroll
    for (int e = 0; e < 8; ++e) { red[tid][e] = s1[e]; red[tid][8 + e] = s2[e]; }
    __syncthreads();
#pragma unroll
    for (int off = NPB / 2; off >= 1; off >>= 1) {
        if (nsub < off) {
#pragma unroll
            for (int e = 0; e < 16; ++e) red[tid][e] += red[tid + off * JT][e];
        }
        __syncthreads();
    }
    if (nsub == 0) {
        float* slot = statsP + (size_t)(blockIdx.x & (NSLOT - 1)) * 256;
#pragma unroll
        for (int e = 0; e < 8; ++e) {
            atomicAdd(&slot[j0 + e],     red[tid][e]);
            atomicAdd(&slot[D + j0 + e], red[tid][8 + e]);
        }
    }
}

// ---------------- CSR gather aggregation (pre-GEMM), fused GN+ReLU+dinv,
// persistent grid-stride ----
template<int D>
__global__ __launch_bounds__(256) void gather_pre_kernel(
    const float* __restrict__ x, float* __restrict__ out,
    const int* __restrict__ rowptr, const int* __restrict__ esrc,
    const float* __restrict__ dinv, const float* __restrict__ tr, int n)
{
    constexpr int JT  = D / 8;
    constexpr int NPB = 256 / JT;
    const int tid  = threadIdx.x;
    const int jq   = tid % JT;
    const int nsub = tid / JT;
    const int j0   = jq * 8;

    float av[8], cv[8];
#pragma unroll
    for (int e = 0; e < 8; ++e) { av[e] = tr[j0 + e]; cv[e] = tr[D + j0 + e]; }

    const int ntiles = (n + NPB - 1) / NPB;
    for (int tile = blockIdx.x; tile < ntiles; tile += gridDim.x) {
        const int node = tile * NPB + nsub;
        if (node < n) {
            const int rb = rowptr[node], re = rowptr[node + 1];
            const float dd = dinv[node];
            float acc[8], v[8];
            *(float4*)&v[0] = *(const float4*)&x[(size_t)node * D + j0];
            *(float4*)&v[4] = *(const float4*)&x[(size_t)node * D + j0 + 4];
#pragma unroll
            for (int e = 0; e < 8; ++e)
                acc[e] = fmaxf(fmaf(v[e], av[e], cv[e]), 0.f) * dd;
            int k = rb;
            for (; k + 3 < re; k += 4) {
                const int sa = esrc[k], sb = esrc[k + 1];
                const int sc = esrc[k + 2], sd = esrc[k + 3];
                const float da = dinv[sa], db = dinv[sb];
                const float dc = dinv[sc], de = dinv[sd];
                float va[8], vb[8], vc[8], ve[8];
                *(float4*)&va[0] = *(const float4*)&x[(size_t)sa * D + j0];
                *(float4*)&va[4] = *(const float4*)&x[(size_t)sa * D + j0 + 4];
                *(float4*)&vb[0] = *(const float4*)&x[(size_t)sb * D + j0];
                *(float4*)&vb[4] = *(const float4*)&x[(size_t)sb * D + j0 + 4];
                *(float4*)&vc[0] = *(const float4*)&x[(size_t)sc * D + j0];
                *(float4*)&vc[4] = *(const float4*)&x[(size_t)sc * D + j0 + 4];
                *(float4*)&ve[0] = *(const float4*)&x[(size_t)sd * D + j0];
                *(float4*)&ve[4] = *(const float4*)&x[(size_t)sd * D + j0 + 4];
#pragma unroll
                for (int e = 0; e < 8; ++e) {
                    float fa = fmaxf(fmaf(va[e], av[e], cv[e]), 0.f) * da;
                    float fb = fmaxf(fmaf(vb[e], av[e], cv[e]), 0.f) * db;
                    float fc = fmaxf(fmaf(vc[e], av[e], cv[e]), 0.f) * dc;
                    float fe = fmaxf(fmaf(ve[e], av[e], cv[e]), 0.f) * de;
                    acc[e] += (fa + fb) + (fc + fe);
                }
            }
            for (; k < re; ++k) {
                const int sa = esrc[k];
                const float da = dinv[sa];
                float va[8];
                *(float4*)&va[0] = *(const float4*)&x[(size_t)sa * D + j0];
                *(float4*)&va[4] = *(const float4*)&x[(size_t)sa * D + j0 + 4];
#pragma unroll
                for (int e = 0; e < 8; ++e)
                    acc[e] += fmaxf(fmaf(va[e], av[e], cv[e]), 0.f) * da;
            }
            float4 o0 = make_float4(acc[0] * dd, acc[1] * dd, acc[2] * dd, acc[3] * dd);
            float4 o1 = make_float4(acc[4] * dd, acc[5] * dd, acc[6] * dd, acc[7] * dd);
            *(float4*)&out[(size_t)node * D + j0]     = o0;
            *(float4*)&out[(size_t)node * D + j0 + 4] = o1;
        }
    }
}

template<int D>
__global__ void gn_finalize_kernel(const float* __restrict__ part, float* __restrict__ ac,
                                   const float* __restrict__ gw, const float* __restrict__ gb,
                                   const float* __restrict__ gm, float inv_n)
{
    int j = threadIdx.x;
    if (j >= D) return;
    float s1 = 0.f, s2 = 0.f;
    for (int t = 0; t < NSLOT; ++t) {
        s1 += part[(size_t)t * 256 + j];
        s2 += part[(size_t)t * 256 + D + j];
    }
    float mean = s1 * inv_n;
    float ex2  = s2 * inv_n;
    float m    = gm[j];
    float var  = ex2 - (2.f * m - m * m) * mean * mean;
    float a    = gw[j] * rsqrtf(var + 1e-5f);
    float c    = gb[j] - a * m * mean;
    ac[j]     = a;
    ac[D + j] = c;
}

// ---------------- fused decoder tail ----------------
__global__ __launch_bounds__(256) void dec_tail_kernel(
    const float* __restrict__ in, const float* __restrict__ W1, const float* __restrict__ b1,
    const float* __restrict__ W2, const float* __restrict__ b2,
    const float* __restrict__ W3, const float* __restrict__ b3,
    float* __restrict__ out, int n)
{
    int t = blockIdx.x * THREADS + threadIdx.x;
    if (t >= n) return;

    float x[64];
#pragma unroll
    for (int q = 0; q < 16; ++q)
        *(float4*)&x[q * 4] = *(const float4*)&in[(size_t)t * 64 + q * 4];

    float h1[32];
#pragma unroll
    for (int j = 0; j < 32; ++j) h1[j] = b1[j];
#pragma unroll 8
    for (int k = 0; k < 64; ++k) {
        const float xk = x[k];
#pragma unroll
        for (int j = 0; j < 32; ++j) h1[j] = fmaf(xk, W1[k * 32 + j], h1[j]);
    }
#pragma unroll
    for (int j = 0; j < 32; ++j) h1[j] = fmaxf(h1[j], 0.f);

    float h2[16];
#pragma unroll
    for (int j = 0; j < 16; ++j) h2[j] = b2[j];
#pragma unroll 8
    for (int k = 0; k < 32; ++k) {
        const float hk = h1[k];
#pragma unroll
        for (int j = 0; j < 16; ++j) h2[j] = fmaf(hk, W2[k * 16 + j], h2[j]);
    }

    float acc = b3[0];
#pragma unroll
    for (int k = 0; k < 16; ++k) acc = fmaf(fmaxf(h2[k], 0.f), W3[k], acc);
    out[t] = 1.0f / (1.0f + expf(-acc));
}

// ---------------- launch ----------------

extern "C" void kernel_launch(void* const* d_in, const int* in_sizes, int n_in,
                              void* d_out, int out_size, void* d_ws, size_t ws_size,
                              hipStream_t stream)
{
    const float* local_x    = (const float*)d_in[0];
    const int*   local_type = (const int*)d_in[1];
    const float* voxel_x    = (const float*)d_in[2];
    const int*   voxel_type = (const int*)d_in[3];
    const int*   edge_index = (const int*)d_in[4];
    const float* label      = (const float*)d_in[5];
    const float* We1 = (const float*)d_in[6],  *be1 = (const float*)d_in[7];
    const float* We2 = (const float*)d_in[8],  *be2 = (const float*)d_in[9];
    const float *Wc[4], *bc[4], *gw[4], *gb[4], *gm[4];
    for (int i = 0; i < 4; ++i) {
        Wc[i] = (const float*)d_in[10 + i * 5];
        bc[i] = (const float*)d_in[11 + i * 5];
        gw[i] = (const float*)d_in[12 + i * 5];
        gb[i] = (const float*)d_in[13 + i * 5];
        gm[i] = (const float*)d_in[14 + i * 5];
    }
    const float* Wd0 = (const float*)d_in[30], *bd0 = (const float*)d_in[31];
    const float* Wd1 = (const float*)d_in[32], *bd1 = (const float*)d_in[33];
    const float* Wd2 = (const float*)d_in[34], *bd2 = (const float*)d_in[35];
    const float* Wd3 = (const float*)d_in[36], *bd3 = (const float*)d_in[37];

    const int n  = in_sizes[2] / 6;    // 200000
    const int E  = in_sizes[4] / 2;    // 1200000
    const int nl = in_sizes[0] / 19;   // 400
    const int* src = edge_index;
    const int* dst = edge_index + E;

    auto align256 = [](size_t x) { return (x + 255) & ~(size_t)255; };
    char* w = (char*)d_ws;
    float* ac_all = (float*)w;
    float* means  = (float*)(w + 4096);
    int* blocksums = (int*)(w + 8192);
    float* stats_part = (float*)(w + 8192 + 1024);
    size_t off = 8192 + 1024 + 4 * NSLOT * 256 * sizeof(float);
    ushort_t* wt0 = (ushort_t*)(w + off); off += align256(16384 * 2);
    ushort_t* wt1 = (ushort_t*)(w + off); off += align256(8192 * 2);
    ushort_t* wt2 = (ushort_t*)(w + off); off += align256(8192 * 2);
    ushort_t* wt3 = (ushort_t*)(w + off); off += align256(8192 * 2);
    int*   rowptr = (int*)(w + off);   off += align256((size_t)(n + 1) * 4);
    float* dinv   = (float*)(w + off); off += align256((size_t)n * 4);
    int*   esrc   = (int*)(w + off);   off += align256((size_t)E * 4);
    int*   qpos   = (int*)(w + off);   off += align256((size_t)E * 4);
    float* A    = (float*)(w + off);
    float* B    = A + (size_t)n * 128;
    float* A_lo = A;
    float* A_hi = A + (size_t)n * 64;
    float* B_lo = B;
    float* B_hi = B + (size_t)n * 64;
    int*   degi = (int*)A;

    const float inv_n = 1.0f / (float)n;
    auto cdiv = [](long long a, long long b) { return (int)((a + b - 1) / b); };
    const int nb = cdiv(n, 1024);

    float* part0 = stats_part + 0 * NSLOT * 256;
    float* part1 = stats_part + 1 * NSLOT * 256;
    float* part2 = stats_part + 2 * NSLOT * 256;
    float* part3 = stats_part + 3 * NSLOT * 256;
    float* ac0 = ac_all + 0, *ac1 = ac_all + 256, *ac2 = ac_all + 512, *ac3 = ac_all + 768;

    hipMemsetAsync(stats_part, 0, 4 * NSLOT * 256 * sizeof(float), stream);
    hipMemsetAsync(degi, 0, (size_t)n * sizeof(int), stream);

    wtrans_kernel<<<cdiv(128 * 128, 256), 256, 0, stream>>>(We2,   wt0, 128, 128);
    wtrans_kernel<<<cdiv(128 * 64, 256), 256, 0, stream>>>(Wc[0], wt1, 128, 64);
    wtrans_kernel<<<cdiv(64 * 128, 256), 256, 0, stream>>>(Wc[3], wt2, 64, 128);
    wtrans_kernel<<<cdiv(128 * 64, 256), 256, 0, stream>>>(Wd0,   wt3, 128, 64);

    local_means_kernel<<<1, 256, 0, stream>>>(local_x, local_type, means, nl);
    hist_kernel<<<cdiv(E, 256), 256, 0, stream>>>(dst, degi, qpos, E);
    scan_part1_kernel<<<nb, 256, 0, stream>>>(degi, blocksums, n);
    scan_part2_kernel<<<1, 256, 0, stream>>>(blocksums, nb);
    scan_part3_kernel<<<nb, 256, 0, stream>>>(degi, blocksums, rowptr, dinv, n, E);
    fill_kernel<<<cdiv(E, 256), 256, 0, stream>>>(src, dst, qpos, rowptr, esrc, E);
    build_x0_kernel<<<cdiv((long long)n * 32, 256), 256, 0, stream>>>(means, voxel_type, voxel_x, label, B_lo, n);

    const int gagg  = 2048;
    const int gmfma = cdiv(n, 128);

    // enc1 (f32): X0=B_lo(32w) -> A(128)
    mlp_kernel<32, 128, 128, 8, true, true, false, false, false><<<cdiv(n, 128), 256, 0, stream>>>(B_lo, A, We1, be1, nullptr, nullptr, nullptr, n);
    // enc2 (MFMA): A -> B
    mfma_mlp_kernel<128, 128, true, true, false, false, false><<<gmfma, 256, 0, stream>>>(A, B, wt0, be2, nullptr, nullptr, nullptr, n);

    // conv0 (MFMA): B -> T0=A_lo(64w, dinv-scaled); gather -> A_hi [+stats0]
    mfma_mlp_kernel<128, 64, false, false, false, true, false><<<gmfma, 256, 0, stream>>>(B, A_lo, wt1, nullptr, nullptr, dinv, nullptr, n);
    gather_agg_kernel<64><<<gagg, 256, 0, stream>>>(A_lo, A_hi, rowptr, esrc, dinv, bc[0], part0, n);
    gn_finalize_kernel<64><<<1, 64, 0, stream>>>(part0, ac0, gw[0], gb[0], gm[0], inv_n);

    // conv1 (f32): A_hi(+GN ac0) -> T1=B_lo(32w, dinv-scaled); gather -> B_hi(32w) [+stats1]
    mlp_kernel<64, 32, 256, 4, false, false, true, true, false><<<cdiv(n, 256), 256, 0, stream>>>(A_hi, B_lo, Wc[1], nullptr, ac0, dinv, nullptr, n);
    gather_agg_kernel<32><<<gagg, 256, 0, stream>>>(B_lo, B_hi, rowptr, esrc, dinv, bc[1], part1, n);
    gn_finalize_kernel<32><<<1, 32, 0, stream>>>(part1, ac1, gw[1], gb[1], gm[1], inv_n);

    // conv2: gather_pre<32>(B_hi,+GN ac1) -> G2=A_lo(32w); f32 GEMM -> B_hi(64w) [+stats2 fused]
    gather_pre_kernel<32><<<gagg, 256, 0, stream>>>(B_hi, A_lo, rowptr, esrc, dinv, ac1, n);
    mlp_kernel<32, 64, 256, 8, false, true, false, false, true><<<cdiv(n, 256), 256, 0, stream>>>(A_lo, B_hi, Wc[2], bc[2], nullptr, nullptr, part2, n);
    gn_finalize_kernel<64><<<1, 64, 0, stream>>>(part2, ac2, gw[2], gb[2], gm[2], inv_n);

    // conv3: gather_pre<64>(B_hi,+GN ac2) -> G3=B_lo(64w); MFMA -> A(128) [+stats3 fused]
    gather_pre_kernel<64><<<gagg, 256, 0, stream>>>(B_hi, B_lo, rowptr, esrc, dinv, ac2, n);
    mfma_mlp_kernel<64, 128, false, true, false, false, true><<<gmfma, 256, 0, stream>>>(B_lo, A, wt2, bc[3], nullptr, nullptr, part3, n);
    gn_finalize_kernel<128><<<1, 128, 0, stream>>>(part3, ac3, gw[3], gb[3], gm[3], inv_n);

    // dec0 (MFMA): A(+GN ac3) -> D0=B_lo(64w); fused tail -> out
    mfma_mlp_kernel<128, 64, true, true, true, false, false><<<gmfma, 256, 0, stream>>>(A, B_lo, wt3, bd0, ac3, nullptr, nullptr, n);
    dec_tail_kernel<<<cdiv(n, 256), 256, 0, stream>>>(B_lo, Wd1, bd1, Wd2, bd2, Wd3, bd3, (float*)d_out, n);
}